// Round 9
// baseline (13456.056 us; speedup 1.0000x reference)
//
#include <hip/hip_runtime.h>

#define NN 100000
#define NE 1000000
#define NG 100
#define DD 70
#define EL0 64             // edges per slot in k_edge0
#define CH0 (9 * EL0)      // 576 edges per block
#define EL2 56             // edges per slot in k_edge2
#define CH2 (9 * EL2)      // 504 edges per block
#define SCB 512
#define WTS (70 * 72)      // one transposed weight matrix, padded

__device__ __forceinline__ float sigmoidf_(float x) { return 1.f / (1.f + expf(-x)); }

#define DOT4(acc, vv, ww) { acc = fmaf((vv).x, (ww).x, acc); acc = fmaf((vv).y, (ww).y, acc); \
                            acc = fmaf((vv).z, (ww).z, acc); acc = fmaf((vv).w, (ww).w, acc); }

// ---------- transpose all 10 weight matrices into WT[m][70][72], zero-padded ----------
__global__ void k_trAll(const float* __restrict__ Wh, const float* __restrict__ Wg,
                        float* __restrict__ WT) {
    int m = blockIdx.y, f = blockIdx.x, k = threadIdx.x;  // k in [0,72)
    const float* W;
    int K = DD;
    switch (m) {
        case 0: W = Wh; K = 64; break;
        case 1: W = Wg + 0 * 4900; break;
        case 2: W = Wg + 1 * 4900; break;
        case 3: W = Wg + 3 * 4900; break;
        case 4: W = Wg + 4 * 4900; break;
        case 5: W = Wg + 10 * 4900; break;
        case 6: W = Wg + 11 * 4900; break;
        case 7: W = Wg + 13 * 4900; break;
        case 8: W = Wg + 14 * 4900; break;
        default: W = Wg + 12 * 4900; break;  // m=9: C2
    }
    if (k < 72) WT[(m * 70 + f) * 72 + k] = (k < K) ? W[k * DD + f] : 0.f;
}

// ---------- skinny dense: 36-row tile, 4 rows/thread, 1 barrier ----------
__global__ __launch_bounds__(640) void k_dense_r(const float* __restrict__ x, int K,
                                                 const float* __restrict__ WTm,
                                                 const float* __restrict__ bias,
                                                 float* __restrict__ out, int nrows) {
    __shared__ float sx[36 * 72];
    int t = threadIdx.x;
    int r = t / DD, f = t - r * DD;
    long rb = (long)blockIdx.x * 36;
    for (int idx = t; idx < 36 * 72; idx += 640) {
        int rr = idx / 72, kk = idx - rr * 72;
        long i = rb + rr;
        sx[idx] = (kk < K && i < nrows) ? x[i * K + kk] : 0.f;
    }
    __syncthreads();
    if (r < 9) {
        const float4* wr = (const float4*)(WTm + f * 72);
        float bb = bias[f];
        float a0 = bb, a1 = bb, a2 = bb, a3 = bb;
        const float4* s0 = (const float4*)&sx[(r) * 72];
        const float4* s1 = (const float4*)&sx[(r + 9) * 72];
        const float4* s2 = (const float4*)&sx[(r + 18) * 72];
        const float4* s3 = (const float4*)&sx[(r + 27) * 72];
#pragma unroll
        for (int q = 0; q < 18; ++q) {
            float4 w4 = wr[q];
            float4 v0 = s0[q], v1 = s1[q], v2 = s2[q], v3 = s3[q];
            DOT4(a0, v0, w4)
            DOT4(a1, v1, w4)
            DOT4(a2, v2, w4)
            DOT4(a3, v3, w4)
        }
        long i0 = rb + r, i1 = i0 + 9, i2 = i0 + 18, i3 = i0 + 27;
        if (i0 < nrows) out[i0 * DD + f] = a0;
        if (i1 < nrows) out[i1 * DD + f] = a1;
        if (i2 < nrows) out[i2 * DD + f] = a2;
        if (i3 < nrows) out[i3 * DD + f] = a3;
    }
}

// ---------- v1 = We @ Wc0 ; v2 = be @ Wc0 + bc0 ----------
__global__ void k_pre(const float* __restrict__ We, const float* __restrict__ be,
                      const float* __restrict__ Wg, const float* __restrict__ bg,
                      float* __restrict__ v1, float* __restrict__ v2) {
    int f = threadIdx.x;
    if (f < DD) {
        const float* W2 = Wg + 2 * DD * DD;  // layer0, proj C
        const float* b2 = bg + 2 * DD;
        float a = 0.f, c = 0.f;
        for (int k = 0; k < DD; ++k) {
            a = fmaf(We[k], W2[k * DD + f], a);
            c = fmaf(be[k], W2[k * DD + f], c);
        }
        v1[f] = a;
        v2[f] = c + b2[f];
    }
}

// ---------- CSR build: count / scan / fill ----------
__global__ void k_count(const int* __restrict__ dst, int* __restrict__ off) {
    int j = blockIdx.x * 256 + threadIdx.x;
    if (j < NE) atomicAdd(&off[dst[j]], 1);
}

__global__ void k_scan_a(int* __restrict__ off, int* __restrict__ part) {
    __shared__ int s[SCB];
    int t = threadIdx.x, i = blockIdx.x * SCB + t;
    int v = (i < NN) ? off[i] : 0;
    s[t] = v;
    __syncthreads();
    for (int d = 1; d < SCB; d <<= 1) {
        int x = (t >= d) ? s[t - d] : 0;
        __syncthreads();
        s[t] += x;
        __syncthreads();
    }
    if (i < NN) off[i] = s[t] - v;
    if (t == SCB - 1) part[blockIdx.x] = s[t];
}

__global__ void k_scan_b(int* __restrict__ part, int nb) {
    __shared__ int s[256];
    int t = threadIdx.x;
    int v = (t < nb) ? part[t] : 0;
    s[t] = v;
    __syncthreads();
    for (int d = 1; d < 256; d <<= 1) {
        int x = (t >= d) ? s[t - d] : 0;
        __syncthreads();
        s[t] += x;
        __syncthreads();
    }
    if (t < nb) part[t] = s[t] - v;
}

__global__ void k_scan_c(int* __restrict__ off, const int* __restrict__ part) {
    int i = blockIdx.x * SCB + threadIdx.x;
    if (i < NN) off[i] += part[blockIdx.x];
}

__global__ void k_fill(const int* __restrict__ src, const int* __restrict__ dst,
                       const float* __restrict__ ef, const float* __restrict__ sne,
                       int* __restrict__ off, int* __restrict__ src_s,
                       float* __restrict__ ef_s, float* __restrict__ sne_s) {
    int j = blockIdx.x * 256 + threadIdx.x;
    if (j < NE) {
        int d = dst[j];
        int pos = atomicAdd(&off[d], 1);  // off becomes shifted: off[n] = end(n)
        src_s[pos] = src[j];
        ef_s[pos] = ef[j];
        sne_s[pos] = sne[j];
    }
}

// ---------- layer-0 edge pass: edge-centric, 4-wide gather batching ----------
__global__ __launch_bounds__(640) void k_edge0(
    const float* __restrict__ ef_s, const float* __restrict__ sne_s,
    const int* __restrict__ src_s, const int* __restrict__ off,
    const float* __restrict__ PB, const float* __restrict__ PD,
    const float* __restrict__ PE, const float* __restrict__ v1,
    const float* __restrict__ v2, float* __restrict__ num,
    float* __restrict__ den, float* __restrict__ red) {
    int t = threadIdx.x;
    int r = t / DD, f = t - r * DD;
    bool act = (r < 9);
    float c1 = 0.f, c2 = 0.f;
    if (act) { c1 = v1[f]; c2 = v2[f]; }
    float acc_s = 0.f, acc_q = 0.f;
    int e_beg = blockIdx.x * CH0 + r * EL0;
    bool live = act && e_beg < NE;
    int n = 0;
    float pe = 0.f, accn = 0.f, accd = 0.f;
    int lim = 0;
    if (live) {
        int lo = 0, hi = NN - 1;  // smallest n with off[n] > e_beg (off[n]=end(n))
        while (lo < hi) {
            int mid = (lo + hi) >> 1;
            if (off[mid] > e_beg) hi = mid; else lo = mid + 1;
        }
        n = lo;
        pe = PE[(long)n * DD + f];
        lim = NE - e_beg;
        if (lim > EL0) lim = EL0;
    }
    for (int g = 0; g < lim; g += 4) {
        int m = lim - g;
        if (m > 4) m = 4;
        int sj[4];
        float pdj[4], pbj[4], efj[4], snj[4];
#pragma unroll
        for (int j = 0; j < 4; ++j) {
            if (j < m) {
                int e = e_beg + g + j;
                int s = src_s[e];
                sj[j] = s;
                efj[j] = ef_s[e];
                snj[j] = sne_s[e];
                pdj[j] = PD[(long)s * DD + f];
                pbj[j] = PB[(long)s * DD + f];
            }
        }
#pragma unroll
        for (int j = 0; j < 4; ++j) {
            if (j < m) {
                int e = e_beg + g + j;
                if (e >= off[n]) {  // crossed into next dst run: flush
                    unsafeAtomicAdd(&num[(long)n * DD + f], accn);
                    unsafeAtomicAdd(&den[(long)n * DD + f], accd);
                    accn = 0.f; accd = 0.f;
                    do { ++n; } while (off[n] <= e);
                    pe = PE[(long)n * DD + f];
                }
                float en = pdj[j] + pe + efj[j] * c1 + c2;
                float sg = sigmoidf_(en);
                accn = fmaf(sg, pbj[j], accn);
                accd += sg;
                float tv = en * snj[j];
                acc_s += tv;
                acc_q = fmaf(tv, tv, acc_q);
            }
        }
    }
    if (live) {
        unsafeAtomicAdd(&num[(long)n * DD + f], accn);
        unsafeAtomicAdd(&den[(long)n * DD + f], accd);
    }
    __shared__ float ss[DD], sq[DD];
    if (t < DD) { ss[t] = 0.f; sq[t] = 0.f; }
    __syncthreads();
    if (act) { atomicAdd(&ss[f], acc_s); atomicAdd(&sq[f], acc_q); }
    __syncthreads();
    if (t < DD) {
        atomicAdd(&red[t], ss[t]);
        atomicAdd(&red[DD + t], sq[t]);
    }
}

// ---------- layer-2 edge kernel: 4-edge micro-batch, 4 independent FMA chains ----------
__global__ __launch_bounds__(640) void k_edge2(
    const float* __restrict__ ef_s, const float* __restrict__ sne_s,
    const int* __restrict__ src_s, const int* __restrict__ off,
    const float* __restrict__ PD0, const float* __restrict__ PE0,
    const float* __restrict__ PB2, const float* __restrict__ PD2,
    const float* __restrict__ PE2,
    const float* __restrict__ v1, const float* __restrict__ v2,
    const float* __restrict__ murs_e, const float* __restrict__ ge,
    const float* __restrict__ bbe, const float* __restrict__ We,
    const float* __restrict__ be,
    const float* __restrict__ WT9, const float* __restrict__ bC2,
    float* __restrict__ num, float* __restrict__ den) {
    __shared__ float se[9 * 4 * 72];  // 9 rows x 4 staged edges x padded 72
    int t = threadIdx.x;
    int r = t / DD, f = t - r * DD;
    bool act = (r < 9);
    float c_v1 = 0.f, c_v2 = 0.f, c_mu = 0.f, c_rs = 0.f, c_g = 0.f, c_b = 0.f,
          c_We = 0.f, c_be = 0.f, c_b2 = 0.f;
    if (act) {
        c_v1 = v1[f]; c_v2 = v2[f];
        c_mu = murs_e[f]; c_rs = murs_e[DD + f];
        c_g = ge[f]; c_b = bbe[f];
        c_We = We[f]; c_be = be[f];
        c_b2 = bC2[f];
    }
    for (int idx = t; idx < 9 * 4 * 72; idx += 640) se[idx] = 0.f;
    int e_beg = blockIdx.x * CH2 + r * EL2;
    bool live = act && e_beg < NE;
    int n = 0, ns = 0;
    float pe0 = 0.f, pe2 = 0.f, accn = 0.f, accd = 0.f;
    int lim = 0;
    if (live) {
        int lo = 0, hi = NN - 1;  // smallest n with off[n] > e_beg
        while (lo < hi) {
            int mid = (lo + hi) >> 1;
            if (off[mid] > e_beg) hi = mid; else lo = mid + 1;
        }
        n = lo; ns = lo;
        pe0 = PE0[(long)ns * DD + f];
        pe2 = PE2[(long)n * DD + f];
        lim = NE - e_beg;
        if (lim > EL2) lim = EL2;
    }
    __syncthreads();  // zeros (incl. pads) visible before first stage
    for (int g = 0; g < EL2; g += 4) {
        int m = lim - g;
        if (m > 4) m = 4;
        if (m < 0) m = 0;
        int sj[4];
#pragma unroll
        for (int j = 0; j < 4; ++j) {
            if (j < m) {
                int e = e_beg + g + j;
                if (e >= off[ns]) {  // staging run pointer (no flush)
                    do { ++ns; } while (off[ns] <= e);
                    pe0 = PE0[(long)ns * DD + f];
                }
                int s = src_s[e];
                sj[j] = s;
                float efv = ef_s[e], snv = sne_s[e];
                // e1[e,f] = e0 + relu(bn_e((Dh0[s]+Eh0[d]+Ce0)*sne))
                float en0 = PD0[(long)s * DD + f] + pe0 + efv * c_v1 + c_v2;
                float tv = en0 * snv;
                float bnv = (tv - c_mu) * c_rs * c_g + c_b;
                se[(r * 4 + j) * 72 + f] = fmaf(efv, c_We, c_be) + fmaxf(bnv, 0.f);
            }
        }
        __syncthreads();
        if (act) {
            float a0 = c_b2, a1 = c_b2, a2 = c_b2, a3 = c_b2;
            const float4* sb = (const float4*)&se[(r * 4) * 72];
            const float4* wr = (const float4*)(WT9 + f * 72);
#pragma unroll
            for (int q = 0; q < 18; ++q) {
                float4 w4 = wr[q];
                float4 x0 = sb[q], x1 = sb[18 + q], x2 = sb[36 + q], x3 = sb[54 + q];
                DOT4(a0, x0, w4)
                DOT4(a1, x1, w4)
                DOT4(a2, x2, w4)
                DOT4(a3, x3, w4)
            }
#pragma unroll
            for (int j = 0; j < 4; ++j) {
                if (j < m) {
                    float aj = (j == 0) ? a0 : (j == 1) ? a1 : (j == 2) ? a2 : a3;
                    int e = e_beg + g + j;
                    if (e >= off[n]) {  // accumulate run pointer: flush
                        unsafeAtomicAdd(&num[(long)n * DD + f], accn);
                        unsafeAtomicAdd(&den[(long)n * DD + f], accd);
                        accn = 0.f; accd = 0.f;
                        do { ++n; } while (off[n] <= e);
                        pe2 = PE2[(long)n * DD + f];
                    }
                    float en = PD2[(long)sj[j] * DD + f] + pe2 + aj;
                    float sg = sigmoidf_(en);
                    accn = fmaf(sg, PB2[(long)sj[j] * DD + f], accn);
                    accd += sg;
                }
            }
        }
        __syncthreads();
    }
    if (live) {
        unsafeAtomicAdd(&num[(long)n * DD + f], accn);
        unsafeAtomicAdd(&den[(long)n * DD + f], accd);
    }
}

// ---------- node BN stats: grid-stride, reg-accum ----------
__global__ __launch_bounds__(640) void k_nstats(const float* __restrict__ PA,
                                                const float* __restrict__ num,
                                                const float* __restrict__ den,
                                                const float* __restrict__ snn,
                                                float* __restrict__ red) {
    int t = threadIdx.x;
    int r = t / DD, f = t - r * DD;
    bool act = (r < 9);
    float acc_s = 0.f, acc_q = 0.f;
    const int T = (NN + 8) / 9;
    for (int tile = blockIdx.x; tile < T; tile += gridDim.x) {
        int i = tile * 9 + r;
        if (act && i < NN) {
            long o = (long)i * DD + f;
            float v = (PA[o] + num[o] / (den[o] + 1e-6f)) * snn[i];
            acc_s += v;
            acc_q = fmaf(v, v, acc_q);
        }
    }
    __shared__ float ss[DD], sq[DD];
    if (t < DD) { ss[t] = 0.f; sq[t] = 0.f; }
    __syncthreads();
    if (act) { atomicAdd(&ss[f], acc_s); atomicAdd(&sq[f], acc_q); }
    __syncthreads();
    if (t < DD) {
        atomicAdd(&red[t], ss[t]);
        atomicAdd(&red[DD + t], sq[t]);
    }
}

// ---------- finalize BN stats ----------
__global__ void k_stats(const float* __restrict__ sums, float* __restrict__ murs, float invn) {
    int f = threadIdx.x;
    if (f < DD) {
        float mu = sums[f] * invn;
        float var = sums[DD + f] * invn - mu * mu;
        murs[f] = mu;
        murs[DD + f] = rsqrtf(var + 1e-5f);
    }
}

// ---------- recompute v, BN-apply + relu + residual ----------
__global__ __launch_bounds__(256) void k_apply(const float* __restrict__ hin,
                                               const float* __restrict__ PA,
                                               const float* __restrict__ num,
                                               const float* __restrict__ den,
                                               const float* __restrict__ snn,
                                               const float* __restrict__ murs,
                                               const float* __restrict__ g,
                                               const float* __restrict__ b,
                                               float* __restrict__ hout) {
    long idx = (long)blockIdx.x * 256 + threadIdx.x;
    if (idx < (long)NN * DD) {
        int i = (int)(idx / DD);
        int f = (int)(idx - (long)i * DD);
        float v = (PA[idx] + num[idx] / (den[idx] + 1e-6f)) * snn[i];
        float bnv = (v - murs[f]) * murs[DD + f] * g[f] + b[f];
        hout[idx] = hin[idx] + fmaxf(bnv, 0.f);
    }
}

// ---------- per-graph sums (ids sorted -> run-length within block) ----------
__global__ __launch_bounds__(640) void k_readout(const float* __restrict__ h,
                                                 const int* __restrict__ gid,
                                                 float* __restrict__ gsum,
                                                 float* __restrict__ gcnt) {
    __shared__ float sv[9 * DD];
    __shared__ int sg_[9];
    int t = threadIdx.x;
    int r = t / DD, f = t - r * DD;
    int i = blockIdx.x * 9 + r;
    if (r < 9 && i < NN) {
        sv[r * DD + f] = h[(long)i * DD + f];
        if (f == 0) sg_[r] = gid[i];
    }
    __syncthreads();
    int nvalid = NN - blockIdx.x * 9;
    if (nvalid > 9) nvalid = 9;
    if (t < DD && nvalid > 0) {
        float acc = 0.f;
        int cur = sg_[0];
        for (int rr = 0; rr < nvalid; ++rr) {
            int g = sg_[rr];
            if (g != cur) {
                unsafeAtomicAdd(&gsum[cur * DD + t], acc);
                acc = 0.f;
                cur = g;
            }
            acc += sv[rr * DD + t];
        }
        unsafeAtomicAdd(&gsum[cur * DD + t], acc);
        if (t == 0) {
            int cnt = 0;
            cur = sg_[0];
            for (int rr = 0; rr < nvalid; ++rr) {
                if (sg_[rr] != cur) {
                    unsafeAtomicAdd(&gcnt[cur], (float)cnt);
                    cnt = 0;
                    cur = sg_[rr];
                }
                cnt++;
            }
            unsafeAtomicAdd(&gcnt[cur], (float)cnt);
        }
    }
}

__global__ void k_out(const float* __restrict__ gsum, const float* __restrict__ gcnt,
                      float* __restrict__ out) {
    int idx = blockIdx.x * 256 + threadIdx.x;
    if (idx < NG * DD) {
        int g = idx / DD;
        out[idx] = gsum[idx] / fmaxf(gcnt[g], 1.f);
    }
}

extern "C" void kernel_launch(void* const* d_in, const int* in_sizes, int n_in,
                              void* d_out, int out_size, void* d_ws, size_t ws_size,
                              hipStream_t stream) {
    const float* x   = (const float*)d_in[0];
    const float* ef  = (const float*)d_in[1];
    const float* snn = (const float*)d_in[2];
    const float* sne = (const float*)d_in[3];
    const int*   src = (const int*)d_in[4];
    const int*   dst = (const int*)d_in[5];
    const int*   gid = (const int*)d_in[6];
    const float* Wh  = (const float*)d_in[7];
    const float* bh  = (const float*)d_in[8];
    const float* We  = (const float*)d_in[9];
    const float* be  = (const float*)d_in[10];
    const float* Wg  = (const float*)d_in[11];
    const float* bg  = (const float*)d_in[12];
    const float* gh  = (const float*)d_in[13];
    const float* bbh = (const float*)d_in[14];
    const float* ge  = (const float*)d_in[15];
    const float* bbe = (const float*)d_in[16];
    float* out = (float*)d_out;

    const size_t NF = (size_t)NN * DD;  // 7,000,000

    float* ws = (float*)d_ws;
    float* B0 = ws;            // h0 -> PD2 -> h_final
    float* B1 = B0 + NF;       // h1
    float* B2 = B1 + NF;       // PA / PA2
    float* B3 = B2 + NF;       // PB / PB2
    float* B4 = B3 + NF;       // PD0 (kept through k_edge2)
    float* B5 = B4 + NF;       // PE0 (kept through k_edge2)
    float* B6 = B5 + NF;       // PE2
    float* num = B6 + NF;      // NF
    float* den = num + NF;     // NF
    float* red  = den + NF;        // 4*DD
    float* gsum = red + 4 * DD;    // NG*DD
    float* gcnt = gsum + NG * DD;  // NG
    float* v1 = gcnt + NG;
    float* v2 = v1 + DD;
    float* murs_e = v2 + DD;       // 2*DD
    float* murs_h = murs_e + 2 * DD;
    int* off   = (int*)(murs_h + 2 * DD);  // NN
    int* part  = off + NN;                  // 256
    int* src_s = part + 256;                // NE
    float* ef_s  = (float*)(src_s + NE);    // NE
    float* sne_s = ef_s + NE;               // NE
    float* WT    = sne_s + NE;              // 10 * WTS

    size_t need = (size_t)((char*)(WT + 10 * WTS) - (char*)d_ws);  // ~264.6 MB
    if (ws_size < need) return;

    const int NB_N36 = (NN + 35) / 36;        // 2778
    const int NB_N9  = (NN + 8) / 9;          // 11112
    const int NB_E256 = (NE + 255) / 256;     // 3907
    const int NB_SC  = (NN + SCB - 1) / SCB;  // 196
    const int NB_E0  = (NE + CH0 - 1) / CH0;  // 1737
    const int NB_E2  = (NE + CH2 - 1) / CH2;  // 1985

    // zero: num/den (edge0 is now atomic-flush) + red + gsum + gcnt (contiguous) + CSR counts
    hipMemsetAsync(num, 0, (2 * NF + 4 * DD + NG * DD + NG) * sizeof(float), stream);
    hipMemsetAsync(off, 0, NN * sizeof(int), stream);

    // ---- weight transposes + CSR build ----
    k_trAll<<<dim3(70, 10), 72, 0, stream>>>(Wh, Wg, WT);
    k_count<<<NB_E256, 256, 0, stream>>>(dst, off);
    k_scan_a<<<NB_SC, SCB, 0, stream>>>(off, part);
    k_scan_b<<<1, 256, 0, stream>>>(part, NB_SC);
    k_scan_c<<<NB_SC, SCB, 0, stream>>>(off, part);
    k_fill<<<NB_E256, 256, 0, stream>>>(src, dst, ef, sne, off, src_s, ef_s, sne_s);

    k_pre<<<1, 128, 0, stream>>>(We, be, Wg, bg, v1, v2);
    k_dense_r<<<NB_N36, 640, 0, stream>>>(x, 64, WT + 0 * WTS, bh, B0, NN);

    // ---- layer 0 (params index 0) ----
    k_dense_r<<<NB_N36, 640, 0, stream>>>(B0, 70, WT + 1 * WTS, bg + 0 * 70, B2, NN);  // A
    k_dense_r<<<NB_N36, 640, 0, stream>>>(B0, 70, WT + 2 * WTS, bg + 1 * 70, B3, NN);  // B
    k_dense_r<<<NB_N36, 640, 0, stream>>>(B0, 70, WT + 3 * WTS, bg + 3 * 70, B4, NN);  // D
    k_dense_r<<<NB_N36, 640, 0, stream>>>(B0, 70, WT + 4 * WTS, bg + 4 * 70, B5, NN);  // E
    k_edge0<<<NB_E0, 640, 0, stream>>>(ef_s, sne_s, src_s, off, B3, B4, B5, v1, v2,
                                       num, den, red);
    k_stats<<<1, 128, 0, stream>>>(red, murs_e, 1.f / NE);
    k_nstats<<<2048, 640, 0, stream>>>(B2, num, den, snn, red + 2 * DD);
    k_stats<<<1, 128, 0, stream>>>(red + 2 * DD, murs_h, 1.f / NN);
    k_apply<<<(int)((NF + 255) / 256), 256, 0, stream>>>(B0, B2, num, den, snn, murs_h,
                                                         gh + 0, bbh + 0, B1);

    // ---- layer 2 (params index 2) ----
    hipMemsetAsync(num, 0, (2 * NF + 4 * DD) * sizeof(float), stream);  // num, den, red
    k_dense_r<<<NB_N36, 640, 0, stream>>>(B1, 70, WT + 5 * WTS, bg + 10 * 70, B2, NN); // A
    k_dense_r<<<NB_N36, 640, 0, stream>>>(B1, 70, WT + 6 * WTS, bg + 11 * 70, B3, NN); // B
    k_dense_r<<<NB_N36, 640, 0, stream>>>(B1, 70, WT + 7 * WTS, bg + 13 * 70, B0, NN); // D
    k_dense_r<<<NB_N36, 640, 0, stream>>>(B1, 70, WT + 8 * WTS, bg + 14 * 70, B6, NN); // E
    k_edge2<<<NB_E2, 640, 0, stream>>>(ef_s, sne_s, src_s, off, B4, B5, B3, B0, B6,
                                       v1, v2, murs_e, ge + 0, bbe + 0, We, be,
                                       WT + 9 * WTS, bg + 12 * 70, num, den);
    k_nstats<<<2048, 640, 0, stream>>>(B2, num, den, snn, red + 2 * DD);
    k_stats<<<1, 128, 0, stream>>>(red + 2 * DD, murs_h, 1.f / NN);
    k_apply<<<(int)((NF + 255) / 256), 256, 0, stream>>>(B1, B2, num, den, snn, murs_h,
                                                         gh + 2 * DD, bbh + 2 * DD, B0);

    // ---- readout ----
    k_readout<<<NB_N9, 640, 0, stream>>>(B0, gid, gsum, gcnt);
    k_out<<<(NG * DD + 255) / 256, 256, 0, stream>>>(gsum, gcnt, out);
}

// Round 10
// 2202.846 us; speedup vs baseline: 6.1085x; 6.1085x over previous
//
#include <hip/hip_runtime.h>

#define NN 100000
#define NE 1000000
#define NG 100
#define DD 70
#define EL0 64             // edges per slot in k_edge0
#define CH0 (9 * EL0)      // 576 edges per block
#define EL2 56             // edges per slot in k_edge2
#define CH2 (9 * EL2)      // 504 edges per block
#define SCB 512
#define WTS (70 * 72)      // one transposed weight matrix, padded

__device__ __forceinline__ float sigmoidf_(float x) { return 1.f / (1.f + expf(-x)); }

#define DOT4(acc, vv, ww) { acc = fmaf((vv).x, (ww).x, acc); acc = fmaf((vv).y, (ww).y, acc); \
                            acc = fmaf((vv).z, (ww).z, acc); acc = fmaf((vv).w, (ww).w, acc); }

// ---------- transpose all 10 weight matrices into WT[m][70][72], zero-padded ----------
__global__ void k_trAll(const float* __restrict__ Wh, const float* __restrict__ Wg,
                        float* __restrict__ WT) {
    int m = blockIdx.y, f = blockIdx.x, k = threadIdx.x;  // k in [0,72)
    const float* W;
    int K = DD;
    switch (m) {
        case 0: W = Wh; K = 64; break;
        case 1: W = Wg + 0 * 4900; break;
        case 2: W = Wg + 1 * 4900; break;
        case 3: W = Wg + 3 * 4900; break;
        case 4: W = Wg + 4 * 4900; break;
        case 5: W = Wg + 10 * 4900; break;
        case 6: W = Wg + 11 * 4900; break;
        case 7: W = Wg + 13 * 4900; break;
        case 8: W = Wg + 14 * 4900; break;
        default: W = Wg + 12 * 4900; break;  // m=9: C2
    }
    if (k < 72) WT[(m * 70 + f) * 72 + k] = (k < K) ? W[k * DD + f] : 0.f;
}

// ---------- skinny dense: 36-row tile, 4 rows/thread, 1 barrier ----------
// DOT loop: manual 2-wide, unroll-1 outer -> small live set, no spill (r9 lesson).
__global__ __launch_bounds__(640) void k_dense_r(const float* __restrict__ x, int K,
                                                 const float* __restrict__ WTm,
                                                 const float* __restrict__ bias,
                                                 float* __restrict__ out, int nrows) {
    __shared__ float sx[36 * 72];
    int t = threadIdx.x;
    int r = t / DD, f = t - r * DD;
    long rb = (long)blockIdx.x * 36;
    for (int idx = t; idx < 36 * 72; idx += 640) {
        int rr = idx / 72, kk = idx - rr * 72;
        long i = rb + rr;
        sx[idx] = (kk < K && i < nrows) ? x[i * K + kk] : 0.f;
    }
    __syncthreads();
    if (r < 9) {
        const float4* wr = (const float4*)(WTm + f * 72);
        float bb = bias[f];
        float a0 = bb, a1 = bb, a2 = bb, a3 = bb;
        const float4* s0 = (const float4*)&sx[(r) * 72];
        const float4* s1 = (const float4*)&sx[(r + 9) * 72];
        const float4* s2 = (const float4*)&sx[(r + 18) * 72];
        const float4* s3 = (const float4*)&sx[(r + 27) * 72];
#pragma unroll 1
        for (int q = 0; q < 18; q += 2) {
            float4 wA = wr[q], wB = wr[q + 1];
            float4 vA0 = s0[q], vB0 = s0[q + 1];
            DOT4(a0, vA0, wA) DOT4(a0, vB0, wB)
            float4 vA1 = s1[q], vB1 = s1[q + 1];
            DOT4(a1, vA1, wA) DOT4(a1, vB1, wB)
            float4 vA2 = s2[q], vB2 = s2[q + 1];
            DOT4(a2, vA2, wA) DOT4(a2, vB2, wB)
            float4 vA3 = s3[q], vB3 = s3[q + 1];
            DOT4(a3, vA3, wA) DOT4(a3, vB3, wB)
        }
        long i0 = rb + r, i1 = i0 + 9, i2 = i0 + 18, i3 = i0 + 27;
        if (i0 < nrows) out[i0 * DD + f] = a0;
        if (i1 < nrows) out[i1 * DD + f] = a1;
        if (i2 < nrows) out[i2 * DD + f] = a2;
        if (i3 < nrows) out[i3 * DD + f] = a3;
    }
}

// ---------- v1 = We @ Wc0 ; v2 = be @ Wc0 + bc0 ----------
__global__ void k_pre(const float* __restrict__ We, const float* __restrict__ be,
                      const float* __restrict__ Wg, const float* __restrict__ bg,
                      float* __restrict__ v1, float* __restrict__ v2) {
    int f = threadIdx.x;
    if (f < DD) {
        const float* W2 = Wg + 2 * DD * DD;  // layer0, proj C
        const float* b2 = bg + 2 * DD;
        float a = 0.f, c = 0.f;
        for (int k = 0; k < DD; ++k) {
            a = fmaf(We[k], W2[k * DD + f], a);
            c = fmaf(be[k], W2[k * DD + f], c);
        }
        v1[f] = a;
        v2[f] = c + b2[f];
    }
}

// ---------- CSR build: count / scan / fill ----------
__global__ void k_count(const int* __restrict__ dst, int* __restrict__ off) {
    int j = blockIdx.x * 256 + threadIdx.x;
    if (j < NE) atomicAdd(&off[dst[j]], 1);
}

__global__ void k_scan_a(int* __restrict__ off, int* __restrict__ part) {
    __shared__ int s[SCB];
    int t = threadIdx.x, i = blockIdx.x * SCB + t;
    int v = (i < NN) ? off[i] : 0;
    s[t] = v;
    __syncthreads();
    for (int d = 1; d < SCB; d <<= 1) {
        int x = (t >= d) ? s[t - d] : 0;
        __syncthreads();
        s[t] += x;
        __syncthreads();
    }
    if (i < NN) off[i] = s[t] - v;
    if (t == SCB - 1) part[blockIdx.x] = s[t];
}

__global__ void k_scan_b(int* __restrict__ part, int nb) {
    __shared__ int s[256];
    int t = threadIdx.x;
    int v = (t < nb) ? part[t] : 0;
    s[t] = v;
    __syncthreads();
    for (int d = 1; d < 256; d <<= 1) {
        int x = (t >= d) ? s[t - d] : 0;
        __syncthreads();
        s[t] += x;
        __syncthreads();
    }
    if (t < nb) part[t] = s[t] - v;
}

__global__ void k_scan_c(int* __restrict__ off, const int* __restrict__ part) {
    int i = blockIdx.x * SCB + threadIdx.x;
    if (i < NN) off[i] += part[blockIdx.x];
}

__global__ void k_fill(const int* __restrict__ src, const int* __restrict__ dst,
                       const float* __restrict__ ef, const float* __restrict__ sne,
                       int* __restrict__ off, int* __restrict__ src_s,
                       float* __restrict__ ef_s, float* __restrict__ sne_s) {
    int j = blockIdx.x * 256 + threadIdx.x;
    if (j < NE) {
        int d = dst[j];
        int pos = atomicAdd(&off[d], 1);  // off becomes shifted: off[n] = end(n)
        src_s[pos] = src[j];
        ef_s[pos] = ef[j];
        sne_s[pos] = sne[j];
    }
}

// ---------- layer-0 edge pass: edge-centric, 4-wide gather batching ----------
__global__ __launch_bounds__(640) void k_edge0(
    const float* __restrict__ ef_s, const float* __restrict__ sne_s,
    const int* __restrict__ src_s, const int* __restrict__ off,
    const float* __restrict__ PB, const float* __restrict__ PD,
    const float* __restrict__ PE, const float* __restrict__ v1,
    const float* __restrict__ v2, float* __restrict__ num,
    float* __restrict__ den, float* __restrict__ red) {
    int t = threadIdx.x;
    int r = t / DD, f = t - r * DD;
    bool act = (r < 9);
    float c1 = 0.f, c2 = 0.f;
    if (act) { c1 = v1[f]; c2 = v2[f]; }
    float acc_s = 0.f, acc_q = 0.f;
    int e_beg = blockIdx.x * CH0 + r * EL0;
    bool live = act && e_beg < NE;
    int n = 0;
    float pe = 0.f, accn = 0.f, accd = 0.f;
    int lim = 0;
    if (live) {
        int lo = 0, hi = NN - 1;  // smallest n with off[n] > e_beg (off[n]=end(n))
        while (lo < hi) {
            int mid = (lo + hi) >> 1;
            if (off[mid] > e_beg) hi = mid; else lo = mid + 1;
        }
        n = lo;
        pe = PE[(long)n * DD + f];
        lim = NE - e_beg;
        if (lim > EL0) lim = EL0;
    }
    for (int g = 0; g < lim; g += 4) {
        int m = lim - g;
        if (m > 4) m = 4;
        int sj[4];
        float pdj[4], pbj[4], efj[4], snj[4];
#pragma unroll
        for (int j = 0; j < 4; ++j) {
            if (j < m) {
                int e = e_beg + g + j;
                int s = src_s[e];
                sj[j] = s;
                efj[j] = ef_s[e];
                snj[j] = sne_s[e];
                pdj[j] = PD[(long)s * DD + f];
                pbj[j] = PB[(long)s * DD + f];
            }
        }
#pragma unroll
        for (int j = 0; j < 4; ++j) {
            if (j < m) {
                int e = e_beg + g + j;
                if (e >= off[n]) {  // crossed into next dst run: flush
                    unsafeAtomicAdd(&num[(long)n * DD + f], accn);
                    unsafeAtomicAdd(&den[(long)n * DD + f], accd);
                    accn = 0.f; accd = 0.f;
                    do { ++n; } while (off[n] <= e);
                    pe = PE[(long)n * DD + f];
                }
                float en = pdj[j] + pe + efj[j] * c1 + c2;
                float sg = sigmoidf_(en);
                accn = fmaf(sg, pbj[j], accn);
                accd += sg;
                float tv = en * snj[j];
                acc_s += tv;
                acc_q = fmaf(tv, tv, acc_q);
            }
        }
    }
    if (live) {
        unsafeAtomicAdd(&num[(long)n * DD + f], accn);
        unsafeAtomicAdd(&den[(long)n * DD + f], accd);
    }
    __shared__ float ss[DD], sq[DD];
    if (t < DD) { ss[t] = 0.f; sq[t] = 0.f; }
    __syncthreads();
    if (act) { atomicAdd(&ss[f], acc_s); atomicAdd(&sq[f], acc_q); }
    __syncthreads();
    if (t < DD) {
        atomicAdd(&red[t], ss[t]);
        atomicAdd(&red[DD + t], sq[t]);
    }
}

// ---------- layer-2 edge kernel: 4-edge micro-batch, 2-wide unroll-1 DOT ----------
__global__ __launch_bounds__(640) void k_edge2(
    const float* __restrict__ ef_s, const float* __restrict__ sne_s,
    const int* __restrict__ src_s, const int* __restrict__ off,
    const float* __restrict__ PD0, const float* __restrict__ PE0,
    const float* __restrict__ PB2, const float* __restrict__ PD2,
    const float* __restrict__ PE2,
    const float* __restrict__ v1, const float* __restrict__ v2,
    const float* __restrict__ murs_e, const float* __restrict__ ge,
    const float* __restrict__ bbe, const float* __restrict__ We,
    const float* __restrict__ be,
    const float* __restrict__ WT9, const float* __restrict__ bC2,
    float* __restrict__ num, float* __restrict__ den) {
    __shared__ float se[9 * 4 * 72];  // 9 rows x 4 staged edges x padded 72
    int t = threadIdx.x;
    int r = t / DD, f = t - r * DD;
    bool act = (r < 9);
    float c_v1 = 0.f, c_v2 = 0.f, c_mu = 0.f, c_rs = 0.f, c_g = 0.f, c_b = 0.f,
          c_We = 0.f, c_be = 0.f, c_b2 = 0.f;
    if (act) {
        c_v1 = v1[f]; c_v2 = v2[f];
        c_mu = murs_e[f]; c_rs = murs_e[DD + f];
        c_g = ge[f]; c_b = bbe[f];
        c_We = We[f]; c_be = be[f];
        c_b2 = bC2[f];
    }
    for (int idx = t; idx < 9 * 4 * 72; idx += 640) se[idx] = 0.f;
    int e_beg = blockIdx.x * CH2 + r * EL2;
    bool live = act && e_beg < NE;
    int n = 0, ns = 0;
    float pe0 = 0.f, pe2 = 0.f, accn = 0.f, accd = 0.f;
    int lim = 0;
    if (live) {
        int lo = 0, hi = NN - 1;  // smallest n with off[n] > e_beg
        while (lo < hi) {
            int mid = (lo + hi) >> 1;
            if (off[mid] > e_beg) hi = mid; else lo = mid + 1;
        }
        n = lo; ns = lo;
        pe0 = PE0[(long)ns * DD + f];
        pe2 = PE2[(long)n * DD + f];
        lim = NE - e_beg;
        if (lim > EL2) lim = EL2;
    }
    __syncthreads();  // zeros (incl. pads) visible before first stage
    for (int g = 0; g < EL2; g += 4) {
        int m = lim - g;
        if (m > 4) m = 4;
        if (m < 0) m = 0;
        int sj[4];
#pragma unroll
        for (int j = 0; j < 4; ++j) {
            if (j < m) {
                int e = e_beg + g + j;
                if (e >= off[ns]) {  // staging run pointer (no flush)
                    do { ++ns; } while (off[ns] <= e);
                    pe0 = PE0[(long)ns * DD + f];
                }
                int s = src_s[e];
                sj[j] = s;
                float efv = ef_s[e], snv = sne_s[e];
                // e1[e,f] = e0 + relu(bn_e((Dh0[s]+Eh0[d]+Ce0)*sne))
                float en0 = PD0[(long)s * DD + f] + pe0 + efv * c_v1 + c_v2;
                float tv = en0 * snv;
                float bnv = (tv - c_mu) * c_rs * c_g + c_b;
                se[(r * 4 + j) * 72 + f] = fmaf(efv, c_We, c_be) + fmaxf(bnv, 0.f);
            }
        }
        __syncthreads();
        if (act) {
            float a0 = c_b2, a1 = c_b2, a2 = c_b2, a3 = c_b2;
            const float4* sb = (const float4*)&se[(r * 4) * 72];
            const float4* wr = (const float4*)(WT9 + f * 72);
#pragma unroll 1
            for (int q = 0; q < 18; q += 2) {
                float4 wA = wr[q], wB = wr[q + 1];
                float4 xA0 = sb[q], xB0 = sb[q + 1];
                DOT4(a0, xA0, wA) DOT4(a0, xB0, wB)
                float4 xA1 = sb[18 + q], xB1 = sb[19 + q];
                DOT4(a1, xA1, wA) DOT4(a1, xB1, wB)
                float4 xA2 = sb[36 + q], xB2 = sb[37 + q];
                DOT4(a2, xA2, wA) DOT4(a2, xB2, wB)
                float4 xA3 = sb[54 + q], xB3 = sb[55 + q];
                DOT4(a3, xA3, wA) DOT4(a3, xB3, wB)
            }
#pragma unroll
            for (int j = 0; j < 4; ++j) {
                if (j < m) {
                    float aj = (j == 0) ? a0 : (j == 1) ? a1 : (j == 2) ? a2 : a3;
                    int e = e_beg + g + j;
                    if (e >= off[n]) {  // accumulate run pointer: flush
                        unsafeAtomicAdd(&num[(long)n * DD + f], accn);
                        unsafeAtomicAdd(&den[(long)n * DD + f], accd);
                        accn = 0.f; accd = 0.f;
                        do { ++n; } while (off[n] <= e);
                        pe2 = PE2[(long)n * DD + f];
                    }
                    float en = PD2[(long)sj[j] * DD + f] + pe2 + aj;
                    float sg = sigmoidf_(en);
                    accn = fmaf(sg, PB2[(long)sj[j] * DD + f], accn);
                    accd += sg;
                }
            }
        }
        __syncthreads();
    }
    if (live) {
        unsafeAtomicAdd(&num[(long)n * DD + f], accn);
        unsafeAtomicAdd(&den[(long)n * DD + f], accd);
    }
}

// ---------- node BN stats: grid-stride, reg-accum ----------
__global__ __launch_bounds__(640) void k_nstats(const float* __restrict__ PA,
                                                const float* __restrict__ num,
                                                const float* __restrict__ den,
                                                const float* __restrict__ snn,
                                                float* __restrict__ red) {
    int t = threadIdx.x;
    int r = t / DD, f = t - r * DD;
    bool act = (r < 9);
    float acc_s = 0.f, acc_q = 0.f;
    const int T = (NN + 8) / 9;
    for (int tile = blockIdx.x; tile < T; tile += gridDim.x) {
        int i = tile * 9 + r;
        if (act && i < NN) {
            long o = (long)i * DD + f;
            float v = (PA[o] + num[o] / (den[o] + 1e-6f)) * snn[i];
            acc_s += v;
            acc_q = fmaf(v, v, acc_q);
        }
    }
    __shared__ float ss[DD], sq[DD];
    if (t < DD) { ss[t] = 0.f; sq[t] = 0.f; }
    __syncthreads();
    if (act) { atomicAdd(&ss[f], acc_s); atomicAdd(&sq[f], acc_q); }
    __syncthreads();
    if (t < DD) {
        atomicAdd(&red[t], ss[t]);
        atomicAdd(&red[DD + t], sq[t]);
    }
}

// ---------- finalize BN stats ----------
__global__ void k_stats(const float* __restrict__ sums, float* __restrict__ murs, float invn) {
    int f = threadIdx.x;
    if (f < DD) {
        float mu = sums[f] * invn;
        float var = sums[DD + f] * invn - mu * mu;
        murs[f] = mu;
        murs[DD + f] = rsqrtf(var + 1e-5f);
    }
}

// ---------- recompute v, BN-apply + relu + residual ----------
__global__ __launch_bounds__(256) void k_apply(const float* __restrict__ hin,
                                               const float* __restrict__ PA,
                                               const float* __restrict__ num,
                                               const float* __restrict__ den,
                                               const float* __restrict__ snn,
                                               const float* __restrict__ murs,
                                               const float* __restrict__ g,
                                               const float* __restrict__ b,
                                               float* __restrict__ hout) {
    long idx = (long)blockIdx.x * 256 + threadIdx.x;
    if (idx < (long)NN * DD) {
        int i = (int)(idx / DD);
        int f = (int)(idx - (long)i * DD);
        float v = (PA[idx] + num[idx] / (den[idx] + 1e-6f)) * snn[i];
        float bnv = (v - murs[f]) * murs[DD + f] * g[f] + b[f];
        hout[idx] = hin[idx] + fmaxf(bnv, 0.f);
    }
}

// ---------- per-graph sums (ids sorted -> run-length within block) ----------
__global__ __launch_bounds__(640) void k_readout(const float* __restrict__ h,
                                                 const int* __restrict__ gid,
                                                 float* __restrict__ gsum,
                                                 float* __restrict__ gcnt) {
    __shared__ float sv[9 * DD];
    __shared__ int sg_[9];
    int t = threadIdx.x;
    int r = t / DD, f = t - r * DD;
    int i = blockIdx.x * 9 + r;
    if (r < 9 && i < NN) {
        sv[r * DD + f] = h[(long)i * DD + f];
        if (f == 0) sg_[r] = gid[i];
    }
    __syncthreads();
    int nvalid = NN - blockIdx.x * 9;
    if (nvalid > 9) nvalid = 9;
    if (t < DD && nvalid > 0) {
        float acc = 0.f;
        int cur = sg_[0];
        for (int rr = 0; rr < nvalid; ++rr) {
            int g = sg_[rr];
            if (g != cur) {
                unsafeAtomicAdd(&gsum[cur * DD + t], acc);
                acc = 0.f;
                cur = g;
            }
            acc += sv[rr * DD + t];
        }
        unsafeAtomicAdd(&gsum[cur * DD + t], acc);
        if (t == 0) {
            int cnt = 0;
            cur = sg_[0];
            for (int rr = 0; rr < nvalid; ++rr) {
                if (sg_[rr] != cur) {
                    unsafeAtomicAdd(&gcnt[cur], (float)cnt);
                    cnt = 0;
                    cur = sg_[rr];
                }
                cnt++;
            }
            unsafeAtomicAdd(&gcnt[cur], (float)cnt);
        }
    }
}

__global__ void k_out(const float* __restrict__ gsum, const float* __restrict__ gcnt,
                      float* __restrict__ out) {
    int idx = blockIdx.x * 256 + threadIdx.x;
    if (idx < NG * DD) {
        int g = idx / DD;
        out[idx] = gsum[idx] / fmaxf(gcnt[g], 1.f);
    }
}

extern "C" void kernel_launch(void* const* d_in, const int* in_sizes, int n_in,
                              void* d_out, int out_size, void* d_ws, size_t ws_size,
                              hipStream_t stream) {
    const float* x   = (const float*)d_in[0];
    const float* ef  = (const float*)d_in[1];
    const float* snn = (const float*)d_in[2];
    const float* sne = (const float*)d_in[3];
    const int*   src = (const int*)d_in[4];
    const int*   dst = (const int*)d_in[5];
    const int*   gid = (const int*)d_in[6];
    const float* Wh  = (const float*)d_in[7];
    const float* bh  = (const float*)d_in[8];
    const float* We  = (const float*)d_in[9];
    const float* be  = (const float*)d_in[10];
    const float* Wg  = (const float*)d_in[11];
    const float* bg  = (const float*)d_in[12];
    const float* gh  = (const float*)d_in[13];
    const float* bbh = (const float*)d_in[14];
    const float* ge  = (const float*)d_in[15];
    const float* bbe = (const float*)d_in[16];
    float* out = (float*)d_out;

    const size_t NF = (size_t)NN * DD;  // 7,000,000

    float* ws = (float*)d_ws;
    float* B0 = ws;            // h0 -> PD2 -> h_final
    float* B1 = B0 + NF;       // h1
    float* B2 = B1 + NF;       // PA / PA2
    float* B3 = B2 + NF;       // PB / PB2
    float* B4 = B3 + NF;       // PD0 (kept through k_edge2)
    float* B5 = B4 + NF;       // PE0 (kept through k_edge2)
    float* B6 = B5 + NF;       // PE2
    float* num = B6 + NF;      // NF
    float* den = num + NF;     // NF
    float* red  = den + NF;        // 4*DD
    float* gsum = red + 4 * DD;    // NG*DD
    float* gcnt = gsum + NG * DD;  // NG
    float* v1 = gcnt + NG;
    float* v2 = v1 + DD;
    float* murs_e = v2 + DD;       // 2*DD
    float* murs_h = murs_e + 2 * DD;
    int* off   = (int*)(murs_h + 2 * DD);  // NN
    int* part  = off + NN;                  // 256
    int* src_s = part + 256;                // NE
    float* ef_s  = (float*)(src_s + NE);    // NE
    float* sne_s = ef_s + NE;               // NE
    float* WT    = sne_s + NE;              // 10 * WTS

    size_t need = (size_t)((char*)(WT + 10 * WTS) - (char*)d_ws);  // ~264.6 MB
    if (ws_size < need) return;

    const int NB_N36 = (NN + 35) / 36;        // 2778
    const int NB_N9  = (NN + 8) / 9;          // 11112
    const int NB_E256 = (NE + 255) / 256;     // 3907
    const int NB_SC  = (NN + SCB - 1) / SCB;  // 196
    const int NB_E0  = (NE + CH0 - 1) / CH0;  // 1737
    const int NB_E2  = (NE + CH2 - 1) / CH2;  // 1985

    // zero: num/den + red + gsum + gcnt (contiguous) + CSR counts
    hipMemsetAsync(num, 0, (2 * NF + 4 * DD + NG * DD + NG) * sizeof(float), stream);
    hipMemsetAsync(off, 0, NN * sizeof(int), stream);

    // ---- weight transposes + CSR build ----
    k_trAll<<<dim3(70, 10), 72, 0, stream>>>(Wh, Wg, WT);
    k_count<<<NB_E256, 256, 0, stream>>>(dst, off);
    k_scan_a<<<NB_SC, SCB, 0, stream>>>(off, part);
    k_scan_b<<<1, 256, 0, stream>>>(part, NB_SC);
    k_scan_c<<<NB_SC, SCB, 0, stream>>>(off, part);
    k_fill<<<NB_E256, 256, 0, stream>>>(src, dst, ef, sne, off, src_s, ef_s, sne_s);

    k_pre<<<1, 128, 0, stream>>>(We, be, Wg, bg, v1, v2);
    k_dense_r<<<NB_N36, 640, 0, stream>>>(x, 64, WT + 0 * WTS, bh, B0, NN);

    // ---- layer 0 (params index 0) ----
    k_dense_r<<<NB_N36, 640, 0, stream>>>(B0, 70, WT + 1 * WTS, bg + 0 * 70, B2, NN);  // A
    k_dense_r<<<NB_N36, 640, 0, stream>>>(B0, 70, WT + 2 * WTS, bg + 1 * 70, B3, NN);  // B
    k_dense_r<<<NB_N36, 640, 0, stream>>>(B0, 70, WT + 3 * WTS, bg + 3 * 70, B4, NN);  // D
    k_dense_r<<<NB_N36, 640, 0, stream>>>(B0, 70, WT + 4 * WTS, bg + 4 * 70, B5, NN);  // E
    k_edge0<<<NB_E0, 640, 0, stream>>>(ef_s, sne_s, src_s, off, B3, B4, B5, v1, v2,
                                       num, den, red);
    k_stats<<<1, 128, 0, stream>>>(red, murs_e, 1.f / NE);
    k_nstats<<<2048, 640, 0, stream>>>(B2, num, den, snn, red + 2 * DD);
    k_stats<<<1, 128, 0, stream>>>(red + 2 * DD, murs_h, 1.f / NN);
    k_apply<<<(int)((NF + 255) / 256), 256, 0, stream>>>(B0, B2, num, den, snn, murs_h,
                                                         gh + 0, bbh + 0, B1);

    // ---- layer 2 (params index 2) ----
    hipMemsetAsync(num, 0, (2 * NF + 4 * DD) * sizeof(float), stream);  // num, den, red
    k_dense_r<<<NB_N36, 640, 0, stream>>>(B1, 70, WT + 5 * WTS, bg + 10 * 70, B2, NN); // A
    k_dense_r<<<NB_N36, 640, 0, stream>>>(B1, 70, WT + 6 * WTS, bg + 11 * 70, B3, NN); // B
    k_dense_r<<<NB_N36, 640, 0, stream>>>(B1, 70, WT + 7 * WTS, bg + 13 * 70, B0, NN); // D
    k_dense_r<<<NB_N36, 640, 0, stream>>>(B1, 70, WT + 8 * WTS, bg + 14 * 70, B6, NN); // E
    k_edge2<<<NB_E2, 640, 0, stream>>>(ef_s, sne_s, src_s, off, B4, B5, B3, B0, B6,
                                       v1, v2, murs_e, ge + 0, bbe + 0, We, be,
                                       WT + 9 * WTS, bg + 12 * 70, num, den);
    k_nstats<<<2048, 640, 0, stream>>>(B2, num, den, snn, red + 2 * DD);
    k_stats<<<1, 128, 0, stream>>>(red + 2 * DD, murs_h, 1.f / NN);
    k_apply<<<(int)((NF + 255) / 256), 256, 0, stream>>>(B1, B2, num, den, snn, murs_h,
                                                         gh + 2 * DD, bbh + 2 * DD, B0);

    // ---- readout ----
    k_readout<<<NB_N9, 640, 0, stream>>>(B0, gid, gsum, gcnt);
    k_out<<<(NG * DD + 255) / 256, 256, 0, stream>>>(gsum, gcnt, out);
}

// Round 11
// 1904.142 us; speedup vs baseline: 7.0667x; 1.1569x over previous
//
#include <hip/hip_runtime.h>

#define NN 100000
#define NE 1000000
#define NG 100
#define DD 70
#define EL0 64             // edges per slot in k_edge0
#define CH0 (9 * EL0)      // 576 edges per block
#define TPW 7              // 16-edge tiles per wave in k_edge2
#define EPW (16 * TPW)     // 112 edges per wave
#define EPB (10 * EPW)     // 1120 edges per block
#define SCB 512
#define WTS (70 * 72)      // one transposed weight matrix, padded

typedef __attribute__((ext_vector_type(8))) short bf16x8;
typedef __attribute__((ext_vector_type(4))) float f32x4;

__device__ __forceinline__ float sigmoidf_(float x) { return 1.f / (1.f + expf(-x)); }

__device__ __forceinline__ unsigned int rne_bf16(float x) {
    unsigned int u = __float_as_uint(x);
    return (u + 0x7FFFu + ((u >> 16) & 1u)) >> 16;
}

__device__ __forceinline__ int lower_off(const int* __restrict__ off, int e) {
    int lo = 0, hi = NN - 1;  // smallest n with off[n] > e  (off[n] = end(n))
    while (lo < hi) {
        int mid = (lo + hi) >> 1;
        if (off[mid] > e) hi = mid; else lo = mid + 1;
    }
    return lo;
}

#define DOT4(acc, vv, ww) { acc = fmaf((vv).x, (ww).x, acc); acc = fmaf((vv).y, (ww).y, acc); \
                            acc = fmaf((vv).z, (ww).z, acc); acc = fmaf((vv).w, (ww).w, acc); }

// ---------- transpose weight matrices into WT[m][70][72], zero-padded ----------
__global__ void k_trAll(const float* __restrict__ Wh, const float* __restrict__ Wg,
                        float* __restrict__ WT) {
    int m = blockIdx.y, f = blockIdx.x, k = threadIdx.x;
    const float* W;
    int K = DD;
    switch (m) {
        case 0: W = Wh; K = 64; break;
        case 1: W = Wg + 0 * 4900; break;
        case 2: W = Wg + 1 * 4900; break;
        case 3: W = Wg + 3 * 4900; break;
        case 4: W = Wg + 4 * 4900; break;
        case 5: W = Wg + 10 * 4900; break;
        case 6: W = Wg + 11 * 4900; break;
        case 7: W = Wg + 13 * 4900; break;
        default: W = Wg + 14 * 4900; break;
    }
    if (k < 72) WT[(m * 70 + f) * 72 + k] = (k < K) ? W[k * DD + f] : 0.f;
}

// ---------- skinny dense: 36-row tile, 4 rows/thread, 1 barrier ----------
__global__ __launch_bounds__(640) void k_dense_r(const float* __restrict__ x, int K,
                                                 const float* __restrict__ WTm,
                                                 const float* __restrict__ bias,
                                                 float* __restrict__ out, int nrows) {
    __shared__ float sx[36 * 72];
    int t = threadIdx.x;
    int r = t / DD, f = t - r * DD;
    long rb = (long)blockIdx.x * 36;
    for (int idx = t; idx < 36 * 72; idx += 640) {
        int rr = idx / 72, kk = idx - rr * 72;
        long i = rb + rr;
        sx[idx] = (kk < K && i < nrows) ? x[i * K + kk] : 0.f;
    }
    __syncthreads();
    if (r < 9) {
        const float4* wr = (const float4*)(WTm + f * 72);
        float bb = bias[f];
        float a0 = bb, a1 = bb, a2 = bb, a3 = bb;
        const float4* s0 = (const float4*)&sx[(r) * 72];
        const float4* s1 = (const float4*)&sx[(r + 9) * 72];
        const float4* s2 = (const float4*)&sx[(r + 18) * 72];
        const float4* s3 = (const float4*)&sx[(r + 27) * 72];
#pragma unroll 1
        for (int q = 0; q < 18; q += 2) {
            float4 wA = wr[q], wB = wr[q + 1];
            float4 vA0 = s0[q], vB0 = s0[q + 1];
            DOT4(a0, vA0, wA) DOT4(a0, vB0, wB)
            float4 vA1 = s1[q], vB1 = s1[q + 1];
            DOT4(a1, vA1, wA) DOT4(a1, vB1, wB)
            float4 vA2 = s2[q], vB2 = s2[q + 1];
            DOT4(a2, vA2, wA) DOT4(a2, vB2, wB)
            float4 vA3 = s3[q], vB3 = s3[q + 1];
            DOT4(a3, vA3, wA) DOT4(a3, vB3, wB)
        }
        long i0 = rb + r, i1 = i0 + 9, i2 = i0 + 18, i3 = i0 + 27;
        if (i0 < nrows) out[i0 * DD + f] = a0;
        if (i1 < nrows) out[i1 * DD + f] = a1;
        if (i2 < nrows) out[i2 * DD + f] = a2;
        if (i3 < nrows) out[i3 * DD + f] = a3;
    }
}

// ---------- v1 = We @ Wc0 ; v2 = be @ Wc0 + bc0 ----------
__global__ void k_pre(const float* __restrict__ We, const float* __restrict__ be,
                      const float* __restrict__ Wg, const float* __restrict__ bg,
                      float* __restrict__ v1, float* __restrict__ v2) {
    int f = threadIdx.x;
    if (f < DD) {
        const float* W2 = Wg + 2 * DD * DD;
        const float* b2 = bg + 2 * DD;
        float a = 0.f, c = 0.f;
        for (int k = 0; k < DD; ++k) {
            a = fmaf(We[k], W2[k * DD + f], a);
            c = fmaf(be[k], W2[k * DD + f], c);
        }
        v1[f] = a;
        v2[f] = c + b2[f];
    }
}

// ---------- prep for MFMA edge2: CT2 staging constants + WB B-fragments (bf16) ----------
__global__ void k_prep2(const float* __restrict__ v1, const float* __restrict__ v2,
                        const float* __restrict__ murs_e, const float* __restrict__ ge,
                        const float* __restrict__ bbe, const float* __restrict__ We,
                        const float* __restrict__ be, const float* __restrict__ Wg,
                        float* __restrict__ CT2, unsigned short* __restrict__ WB) {
    int t = threadIdx.x;  // 512 threads, 1 block
    if (t < 35) {
        int f0 = 2 * t, f1 = 2 * t + 1;
        float A0 = murs_e[DD + f0] * ge[f0], A1 = murs_e[DD + f1] * ge[f1];
        float* c = CT2 + t * 12;
        c[0] = v1[f0];  c[1] = v1[f1];
        c[2] = v2[f0];  c[3] = v2[f1];
        c[4] = A0;      c[5] = A1;
        c[6] = bbe[f0] - murs_e[f0] * A0;
        c[7] = bbe[f1] - murs_e[f1] * A1;
        c[8] = We[f0];  c[9] = We[f1];
        c[10] = be[f0]; c[11] = be[f1];
    }
    const float* WC2 = Wg + 12 * 4900;
    for (int idx = t; idx < 960; idx += 512) {
        int nt = idx / 192, rem = idx - nt * 192;
        int c = rem / 64, l = rem - c * 64;
        int n = nt * 16 + (l & 15);
        int kb = c * 32 + (l >> 4) * 8;
        for (int j = 0; j < 8; ++j) {
            int k = kb + j;
            unsigned short v = 0;
            if (k < 70 && n < 70) v = (unsigned short)rne_bf16(WC2[k * 70 + n]);
            WB[((nt * 3 + c) * 64 + l) * 8 + j] = v;
        }
    }
}

// ---------- CSR build: count / scan / fill ----------
__global__ void k_count(const int* __restrict__ dst, int* __restrict__ off) {
    int j = blockIdx.x * 256 + threadIdx.x;
    if (j < NE) atomicAdd(&off[dst[j]], 1);
}

__global__ void k_scan_a(int* __restrict__ off, int* __restrict__ part) {
    __shared__ int s[SCB];
    int t = threadIdx.x, i = blockIdx.x * SCB + t;
    int v = (i < NN) ? off[i] : 0;
    s[t] = v;
    __syncthreads();
    for (int d = 1; d < SCB; d <<= 1) {
        int x = (t >= d) ? s[t - d] : 0;
        __syncthreads();
        s[t] += x;
        __syncthreads();
    }
    if (i < NN) off[i] = s[t] - v;
    if (t == SCB - 1) part[blockIdx.x] = s[t];
}

__global__ void k_scan_b(int* __restrict__ part, int nb) {
    __shared__ int s[256];
    int t = threadIdx.x;
    int v = (t < nb) ? part[t] : 0;
    s[t] = v;
    __syncthreads();
    for (int d = 1; d < 256; d <<= 1) {
        int x = (t >= d) ? s[t - d] : 0;
        __syncthreads();
        s[t] += x;
        __syncthreads();
    }
    if (t < nb) part[t] = s[t] - v;
}

__global__ void k_scan_c(int* __restrict__ off, const int* __restrict__ part) {
    int i = blockIdx.x * SCB + threadIdx.x;
    if (i < NN) off[i] += part[blockIdx.x];
}

__global__ void k_fill(const int* __restrict__ src, const int* __restrict__ dst,
                       const float* __restrict__ ef, const float* __restrict__ sne,
                       int* __restrict__ off, int* __restrict__ src_s,
                       float* __restrict__ ef_s, float* __restrict__ sne_s) {
    int j = blockIdx.x * 256 + threadIdx.x;
    if (j < NE) {
        int d = dst[j];
        int pos = atomicAdd(&off[d], 1);  // off becomes shifted: off[n] = end(n)
        src_s[pos] = src[j];
        ef_s[pos] = ef[j];
        sne_s[pos] = sne[j];
    }
}

// ---------- layer-0 edge pass: edge-centric, 4-wide gather batching ----------
__global__ __launch_bounds__(640) void k_edge0(
    const float* __restrict__ ef_s, const float* __restrict__ sne_s,
    const int* __restrict__ src_s, const int* __restrict__ off,
    const float* __restrict__ PB, const float* __restrict__ PD,
    const float* __restrict__ PE, const float* __restrict__ v1,
    const float* __restrict__ v2, float* __restrict__ num,
    float* __restrict__ den, float* __restrict__ red) {
    int t = threadIdx.x;
    int r = t / DD, f = t - r * DD;
    bool act = (r < 9);
    float c1 = 0.f, c2 = 0.f;
    if (act) { c1 = v1[f]; c2 = v2[f]; }
    float acc_s = 0.f, acc_q = 0.f;
    int e_beg = blockIdx.x * CH0 + r * EL0;
    bool live = act && e_beg < NE;
    int n = 0;
    float pe = 0.f, accn = 0.f, accd = 0.f;
    int lim = 0;
    if (live) {
        n = lower_off(off, e_beg);
        pe = PE[(long)n * DD + f];
        lim = NE - e_beg;
        if (lim > EL0) lim = EL0;
    }
    for (int g = 0; g < lim; g += 4) {
        int m = lim - g;
        if (m > 4) m = 4;
        float pdj[4], pbj[4], efj[4], snj[4];
#pragma unroll
        for (int j = 0; j < 4; ++j) {
            if (j < m) {
                int e = e_beg + g + j;
                int s = src_s[e];
                efj[j] = ef_s[e];
                snj[j] = sne_s[e];
                pdj[j] = PD[(long)s * DD + f];
                pbj[j] = PB[(long)s * DD + f];
            }
        }
#pragma unroll
        for (int j = 0; j < 4; ++j) {
            if (j < m) {
                int e = e_beg + g + j;
                if (e >= off[n]) {
                    unsafeAtomicAdd(&num[(long)n * DD + f], accn);
                    unsafeAtomicAdd(&den[(long)n * DD + f], accd);
                    accn = 0.f; accd = 0.f;
                    do { ++n; } while (off[n] <= e);
                    pe = PE[(long)n * DD + f];
                }
                float en = pdj[j] + pe + efj[j] * c1 + c2;
                float sg = sigmoidf_(en);
                accn = fmaf(sg, pbj[j], accn);
                accd += sg;
                float tv = en * snj[j];
                acc_s += tv;
                acc_q = fmaf(tv, tv, acc_q);
            }
        }
    }
    if (live) {
        unsafeAtomicAdd(&num[(long)n * DD + f], accn);
        unsafeAtomicAdd(&den[(long)n * DD + f], accd);
    }
    __shared__ float ss[DD], sq[DD];
    if (t < DD) { ss[t] = 0.f; sq[t] = 0.f; }
    __syncthreads();
    if (act) { atomicAdd(&ss[f], acc_s); atomicAdd(&sq[f], acc_q); }
    __syncthreads();
    if (t < DD) {
        atomicAdd(&red[t], ss[t]);
        atomicAdd(&red[DD + t], sq[t]);
    }
}

// ---------- layer-2 edge kernel: MFMA bf16, per-wave independent, no barriers ----------
__global__ __launch_bounds__(640) void k_edge2(
    const float* __restrict__ ef_s, const float* __restrict__ sne_s,
    const int* __restrict__ src_s, const int* __restrict__ off,
    const float* __restrict__ PD0, const float* __restrict__ PE0,
    const float* __restrict__ PB2, const float* __restrict__ PD2,
    const float* __restrict__ PE2, const float* __restrict__ CT2,
    const unsigned short* __restrict__ WB, const float* __restrict__ bC2,
    float* __restrict__ num, float* __restrict__ den) {
    __shared__ __align__(16) unsigned short As[10 * 16 * 104];
    int t = threadIdx.x;
    int w = t >> 6, l = t & 63;
    unsigned short* Aw = &As[w * 1664];
    // zero own wave region once (pads beyond k=70 must stay 0)
    for (int i = l; i < 832; i += 64) ((unsigned int*)Aw)[i] = 0u;
    int wb_e = blockIdx.x * EPB + w * EPW;
    if (wb_e >= NE) return;
    int col = l & 15, hi = l >> 4;
    // B fragments: loaded once, compile-time indexed
    bf16x8 bfr[15];
#pragma unroll
    for (int q = 0; q < 15; ++q)
        bfr[q] = *(const bf16x8*)(WB + (q * 64 + l) * 8);
    float bc[5];
#pragma unroll
    for (int nt = 0; nt < 5; ++nt) bc[nt] = bC2[nt * 16 + col];
    // staging run pointer (per lane, monotone)
    int e0s = wb_e + (l / 35);
    if (e0s > NE - 1) e0s = NE - 1;
    int ns = lower_off(off, e0s);
    // epilogue run pointer (per lane, monotone)
    int e0p = wb_e + hi * 4;
    if (e0p > NE - 1) e0p = NE - 1;
    int np = lower_off(off, e0p);
    float pe2c[5], an[5], ad[5];
#pragma unroll
    for (int nt = 0; nt < 5; ++nt) {
        pe2c[nt] = PE2[(long)np * DD + nt * 16 + col];
        an[nt] = 0.f; ad[nt] = 0.f;
    }
    for (int tt = 0; tt < TPW; ++tt) {
        int et = wb_e + tt * 16;
        if (et >= NE) break;
        // ---- stage 16 e1-rows as bf16 into own LDS tile ----
        for (int i = l; i < 560; i += 64) {
            int el = i / 35, fp = i - el * 35, f = fp * 2;
            int e = et + el;
            unsigned int val = 0u;
            if (e < NE) {
                while (off[ns] <= e) ++ns;  // d = ns
                int s = src_s[e];
                float efv = ef_s[e], sn = sne_s[e];
                const float* ct = CT2 + fp * 12;
                float2 pd = *(const float2*)(PD0 + (long)s * DD + f);
                float2 pe = *(const float2*)(PE0 + (long)ns * DD + f);
                float en0a = pd.x + pe.x + efv * ct[0] + ct[2];
                float en0b = pd.y + pe.y + efv * ct[1] + ct[3];
                float ra = fmaxf(fmaf(en0a * sn, ct[4], ct[6]), 0.f);
                float rb = fmaxf(fmaf(en0b * sn, ct[5], ct[7]), 0.f);
                float e1a = fmaf(efv, ct[8], ct[10]) + ra;
                float e1b = fmaf(efv, ct[9], ct[11]) + rb;
                val = rne_bf16(e1a) | (rne_bf16(e1b) << 16);
            }
            ((unsigned int*)Aw)[(el * 104 + f) >> 1] = val;
        }
        // ---- A fragments + 15 MFMAs ----
        bf16x8 af[3];
#pragma unroll
        for (int c = 0; c < 3; ++c)
            af[c] = *(const bf16x8*)(Aw + (l & 15) * 104 + c * 32 + hi * 8);
        f32x4 acc[5];
#pragma unroll
        for (int nt = 0; nt < 5; ++nt) {
            acc[nt] = (f32x4){0.f, 0.f, 0.f, 0.f};
#pragma unroll
            for (int c = 0; c < 3; ++c)
                acc[nt] = __builtin_amdgcn_mfma_f32_16x16x32_bf16(af[c], bfr[nt * 3 + c],
                                                                  acc[nt], 0, 0, 0);
        }
        // ---- epilogue: D layout col=lane&15, row=(lane>>4)*4+reg ----
#pragma unroll
        for (int j = 0; j < 4; ++j) {
            int e = et + hi * 4 + j;
            if (e < NE) {
                if (e >= off[np]) {
#pragma unroll
                    for (int nt = 0; nt < 5; ++nt) {
                        int nv = nt * 16 + col;
                        if (nv < 70) {
                            unsafeAtomicAdd(&num[(long)np * DD + nv], an[nt]);
                            unsafeAtomicAdd(&den[(long)np * DD + nv], ad[nt]);
                        }
                        an[nt] = 0.f; ad[nt] = 0.f;
                    }
                    do { ++np; } while (off[np] <= e);
#pragma unroll
                    for (int nt = 0; nt < 5; ++nt)
                        pe2c[nt] = PE2[(long)np * DD + nt * 16 + col];
                }
                int s = src_s[e];
#pragma unroll
                for (int nt = 0; nt < 5; ++nt) {
                    int nv = nt * 16 + col;
                    if (nv < 70) {
                        float en = acc[nt][j] + bc[nt] + PD2[(long)s * DD + nv] + pe2c[nt];
                        float sg = sigmoidf_(en);
                        an[nt] = fmaf(sg, PB2[(long)s * DD + nv], an[nt]);
                        ad[nt] += sg;
                    }
                }
            }
        }
    }
#pragma unroll
    for (int nt = 0; nt < 5; ++nt) {
        int nv = nt * 16 + col;
        if (nv < 70) {
            unsafeAtomicAdd(&num[(long)np * DD + nv], an[nt]);
            unsafeAtomicAdd(&den[(long)np * DD + nv], ad[nt]);
        }
    }
}

// ---------- node BN stats: grid-stride, reg-accum ----------
__global__ __launch_bounds__(640) void k_nstats(const float* __restrict__ PA,
                                                const float* __restrict__ num,
                                                const float* __restrict__ den,
                                                const float* __restrict__ snn,
                                                float* __restrict__ red) {
    int t = threadIdx.x;
    int r = t / DD, f = t - r * DD;
    bool act = (r < 9);
    float acc_s = 0.f, acc_q = 0.f;
    const int T = (NN + 8) / 9;
    for (int tile = blockIdx.x; tile < T; tile += gridDim.x) {
        int i = tile * 9 + r;
        if (act && i < NN) {
            long o = (long)i * DD + f;
            float v = (PA[o] + num[o] / (den[o] + 1e-6f)) * snn[i];
            acc_s += v;
            acc_q = fmaf(v, v, acc_q);
        }
    }
    __shared__ float ss[DD], sq[DD];
    if (t < DD) { ss[t] = 0.f; sq[t] = 0.f; }
    __syncthreads();
    if (act) { atomicAdd(&ss[f], acc_s); atomicAdd(&sq[f], acc_q); }
    __syncthreads();
    if (t < DD) {
        atomicAdd(&red[t], ss[t]);
        atomicAdd(&red[DD + t], sq[t]);
    }
}

// ---------- finalize BN stats ----------
__global__ void k_stats(const float* __restrict__ sums, float* __restrict__ murs, float invn) {
    int f = threadIdx.x;
    if (f < DD) {
        float mu = sums[f] * invn;
        float var = sums[DD + f] * invn - mu * mu;
        murs[f] = mu;
        murs[DD + f] = rsqrtf(var + 1e-5f);
    }
}

// ---------- recompute v, BN-apply + relu + residual ----------
__global__ __launch_bounds__(256) void k_apply(const float* __restrict__ hin,
                                               const float* __restrict__ PA,
                                               const float* __restrict__ num,
                                               const float* __restrict__ den,
                                               const float* __restrict__ snn,
                                               const float* __restrict__ murs,
                                               const float* __restrict__ g,
                                               const float* __restrict__ b,
                                               float* __restrict__ hout) {
    long idx = (long)blockIdx.x * 256 + threadIdx.x;
    if (idx < (long)NN * DD) {
        int i = (int)(idx / DD);
        int f = (int)(idx - (long)i * DD);
        float v = (PA[idx] + num[idx] / (den[idx] + 1e-6f)) * snn[i];
        float bnv = (v - murs[f]) * murs[DD + f] * g[f] + b[f];
        hout[idx] = hin[idx] + fmaxf(bnv, 0.f);
    }
}

// ---------- per-graph sums ----------
__global__ __launch_bounds__(640) void k_readout(const float* __restrict__ h,
                                                 const int* __restrict__ gid,
                                                 float* __restrict__ gsum,
                                                 float* __restrict__ gcnt) {
    __shared__ float sv[9 * DD];
    __shared__ int sg_[9];
    int t = threadIdx.x;
    int r = t / DD, f = t - r * DD;
    int i = blockIdx.x * 9 + r;
    if (r < 9 && i < NN) {
        sv[r * DD + f] = h[(long)i * DD + f];
        if (f == 0) sg_[r] = gid[i];
    }
    __syncthreads();
    int nvalid = NN - blockIdx.x * 9;
    if (nvalid > 9) nvalid = 9;
    if (t < DD && nvalid > 0) {
        float acc = 0.f;
        int cur = sg_[0];
        for (int rr = 0; rr < nvalid; ++rr) {
            int g = sg_[rr];
            if (g != cur) {
                unsafeAtomicAdd(&gsum[cur * DD + t], acc);
                acc = 0.f;
                cur = g;
            }
            acc += sv[rr * DD + t];
        }
        unsafeAtomicAdd(&gsum[cur * DD + t], acc);
        if (t == 0) {
            int cnt = 0;
            cur = sg_[0];
            for (int rr = 0; rr < nvalid; ++rr) {
                if (sg_[rr] != cur) {
                    unsafeAtomicAdd(&gcnt[cur], (float)cnt);
                    cnt = 0;
                    cur = sg_[rr];
                }
                cnt++;
            }
            unsafeAtomicAdd(&gcnt[cur], (float)cnt);
        }
    }
}

__global__ void k_out(const float* __restrict__ gsum, const float* __restrict__ gcnt,
                      float* __restrict__ out) {
    int idx = blockIdx.x * 256 + threadIdx.x;
    if (idx < NG * DD) {
        int g = idx / DD;
        out[idx] = gsum[idx] / fmaxf(gcnt[g], 1.f);
    }
}

extern "C" void kernel_launch(void* const* d_in, const int* in_sizes, int n_in,
                              void* d_out, int out_size, void* d_ws, size_t ws_size,
                              hipStream_t stream) {
    const float* x   = (const float*)d_in[0];
    const float* ef  = (const float*)d_in[1];
    const float* snn = (const float*)d_in[2];
    const float* sne = (const float*)d_in[3];
    const int*   src = (const int*)d_in[4];
    const int*   dst = (const int*)d_in[5];
    const int*   gid = (const int*)d_in[6];
    const float* Wh  = (const float*)d_in[7];
    const float* bh  = (const float*)d_in[8];
    const float* We  = (const float*)d_in[9];
    const float* be  = (const float*)d_in[10];
    const float* Wg  = (const float*)d_in[11];
    const float* bg  = (const float*)d_in[12];
    const float* gh  = (const float*)d_in[13];
    const float* bbh = (const float*)d_in[14];
    const float* ge  = (const float*)d_in[15];
    const float* bbe = (const float*)d_in[16];
    float* out = (float*)d_out;

    const size_t NF = (size_t)NN * DD;  // 7,000,000

    float* ws = (float*)d_ws;
    float* B0 = ws;            // h0 -> PD2 -> h_final
    float* B1 = B0 + NF;       // h1
    float* B2 = B1 + NF;       // PA / PA2
    float* B3 = B2 + NF;       // PB / PB2
    float* B4 = B3 + NF;       // PD0 (kept through k_edge2)
    float* B5 = B4 + NF;       // PE0 (kept through k_edge2)
    float* B6 = B5 + NF;       // PE2
    float* num = B6 + NF;      // NF
    float* den = num + NF;     // NF
    float* red  = den + NF;        // 4*DD
    float* gsum = red + 4 * DD;    // NG*DD
    float* gcnt = gsum + NG * DD;  // NG
    float* v1 = gcnt + NG;
    float* v2 = v1 + DD;
    float* murs_e = v2 + DD;       // 2*DD
    float* murs_h = murs_e + 2 * DD;
    int* off   = (int*)(murs_h + 2 * DD);  // NN
    int* part  = off + NN;                  // 256
    int* src_s = part + 256;                // NE
    float* ef_s  = (float*)(src_s + NE);    // NE
    float* sne_s = ef_s + NE;               // NE
    float* WT    = sne_s + NE;              // 10 * WTS
    uintptr_t pal = ((uintptr_t)(WT + 10 * WTS) + 15) & ~(uintptr_t)15;
    float* CT2 = (float*)pal;                        // 420 floats (16B-aligned)
    unsigned short* WB = (unsigned short*)(CT2 + 420);  // 7680 u16 (16B-aligned)

    size_t need = (size_t)((char*)(WB + 7680) - (char*)d_ws);  // ~264.6 MB
    if (ws_size < need) return;

    const int NB_N36 = (NN + 35) / 36;        // 2778
    const int NB_N9  = (NN + 8) / 9;          // 11112
    const int NB_E256 = (NE + 255) / 256;     // 3907
    const int NB_SC  = (NN + SCB - 1) / SCB;  // 196
    const int NB_E0  = (NE + CH0 - 1) / CH0;  // 1737
    const int NB_E2  = (NE + EPB - 1) / EPB;  // 893

    hipMemsetAsync(num, 0, (2 * NF + 4 * DD + NG * DD + NG) * sizeof(float), stream);
    hipMemsetAsync(off, 0, NN * sizeof(int), stream);

    // ---- weight transposes + CSR build ----
    k_trAll<<<dim3(70, 9), 72, 0, stream>>>(Wh, Wg, WT);
    k_count<<<NB_E256, 256, 0, stream>>>(dst, off);
    k_scan_a<<<NB_SC, SCB, 0, stream>>>(off, part);
    k_scan_b<<<1, 256, 0, stream>>>(part, NB_SC);
    k_scan_c<<<NB_SC, SCB, 0, stream>>>(off, part);
    k_fill<<<NB_E256, 256, 0, stream>>>(src, dst, ef, sne, off, src_s, ef_s, sne_s);

    k_pre<<<1, 128, 0, stream>>>(We, be, Wg, bg, v1, v2);
    k_dense_r<<<NB_N36, 640, 0, stream>>>(x, 64, WT + 0 * WTS, bh, B0, NN);

    // ---- layer 0 (params index 0) ----
    k_dense_r<<<NB_N36, 640, 0, stream>>>(B0, 70, WT + 1 * WTS, bg + 0 * 70, B2, NN);  // A
    k_dense_r<<<NB_N36, 640, 0, stream>>>(B0, 70, WT + 2 * WTS, bg + 1 * 70, B3, NN);  // B
    k_dense_r<<<NB_N36, 640, 0, stream>>>(B0, 70, WT + 3 * WTS, bg + 3 * 70, B4, NN);  // D
    k_dense_r<<<NB_N36, 640, 0, stream>>>(B0, 70, WT + 4 * WTS, bg + 4 * 70, B5, NN);  // E
    k_edge0<<<NB_E0, 640, 0, stream>>>(ef_s, sne_s, src_s, off, B3, B4, B5, v1, v2,
                                       num, den, red);
    k_stats<<<1, 128, 0, stream>>>(red, murs_e, 1.f / NE);
    k_prep2<<<1, 512, 0, stream>>>(v1, v2, murs_e, ge + 0, bbe + 0, We, be, Wg, CT2, WB);
    k_nstats<<<2048, 640, 0, stream>>>(B2, num, den, snn, red + 2 * DD);
    k_stats<<<1, 128, 0, stream>>>(red + 2 * DD, murs_h, 1.f / NN);
    k_apply<<<(int)((NF + 255) / 256), 256, 0, stream>>>(B0, B2, num, den, snn, murs_h,
                                                         gh + 0, bbh + 0, B1);

    // ---- layer 2 (params index 2) ----
    hipMemsetAsync(num, 0, (2 * NF + 4 * DD) * sizeof(float), stream);  // num, den, red
    k_dense_r<<<NB_N36, 640, 0, stream>>>(B1, 70, WT + 5 * WTS, bg + 10 * 70, B2, NN); // A
    k_dense_r<<<NB_N36, 640, 0, stream>>>(B1, 70, WT + 6 * WTS, bg + 11 * 70, B3, NN); // B
    k_dense_r<<<NB_N36, 640, 0, stream>>>(B1, 70, WT + 7 * WTS, bg + 13 * 70, B0, NN); // D
    k_dense_r<<<NB_N36, 640, 0, stream>>>(B1, 70, WT + 8 * WTS, bg + 14 * 70, B6, NN); // E
    k_edge2<<<NB_E2, 640, 0, stream>>>(ef_s, sne_s, src_s, off, B4, B5, B3, B0, B6,
                                       CT2, WB, bg + 12 * 70, num, den);
    k_nstats<<<2048, 640, 0, stream>>>(B2, num, den, snn, red + 2 * DD);
    k_stats<<<1, 128, 0, stream>>>(red + 2 * DD, murs_h, 1.f / NN);
    k_apply<<<(int)((NF + 255) / 256), 256, 0, stream>>>(B1, B2, num, den, snn, murs_h,
                                                         gh + 2 * DD, bbh + 2 * DD, B0);

    // ---- readout ----
    k_readout<<<NB_N9, 640, 0, stream>>>(B0, gid, gsum, gcnt);
    k_out<<<(NG * DD + 255) / 256, 256, 0, stream>>>(gsum, gcnt, out);
}

// Round 13
// 1746.496 us; speedup vs baseline: 7.7046x; 1.0903x over previous
//
#include <hip/hip_runtime.h>

#define NN 100000
#define NE 1000000
#define NG 100
#define DD 70
#define EL0 64             // edges per slot in k_edge0
#define CH0 (9 * EL0)      // 576 edges per block
#define TPW 5              // 16-edge tiles per wave in k_edge2
#define EPW (16 * TPW)     // 80 edges per wave
#define EPB (10 * EPW)     // 800 edges per block
#define SCB 512
#define WTS (70 * 72)      // one transposed weight matrix, padded

typedef __attribute__((ext_vector_type(8))) short bf16x8;
typedef __attribute__((ext_vector_type(4))) float f32x4;

__device__ __forceinline__ float sigmoidf_(float x) { return 1.f / (1.f + expf(-x)); }

__device__ __forceinline__ unsigned int rne_bf16(float x) {
    unsigned int u = __float_as_uint(x);
    return (u + 0x7FFFu + ((u >> 16) & 1u)) >> 16;
}

#define DOT4(acc, vv, ww) { acc = fmaf((vv).x, (ww).x, acc); acc = fmaf((vv).y, (ww).y, acc); \
                            acc = fmaf((vv).z, (ww).z, acc); acc = fmaf((vv).w, (ww).w, acc); }

// ---------- transpose weight matrices into WT[m][70][72], zero-padded ----------
__global__ void k_trAll(const float* __restrict__ Wh, const float* __restrict__ Wg,
                        float* __restrict__ WT) {
    int m = blockIdx.y, f = blockIdx.x, k = threadIdx.x;
    const float* W;
    int K = DD;
    switch (m) {
        case 0: W = Wh; K = 64; break;
        case 1: W = Wg + 0 * 4900; break;
        case 2: W = Wg + 1 * 4900; break;
        case 3: W = Wg + 3 * 4900; break;
        case 4: W = Wg + 4 * 4900; break;
        case 5: W = Wg + 10 * 4900; break;
        case 6: W = Wg + 11 * 4900; break;
        case 7: W = Wg + 13 * 4900; break;
        default: W = Wg + 14 * 4900; break;
    }
    if (k < 72) WT[(m * 70 + f) * 72 + k] = (k < K) ? W[k * DD + f] : 0.f;
}

// ---------- skinny dense: 36-row tile, 4 rows/thread, 1 barrier ----------
__global__ __launch_bounds__(640) void k_dense_r(const float* __restrict__ x, int K,
                                                 const float* __restrict__ WTm,
                                                 const float* __restrict__ bias,
                                                 float* __restrict__ out, int nrows) {
    __shared__ float sx[36 * 72];
    int t = threadIdx.x;
    int r = t / DD, f = t - r * DD;
    long rb = (long)blockIdx.x * 36;
    for (int idx = t; idx < 36 * 72; idx += 640) {
        int rr = idx / 72, kk = idx - rr * 72;
        long i = rb + rr;
        sx[idx] = (kk < K && i < nrows) ? x[i * K + kk] : 0.f;
    }
    __syncthreads();
    if (r < 9) {
        const float4* wr = (const float4*)(WTm + f * 72);
        float bb = bias[f];
        float a0 = bb, a1 = bb, a2 = bb, a3 = bb;
        const float4* s0 = (const float4*)&sx[(r) * 72];
        const float4* s1 = (const float4*)&sx[(r + 9) * 72];
        const float4* s2 = (const float4*)&sx[(r + 18) * 72];
        const float4* s3 = (const float4*)&sx[(r + 27) * 72];
#pragma unroll 1
        for (int q = 0; q < 18; q += 2) {
            float4 wA = wr[q], wB = wr[q + 1];
            float4 vA0 = s0[q], vB0 = s0[q + 1];
            DOT4(a0, vA0, wA) DOT4(a0, vB0, wB)
            float4 vA1 = s1[q], vB1 = s1[q + 1];
            DOT4(a1, vA1, wA) DOT4(a1, vB1, wB)
            float4 vA2 = s2[q], vB2 = s2[q + 1];
            DOT4(a2, vA2, wA) DOT4(a2, vB2, wB)
            float4 vA3 = s3[q], vB3 = s3[q + 1];
            DOT4(a3, vA3, wA) DOT4(a3, vB3, wB)
        }
        long i0 = rb + r, i1 = i0 + 9, i2 = i0 + 18, i3 = i0 + 27;
        if (i0 < nrows) out[i0 * DD + f] = a0;
        if (i1 < nrows) out[i1 * DD + f] = a1;
        if (i2 < nrows) out[i2 * DD + f] = a2;
        if (i3 < nrows) out[i3 * DD + f] = a3;
    }
}

// ---------- v1 = We @ Wc0 ; v2 = be @ Wc0 + bc0 ----------
__global__ void k_pre(const float* __restrict__ We, const float* __restrict__ be,
                      const float* __restrict__ Wg, const float* __restrict__ bg,
                      float* __restrict__ v1, float* __restrict__ v2) {
    int f = threadIdx.x;
    if (f < DD) {
        const float* W2 = Wg + 2 * DD * DD;
        const float* b2 = bg + 2 * DD;
        float a = 0.f, c = 0.f;
        for (int k = 0; k < DD; ++k) {
            a = fmaf(We[k], W2[k * DD + f], a);
            c = fmaf(be[k], W2[k * DD + f], c);
        }
        v1[f] = a;
        v2[f] = c + b2[f];
    }
}

// ---------- prep for MFMA edge2: CT2 staging constants + WB B-fragments (bf16) ----------
__global__ void k_prep2(const float* __restrict__ v1, const float* __restrict__ v2,
                        const float* __restrict__ murs_e, const float* __restrict__ ge,
                        const float* __restrict__ bbe, const float* __restrict__ We,
                        const float* __restrict__ be, const float* __restrict__ Wg,
                        float* __restrict__ CT2, unsigned short* __restrict__ WB) {
    int t = threadIdx.x;  // 512 threads, 1 block
    if (t < 35) {
        int f0 = 2 * t, f1 = 2 * t + 1;
        float A0 = murs_e[DD + f0] * ge[f0], A1 = murs_e[DD + f1] * ge[f1];
        float* c = CT2 + t * 12;
        c[0] = v1[f0];  c[1] = v1[f1];
        c[2] = v2[f0];  c[3] = v2[f1];
        c[4] = A0;      c[5] = A1;
        c[6] = bbe[f0] - murs_e[f0] * A0;
        c[7] = bbe[f1] - murs_e[f1] * A1;
        c[8] = We[f0];  c[9] = We[f1];
        c[10] = be[f0]; c[11] = be[f1];
    }
    const float* WC2 = Wg + 12 * 4900;
    for (int idx = t; idx < 960; idx += 512) {
        int nt = idx / 192, rem = idx - nt * 192;
        int c = rem / 64, l = rem - c * 64;
        int n = nt * 16 + (l & 15);
        int kb = c * 32 + (l >> 4) * 8;
        for (int j = 0; j < 8; ++j) {
            int k = kb + j;
            unsigned short v = 0;
            if (k < 70 && n < 70) v = (unsigned short)rne_bf16(WC2[k * 70 + n]);
            WB[((nt * 3 + c) * 64 + l) * 8 + j] = v;
        }
    }
}

// ---------- CSR build: count / scan / fill ----------
__global__ void k_count(const int* __restrict__ dst, int* __restrict__ off) {
    int j = blockIdx.x * 256 + threadIdx.x;
    if (j < NE) atomicAdd(&off[dst[j]], 1);
}

__global__ void k_scan_a(int* __restrict__ off, int* __restrict__ part) {
    __shared__ int s[SCB];
    int t = threadIdx.x, i = blockIdx.x * SCB + t;
    int v = (i < NN) ? off[i] : 0;
    s[t] = v;
    __syncthreads();
    for (int d = 1; d < SCB; d <<= 1) {
        int x = (t >= d) ? s[t - d] : 0;
        __syncthreads();
        s[t] += x;
        __syncthreads();
    }
    if (i < NN) off[i] = s[t] - v;
    if (t == SCB - 1) part[blockIdx.x] = s[t];
}

__global__ void k_scan_b(int* __restrict__ part, int nb) {
    __shared__ int s[256];
    int t = threadIdx.x;
    int v = (t < nb) ? part[t] : 0;
    s[t] = v;
    __syncthreads();
    for (int d = 1; d < 256; d <<= 1) {
        int x = (t >= d) ? s[t - d] : 0;
        __syncthreads();
        s[t] += x;
        __syncthreads();
    }
    if (t < nb) part[t] = s[t] - v;
}

__global__ void k_scan_c(int* __restrict__ off, const int* __restrict__ part) {
    int i = blockIdx.x * SCB + threadIdx.x;
    if (i < NN) off[i] += part[blockIdx.x];
}

__global__ void k_fill(const int* __restrict__ src, const int* __restrict__ dst,
                       const float* __restrict__ ef, const float* __restrict__ sne,
                       int* __restrict__ off, int* __restrict__ src_s,
                       float* __restrict__ ef_s, float* __restrict__ sne_s,
                       int* __restrict__ dst_s) {
    int j = blockIdx.x * 256 + threadIdx.x;
    if (j < NE) {
        int d = dst[j];
        int pos = atomicAdd(&off[d], 1);
        src_s[pos] = src[j];
        ef_s[pos] = ef[j];
        sne_s[pos] = sne[j];
        dst_s[pos] = d;
    }
}

// ---------- layer-0 edge pass: edge-centric, dst_s compare-flush (no CSR walks) ----------
__global__ __launch_bounds__(640) void k_edge0(
    const float* __restrict__ ef_s, const float* __restrict__ sne_s,
    const int* __restrict__ src_s, const int* __restrict__ dst_s,
    const float* __restrict__ PB, const float* __restrict__ PD,
    const float* __restrict__ PE, const float* __restrict__ v1,
    const float* __restrict__ v2, float* __restrict__ num,
    float* __restrict__ den, float* __restrict__ red) {
    int t = threadIdx.x;
    int r = t / DD, f = t - r * DD;
    bool act = (r < 9);
    float c1 = 0.f, c2 = 0.f;
    if (act) { c1 = v1[f]; c2 = v2[f]; }
    float acc_s = 0.f, acc_q = 0.f;
    int e_beg = blockIdx.x * CH0 + r * EL0;
    bool live = act && e_beg < NE;
    int dcur = 0;
    float accn = 0.f, accd = 0.f;
    int lim = 0;
    if (live) {
        dcur = dst_s[e_beg];
        lim = NE - e_beg;
        if (lim > EL0) lim = EL0;
    }
    for (int g = 0; g < lim; g += 4) {
        int m = lim - g;
        if (m > 4) m = 4;
        int dj[4];
        float pdj[4], pbj[4], pej[4], efj[4], snj[4];
#pragma unroll
        for (int j = 0; j < 4; ++j) {
            if (j < m) {
                int e = e_beg + g + j;
                int s = src_s[e];
                int d = dst_s[e];
                dj[j] = d;
                efj[j] = ef_s[e];
                snj[j] = sne_s[e];
                pdj[j] = PD[(long)s * DD + f];
                pbj[j] = PB[(long)s * DD + f];
                pej[j] = PE[(long)d * DD + f];
            }
        }
#pragma unroll
        for (int j = 0; j < 4; ++j) {
            if (j < m) {
                if (dj[j] != dcur) {
                    unsafeAtomicAdd(&num[(long)dcur * DD + f], accn);
                    unsafeAtomicAdd(&den[(long)dcur * DD + f], accd);
                    accn = 0.f; accd = 0.f;
                    dcur = dj[j];
                }
                float en = pdj[j] + pej[j] + efj[j] * c1 + c2;
                float sg = sigmoidf_(en);
                accn = fmaf(sg, pbj[j], accn);
                accd += sg;
                float tv = en * snj[j];
                acc_s += tv;
                acc_q = fmaf(tv, tv, acc_q);
            }
        }
    }
    if (live) {
        unsafeAtomicAdd(&num[(long)dcur * DD + f], accn);
        unsafeAtomicAdd(&den[(long)dcur * DD + f], accd);
    }
    __shared__ float ss[DD], sq[DD];
    if (t < DD) { ss[t] = 0.f; sq[t] = 0.f; }
    __syncthreads();
    if (act) { atomicAdd(&ss[f], acc_s); atomicAdd(&sq[f], acc_q); }
    __syncthreads();
    if (t < DD) {
        atomicAdd(&red[t], ss[t]);
        atomicAdd(&red[DD + t], sq[t]);
    }
}

// ---------- layer-2 edge kernel: MFMA bf16, dst_s-based, no CSR walks ----------
__global__ __launch_bounds__(640) void k_edge2(
    const float* __restrict__ ef_s, const float* __restrict__ sne_s,
    const int* __restrict__ src_s, const int* __restrict__ dst_s,
    const float* __restrict__ PD0, const float* __restrict__ PE0,
    const float* __restrict__ PB2, const float* __restrict__ PD2,
    const float* __restrict__ PE2, const float* __restrict__ CT2,
    const unsigned short* __restrict__ WB, const float* __restrict__ bC2,
    float* __restrict__ num, float* __restrict__ den) {
    __shared__ __align__(16) unsigned short As[10 * 16 * 104];
    int t = threadIdx.x;
    int w = t >> 6, l = t & 63;
    unsigned short* Aw = &As[w * 1664];
    for (int i = l; i < 832; i += 64) ((unsigned int*)Aw)[i] = 0u;
    int wb_e = blockIdx.x * EPB + w * EPW;
    if (wb_e >= NE) return;
    int col = l & 15, hi = l >> 4;
    bf16x8 bfr[15];
#pragma unroll
    for (int q = 0; q < 15; ++q)
        bfr[q] = *(const bf16x8*)(WB + (q * 64 + l) * 8);
    float bc[5];
#pragma unroll
    for (int nt = 0; nt < 5; ++nt) bc[nt] = bC2[nt * 16 + col];
    // epilogue accumulation state: current dst + partial sums
    int e0p = wb_e + hi * 4;
    if (e0p > NE - 1) e0p = NE - 1;
    int dcur = dst_s[e0p];
    float an[5], ad[5];
#pragma unroll
    for (int nt = 0; nt < 5; ++nt) { an[nt] = 0.f; ad[nt] = 0.f; }
    for (int tt = 0; tt < TPW; ++tt) {
        int et = wb_e + tt * 16;
        if (et >= NE) break;
        // ---- stage 16 e1-rows as bf16 (independent iterations: gathers pipeline) ----
        for (int i = l; i < 560; i += 64) {
            int el = i / 35, fp = i - el * 35, f = fp * 2;
            int e = et + el;
            unsigned int val = 0u;
            if (e < NE) {
                int s = src_s[e], d = dst_s[e];
                float efv = ef_s[e], sn = sne_s[e];
                const float* ct = CT2 + fp * 12;
                float2 pd = *(const float2*)(PD0 + (long)s * DD + f);
                float2 pe = *(const float2*)(PE0 + (long)d * DD + f);
                float en0a = pd.x + pe.x + efv * ct[0] + ct[2];
                float en0b = pd.y + pe.y + efv * ct[1] + ct[3];
                float ra = fmaxf(fmaf(en0a * sn, ct[4], ct[6]), 0.f);
                float rb = fmaxf(fmaf(en0b * sn, ct[5], ct[7]), 0.f);
                float e1a = fmaf(efv, ct[8], ct[10]) + ra;
                float e1b = fmaf(efv, ct[9], ct[11]) + rb;
                val = rne_bf16(e1a) | (rne_bf16(e1b) << 16);
            }
            ((unsigned int*)Aw)[(el * 104 + f) >> 1] = val;
        }
        // ---- A fragments + 15 MFMAs ----
        bf16x8 af[3];
#pragma unroll
        for (int c = 0; c < 3; ++c)
            af[c] = *(const bf16x8*)(Aw + (l & 15) * 104 + c * 32 + hi * 8);
        f32x4 acc[5];
#pragma unroll
        for (int nt = 0; nt < 5; ++nt) {
            acc[nt] = (f32x4){0.f, 0.f, 0.f, 0.f};
#pragma unroll
            for (int c = 0; c < 3; ++c)
                acc[nt] = __builtin_amdgcn_mfma_f32_16x16x32_bf16(af[c], bfr[nt * 3 + c],
                                                                  acc[nt], 0, 0, 0);
        }
        // ---- epilogue: D layout col=lane&15, row=(lane>>4)*4+reg ----
#pragma unroll
        for (int j = 0; j < 4; ++j) {
            int e = et + hi * 4 + j;
            if (e < NE) {
                int d = dst_s[e];
                if (d != dcur) {
#pragma unroll
                    for (int nt = 0; nt < 5; ++nt) {
                        int nv = nt * 16 + col;
                        if (nv < 70) {
                            unsafeAtomicAdd(&num[(long)dcur * DD + nv], an[nt]);
                            unsafeAtomicAdd(&den[(long)dcur * DD + nv], ad[nt]);
                        }
                        an[nt] = 0.f; ad[nt] = 0.f;
                    }
                    dcur = d;
                }
                int s = src_s[e];
#pragma unroll
                for (int nt = 0; nt < 5; ++nt) {
                    int nv = nt * 16 + col;
                    if (nv < 70) {
                        float en = acc[nt][j] + bc[nt] + PD2[(long)s * DD + nv]
                                 + PE2[(long)d * DD + nv];
                        float sg = sigmoidf_(en);
                        an[nt] = fmaf(sg, PB2[(long)s * DD + nv], an[nt]);
                        ad[nt] += sg;
                    }
                }
            }
        }
    }
#pragma unroll
    for (int nt = 0; nt < 5; ++nt) {
        int nv = nt * 16 + col;
        if (nv < 70) {
            unsafeAtomicAdd(&num[(long)dcur * DD + nv], an[nt]);
            unsafeAtomicAdd(&den[(long)dcur * DD + nv], ad[nt]);
        }
    }
}

// ---------- node BN stats: grid-stride, reg-accum ----------
__global__ __launch_bounds__(640) void k_nstats(const float* __restrict__ PA,
                                                const float* __restrict__ num,
                                                const float* __restrict__ den,
                                                const float* __restrict__ snn,
                                                float* __restrict__ red) {
    int t = threadIdx.x;
    int r = t / DD, f = t - r * DD;
    bool act = (r < 9);
    float acc_s = 0.f, acc_q = 0.f;
    const int T = (NN + 8) / 9;
    for (int tile = blockIdx.x; tile < T; tile += gridDim.x) {
        int i = tile * 9 + r;
        if (act && i < NN) {
            long o = (long)i * DD + f;
            float v = (PA[o] + num[o] / (den[o] + 1e-6f)) * snn[i];
            acc_s += v;
            acc_q = fmaf(v, v, acc_q);
        }
    }
    __shared__ float ss[DD], sq[DD];
    if (t < DD) { ss[t] = 0.f; sq[t] = 0.f; }
    __syncthreads();
    if (act) { atomicAdd(&ss[f], acc_s); atomicAdd(&sq[f], acc_q); }
    __syncthreads();
    if (t < DD) {
        atomicAdd(&red[t], ss[t]);
        atomicAdd(&red[DD + t], sq[t]);
    }
}

// ---------- finalize BN stats ----------
__global__ void k_stats(const float* __restrict__ sums, float* __restrict__ murs, float invn) {
    int f = threadIdx.x;
    if (f < DD) {
        float mu = sums[f] * invn;
        float var = sums[DD + f] * invn - mu * mu;
        murs[f] = mu;
        murs[DD + f] = rsqrtf(var + 1e-5f);
    }
}

// ---------- recompute v, BN-apply + relu + residual ----------
__global__ __launch_bounds__(256) void k_apply(const float* __restrict__ hin,
                                               const float* __restrict__ PA,
                                               const float* __restrict__ num,
                                               const float* __restrict__ den,
                                               const float* __restrict__ snn,
                                               const float* __restrict__ murs,
                                               const float* __restrict__ g,
                                               const float* __restrict__ b,
                                               float* __restrict__ hout) {
    long idx = (long)blockIdx.x * 256 + threadIdx.x;
    if (idx < (long)NN * DD) {
        int i = (int)(idx / DD);
        int f = (int)(idx - (long)i * DD);
        float v = (PA[idx] + num[idx] / (den[idx] + 1e-6f)) * snn[i];
        float bnv = (v - murs[f]) * murs[DD + f] * g[f] + b[f];
        hout[idx] = hin[idx] + fmaxf(bnv, 0.f);
    }
}

// ---------- per-graph sums ----------
__global__ __launch_bounds__(640) void k_readout(const float* __restrict__ h,
                                                 const int* __restrict__ gid,
                                                 float* __restrict__ gsum,
                                                 float* __restrict__ gcnt) {
    __shared__ float sv[9 * DD];
    __shared__ int sg_[9];
    int t = threadIdx.x;
    int r = t / DD, f = t - r * DD;
    int i = blockIdx.x * 9 + r;
    if (r < 9 && i < NN) {
        sv[r * DD + f] = h[(long)i * DD + f];
        if (f == 0) sg_[r] = gid[i];
    }
    __syncthreads();
    int nvalid = NN - blockIdx.x * 9;
    if (nvalid > 9) nvalid = 9;
    if (t < DD && nvalid > 0) {
        float acc = 0.f;
        int cur = sg_[0];
        for (int rr = 0; rr < nvalid; ++rr) {
            int g = sg_[rr];
            if (g != cur) {
                unsafeAtomicAdd(&gsum[cur * DD + t], acc);
                acc = 0.f;
                cur = g;
            }
            acc += sv[rr * DD + t];
        }
        unsafeAtomicAdd(&gsum[cur * DD + t], acc);
        if (t == 0) {
            int cnt = 0;
            cur = sg_[0];
            for (int rr = 0; rr < nvalid; ++rr) {
                if (sg_[rr] != cur) {
                    unsafeAtomicAdd(&gcnt[cur], (float)cnt);
                    cnt = 0;
                    cur = sg_[rr];
                }
                cnt++;
            }
            unsafeAtomicAdd(&gcnt[cur], (float)cnt);
        }
    }
}

__global__ void k_out(const float* __restrict__ gsum, const float* __restrict__ gcnt,
                      float* __restrict__ out) {
    int idx = blockIdx.x * 256 + threadIdx.x;
    if (idx < NG * DD) {
        int g = idx / DD;
        out[idx] = gsum[idx] / fmaxf(gcnt[g], 1.f);
    }
}

extern "C" void kernel_launch(void* const* d_in, const int* in_sizes, int n_in,
                              void* d_out, int out_size, void* d_ws, size_t ws_size,
                              hipStream_t stream) {
    const float* x   = (const float*)d_in[0];
    const float* ef  = (const float*)d_in[1];
    const float* snn = (const float*)d_in[2];
    const float* sne = (const float*)d_in[3];
    const int*   src = (const int*)d_in[4];
    const int*   dst = (const int*)d_in[5];
    const int*   gid = (const int*)d_in[6];
    const float* Wh  = (const float*)d_in[7];
    const float* bh  = (const float*)d_in[8];
    const float* We  = (const float*)d_in[9];
    const float* be  = (const float*)d_in[10];
    const float* Wg  = (const float*)d_in[11];
    const float* bg  = (const float*)d_in[12];
    const float* gh  = (const float*)d_in[13];
    const float* bbh = (const float*)d_in[14];
    const float* ge  = (const float*)d_in[15];
    const float* bbe = (const float*)d_in[16];
    float* out = (float*)d_out;

    const size_t NF = (size_t)NN * DD;  // 7,000,000

    float* ws = (float*)d_ws;
    float* B0 = ws;            // h0 -> PD2 -> h_final
    float* B1 = B0 + NF;       // h1
    float* B2 = B1 + NF;       // PA / PA2
    float* B3 = B2 + NF;       // PB / PB2
    float* B4 = B3 + NF;       // PD0 (kept through k_edge2)
    float* B5 = B4 + NF;       // PE0 (kept through k_edge2)
    float* B6 = B5 + NF;       // PE2
    float* num = B6 + NF;      // NF
    float* den = num + NF;     // NF
    float* red  = den + NF;        // 4*DD
    float* gsum = red + 4 * DD;    // NG*DD
    float* gcnt = gsum + NG * DD;  // NG
    float* v1 = gcnt + NG;
    float* v2 = v1 + DD;
    float* murs_e = v2 + DD;       // 2*DD
    float* murs_h = murs_e + 2 * DD;
    int* src_s = (int*)(murs_h + 2 * DD);   // NE
    float* ef_s  = (float*)(src_s + NE);    // NE
    float* sne_s = ef_s + NE;               // NE
    int* dst_s = (int*)(sne_s + NE);        // NE
    float* WT    = (float*)(dst_s + NE);    // 10 * WTS
    uintptr_t pal = ((uintptr_t)(WT + 10 * WTS) + 15) & ~(uintptr_t)15;
    float* CT2 = (float*)pal;                        // 420 floats
    unsigned short* WB = (unsigned short*)(CT2 + 420);  // 7680 u16
    // CSR build scratch: DEAD after k_fill -> alias into num (zeroed after build).
    int* off  = (int*)num;       // NN ints
    int* part = off + NN;        // 256 ints

    size_t need = (size_t)((char*)(WB + 7680) - (char*)d_ws);  // 268,249,840 B < 256 MiB
    if (ws_size < need) return;

    const int NB_N36 = (NN + 35) / 36;        // 2778
    const int NB_N9  = (NN + 8) / 9;          // 11112
    const int NB_E256 = (NE + 255) / 256;     // 3907
    const int NB_SC  = (NN + SCB - 1) / SCB;  // 196
    const int NB_E0  = (NE + CH0 - 1) / CH0;  // 1737
    const int NB_E2  = (NE + EPB - 1) / EPB;  // 1250

    // ---- CSR build FIRST (off/part live in num's space) ----
    hipMemsetAsync(off, 0, NN * sizeof(int), stream);
    k_trAll<<<dim3(70, 9), 72, 0, stream>>>(Wh, Wg, WT);
    k_count<<<NB_E256, 256, 0, stream>>>(dst, off);
    k_scan_a<<<NB_SC, SCB, 0, stream>>>(off, part);
    k_scan_b<<<1, 256, 0, stream>>>(part, NB_SC);
    k_scan_c<<<NB_SC, SCB, 0, stream>>>(off, part);
    k_fill<<<NB_E256, 256, 0, stream>>>(src, dst, ef, sne, off, src_s, ef_s, sne_s, dst_s);

    // ---- now zero accumulators (overwrites dead off/part) ----
    hipMemsetAsync(num, 0, (2 * NF + 4 * DD + NG * DD + NG) * sizeof(float), stream);

    k_pre<<<1, 128, 0, stream>>>(We, be, Wg, bg, v1, v2);
    k_dense_r<<<NB_N36, 640, 0, stream>>>(x, 64, WT + 0 * WTS, bh, B0, NN);

    // ---- layer 0 (params index 0) ----
    k_dense_r<<<NB_N36, 640, 0, stream>>>(B0, 70, WT + 1 * WTS, bg + 0 * 70, B2, NN);  // A
    k_dense_r<<<NB_N36, 640, 0, stream>>>(B0, 70, WT + 2 * WTS, bg + 1 * 70, B3, NN);  // B
    k_dense_r<<<NB_N36, 640, 0, stream>>>(B0, 70, WT + 3 * WTS, bg + 3 * 70, B4, NN);  // D
    k_dense_r<<<NB_N36, 640, 0, stream>>>(B0, 70, WT + 4 * WTS, bg + 4 * 70, B5, NN);  // E
    k_edge0<<<NB_E0, 640, 0, stream>>>(ef_s, sne_s, src_s, dst_s, B3, B4, B5, v1, v2,
                                       num, den, red);
    k_stats<<<1, 128, 0, stream>>>(red, murs_e, 1.f / NE);
    k_prep2<<<1, 512, 0, stream>>>(v1, v2, murs_e, ge + 0, bbe + 0, We, be, Wg, CT2, WB);
    k_nstats<<<2048, 640, 0, stream>>>(B2, num, den, snn, red + 2 * DD);
    k_stats<<<1, 128, 0, stream>>>(red + 2 * DD, murs_h, 1.f / NN);
    k_apply<<<(int)((NF + 255) / 256), 256, 0, stream>>>(B0, B2, num, den, snn, murs_h,
                                                         gh + 0, bbh + 0, B1);

    // ---- layer 2 (params index 2) ----
    hipMemsetAsync(num, 0, (2 * NF + 4 * DD) * sizeof(float), stream);  // num, den, red
    k_dense_r<<<NB_N36, 640, 0, stream>>>(B1, 70, WT + 5 * WTS, bg + 10 * 70, B2, NN); // A
    k_dense_r<<<NB_N36, 640, 0, stream>>>(B1, 70, WT + 6 * WTS, bg + 11 * 70, B3, NN); // B
    k_dense_r<<<NB_N36, 640, 0, stream>>>(B1, 70, WT + 7 * WTS, bg + 13 * 70, B0, NN); // D
    k_dense_r<<<NB_N36, 640, 0, stream>>>(B1, 70, WT + 8 * WTS, bg + 14 * 70, B6, NN); // E
    k_edge2<<<NB_E2, 640, 0, stream>>>(ef_s, sne_s, src_s, dst_s, B4, B5, B3, B0, B6,
                                       CT2, WB, bg + 12 * 70, num, den);
    k_nstats<<<2048, 640, 0, stream>>>(B2, num, den, snn, red + 2 * DD);
    k_stats<<<1, 128, 0, stream>>>(red + 2 * DD, murs_h, 1.f / NN);
    k_apply<<<(int)((NF + 255) / 256), 256, 0, stream>>>(B1, B2, num, den, snn, murs_h,
                                                         gh + 2 * DD, bbh + 2 * DD, B0);

    // ---- readout ----
    k_readout<<<NB_N9, 640, 0, stream>>>(B0, gid, gsum, gcnt);
    k_out<<<(NG * DD + 255) / 256, 256, 0, stream>>>(gsum, gcnt, out);
}

// Round 14
// 1740.224 us; speedup vs baseline: 7.7324x; 1.0036x over previous
//
#include <hip/hip_runtime.h>

#define NN 100000
#define NE 1000000
#define NG 100
#define DD 70
#define EL0 64             // edges per slot in k_edge0
#define CH0 (9 * EL0)      // 576 edges per block
#define TPW 5              // 16-edge tiles per wave in k_edge2
#define EPW (16 * TPW)     // 80 edges per wave
#define EPB (10 * EPW)     // 800 edges per block
#define SCB 512
#define WTS (70 * 72)      // one transposed weight matrix, padded

typedef __attribute__((ext_vector_type(8))) short bf16x8;
typedef __attribute__((ext_vector_type(4))) float f32x4;

__device__ __forceinline__ float sigmoidf_(float x) { return 1.f / (1.f + expf(-x)); }

__device__ __forceinline__ unsigned int rne_bf16(float x) {
    unsigned int u = __float_as_uint(x);
    return (u + 0x7FFFu + ((u >> 16) & 1u)) >> 16;
}
__device__ __forceinline__ float b2f(unsigned short u) {
    return __uint_as_float(((unsigned int)u) << 16);
}

#define DOT4(acc, vv, ww) { acc = fmaf((vv).x, (ww).x, acc); acc = fmaf((vv).y, (ww).y, acc); \
                            acc = fmaf((vv).z, (ww).z, acc); acc = fmaf((vv).w, (ww).w, acc); }

// ---------- transpose weight matrices into WT[m][70][72], zero-padded ----------
__global__ void k_trAll(const float* __restrict__ Wh, const float* __restrict__ Wg,
                        float* __restrict__ WT) {
    int m = blockIdx.y, f = blockIdx.x, k = threadIdx.x;
    const float* W;
    int K = DD;
    switch (m) {
        case 0: W = Wh; K = 64; break;
        case 1: W = Wg + 0 * 4900; break;
        case 2: W = Wg + 1 * 4900; break;
        case 3: W = Wg + 3 * 4900; break;
        case 4: W = Wg + 4 * 4900; break;
        case 5: W = Wg + 10 * 4900; break;
        case 6: W = Wg + 11 * 4900; break;
        case 7: W = Wg + 13 * 4900; break;
        default: W = Wg + 14 * 4900; break;
    }
    if (k < 72) WT[(m * 70 + f) * 72 + k] = (k < K) ? W[k * DD + f] : 0.f;
}

// ---------- skinny dense core (shared body via macro): 36-row tile, 4 rows/thread ----------
#define DENSE_BODY(STORE)                                                         \
    __shared__ float sx[36 * 72];                                                 \
    int t = threadIdx.x;                                                          \
    int r = t / DD, f = t - r * DD;                                               \
    long rb = (long)blockIdx.x * 36;                                              \
    for (int idx = t; idx < 36 * 72; idx += 640) {                                \
        int rr = idx / 72, kk = idx - rr * 72;                                    \
        long i = rb + rr;                                                         \
        sx[idx] = (kk < K && i < nrows) ? x[i * K + kk] : 0.f;                    \
    }                                                                             \
    __syncthreads();                                                              \
    if (r < 9) {                                                                  \
        const float4* wr = (const float4*)(WTm + f * 72);                         \
        float bb = bias[f];                                                       \
        float a0 = bb, a1 = bb, a2 = bb, a3 = bb;                                 \
        const float4* s0 = (const float4*)&sx[(r) * 72];                          \
        const float4* s1 = (const float4*)&sx[(r + 9) * 72];                      \
        const float4* s2 = (const float4*)&sx[(r + 18) * 72];                     \
        const float4* s3 = (const float4*)&sx[(r + 27) * 72];                     \
        _Pragma("unroll 1")                                                       \
        for (int q = 0; q < 18; q += 2) {                                         \
            float4 wA = wr[q], wB = wr[q + 1];                                    \
            float4 vA0 = s0[q], vB0 = s0[q + 1];                                  \
            DOT4(a0, vA0, wA) DOT4(a0, vB0, wB)                                   \
            float4 vA1 = s1[q], vB1 = s1[q + 1];                                  \
            DOT4(a1, vA1, wA) DOT4(a1, vB1, wB)                                   \
            float4 vA2 = s2[q], vB2 = s2[q + 1];                                  \
            DOT4(a2, vA2, wA) DOT4(a2, vB2, wB)                                   \
            float4 vA3 = s3[q], vB3 = s3[q + 1];                                  \
            DOT4(a3, vA3, wA) DOT4(a3, vB3, wB)                                   \
        }                                                                         \
        long i0 = rb + r, i1 = i0 + 9, i2 = i0 + 18, i3 = i0 + 27;                \
        if (i0 < nrows) STORE(i0, a0);                                            \
        if (i1 < nrows) STORE(i1, a1);                                            \
        if (i2 < nrows) STORE(i2, a2);                                            \
        if (i3 < nrows) STORE(i3, a3);                                            \
    }

__global__ __launch_bounds__(640) void k_dense_r(const float* __restrict__ x, int K,
                                                 const float* __restrict__ WTm,
                                                 const float* __restrict__ bias,
                                                 float* __restrict__ out, int nrows) {
#define ST_F32(ii, aa) out[(ii) * DD + f] = (aa)
    DENSE_BODY(ST_F32)
#undef ST_F32
}

__global__ __launch_bounds__(640) void k_dense_rh(const float* __restrict__ x, int K,
                                                  const float* __restrict__ WTm,
                                                  const float* __restrict__ bias,
                                                  unsigned short* __restrict__ out, int nrows) {
#define ST_BF16(ii, aa) out[(ii) * DD + f] = (unsigned short)rne_bf16(aa)
    DENSE_BODY(ST_BF16)
#undef ST_BF16
}

// ---------- v1 = We @ Wc0 ; v2 = be @ Wc0 + bc0 ----------
__global__ void k_pre(const float* __restrict__ We, const float* __restrict__ be,
                      const float* __restrict__ Wg, const float* __restrict__ bg,
                      float* __restrict__ v1, float* __restrict__ v2) {
    int f = threadIdx.x;
    if (f < DD) {
        const float* W2 = Wg + 2 * DD * DD;
        const float* b2 = bg + 2 * DD;
        float a = 0.f, c = 0.f;
        for (int k = 0; k < DD; ++k) {
            a = fmaf(We[k], W2[k * DD + f], a);
            c = fmaf(be[k], W2[k * DD + f], c);
        }
        v1[f] = a;
        v2[f] = c + b2[f];
    }
}

// ---------- prep for MFMA edge2: CT2 staging constants + WB B-fragments (bf16) ----------
__global__ void k_prep2(const float* __restrict__ v1, const float* __restrict__ v2,
                        const float* __restrict__ murs_e, const float* __restrict__ ge,
                        const float* __restrict__ bbe, const float* __restrict__ We,
                        const float* __restrict__ be, const float* __restrict__ Wg,
                        float* __restrict__ CT2, unsigned short* __restrict__ WB) {
    int t = threadIdx.x;  // 512 threads, 1 block
    if (t < 35) {
        int f0 = 2 * t, f1 = 2 * t + 1;
        float A0 = murs_e[DD + f0] * ge[f0], A1 = murs_e[DD + f1] * ge[f1];
        float* c = CT2 + t * 12;
        c[0] = v1[f0];  c[1] = v1[f1];
        c[2] = v2[f0];  c[3] = v2[f1];
        c[4] = A0;      c[5] = A1;
        c[6] = bbe[f0] - murs_e[f0] * A0;
        c[7] = bbe[f1] - murs_e[f1] * A1;
        c[8] = We[f0];  c[9] = We[f1];
        c[10] = be[f0]; c[11] = be[f1];
    }
    const float* WC2 = Wg + 12 * 4900;
    for (int idx = t; idx < 960; idx += 512) {
        int nt = idx / 192, rem = idx - nt * 192;
        int c = rem / 64, l = rem - c * 64;
        int n = nt * 16 + (l & 15);
        int kb = c * 32 + (l >> 4) * 8;
        for (int j = 0; j < 8; ++j) {
            int k = kb + j;
            unsigned short v = 0;
            if (k < 70 && n < 70) v = (unsigned short)rne_bf16(WC2[k * 70 + n]);
            WB[((nt * 3 + c) * 64 + l) * 8 + j] = v;
        }
    }
}

// ---------- CSR build: count / scan / fill ----------
__global__ void k_count(const int* __restrict__ dst, int* __restrict__ off) {
    int j = blockIdx.x * 256 + threadIdx.x;
    if (j < NE) atomicAdd(&off[dst[j]], 1);
}

__global__ void k_scan_a(int* __restrict__ off, int* __restrict__ part) {
    __shared__ int s[SCB];
    int t = threadIdx.x, i = blockIdx.x * SCB + t;
    int v = (i < NN) ? off[i] : 0;
    s[t] = v;
    __syncthreads();
    for (int d = 1; d < SCB; d <<= 1) {
        int x = (t >= d) ? s[t - d] : 0;
        __syncthreads();
        s[t] += x;
        __syncthreads();
    }
    if (i < NN) off[i] = s[t] - v;
    if (t == SCB - 1) part[blockIdx.x] = s[t];
}

__global__ void k_scan_b(int* __restrict__ part, int nb) {
    __shared__ int s[256];
    int t = threadIdx.x;
    int v = (t < nb) ? part[t] : 0;
    s[t] = v;
    __syncthreads();
    for (int d = 1; d < 256; d <<= 1) {
        int x = (t >= d) ? s[t - d] : 0;
        __syncthreads();
        s[t] += x;
        __syncthreads();
    }
    if (t < nb) part[t] = s[t] - v;
}

__global__ void k_scan_c(int* __restrict__ off, const int* __restrict__ part) {
    int i = blockIdx.x * SCB + threadIdx.x;
    if (i < NN) off[i] += part[blockIdx.x];
}

__global__ void k_fill(const int* __restrict__ src, const int* __restrict__ dst,
                       const float* __restrict__ ef, const float* __restrict__ sne,
                       int* __restrict__ off, int* __restrict__ src_s,
                       float* __restrict__ ef_s, float* __restrict__ sne_s,
                       int* __restrict__ dst_s) {
    int j = blockIdx.x * 256 + threadIdx.x;
    if (j < NE) {
        int d = dst[j];
        int pos = atomicAdd(&off[d], 1);
        src_s[pos] = src[j];
        ef_s[pos] = ef[j];
        sne_s[pos] = sne[j];
        dst_s[pos] = d;
    }
}

// ---------- layer-0 edge pass: edge-centric, bf16 tables, compare-flush ----------
__global__ __launch_bounds__(640) void k_edge0(
    const float* __restrict__ ef_s, const float* __restrict__ sne_s,
    const int* __restrict__ src_s, const int* __restrict__ dst_s,
    const unsigned short* __restrict__ PB, const unsigned short* __restrict__ PD,
    const unsigned short* __restrict__ PE, const float* __restrict__ v1,
    const float* __restrict__ v2, float* __restrict__ num,
    float* __restrict__ den, float* __restrict__ red) {
    int t = threadIdx.x;
    int r = t / DD, f = t - r * DD;
    bool act = (r < 9);
    float c1 = 0.f, c2 = 0.f;
    if (act) { c1 = v1[f]; c2 = v2[f]; }
    float acc_s = 0.f, acc_q = 0.f;
    int e_beg = blockIdx.x * CH0 + r * EL0;
    bool live = act && e_beg < NE;
    int dcur = 0;
    float accn = 0.f, accd = 0.f;
    int lim = 0;
    if (live) {
        dcur = dst_s[e_beg];
        lim = NE - e_beg;
        if (lim > EL0) lim = EL0;
    }
    for (int g = 0; g < lim; g += 4) {
        int m = lim - g;
        if (m > 4) m = 4;
        int dj[4];
        float pdj[4], pbj[4], pej[4], efj[4], snj[4];
#pragma unroll
        for (int j = 0; j < 4; ++j) {
            if (j < m) {
                int e = e_beg + g + j;
                int s = src_s[e];
                int d = dst_s[e];
                dj[j] = d;
                efj[j] = ef_s[e];
                snj[j] = sne_s[e];
                pdj[j] = b2f(PD[(long)s * DD + f]);
                pbj[j] = b2f(PB[(long)s * DD + f]);
                pej[j] = b2f(PE[(long)d * DD + f]);
            }
        }
#pragma unroll
        for (int j = 0; j < 4; ++j) {
            if (j < m) {
                if (dj[j] != dcur) {
                    unsafeAtomicAdd(&num[(long)dcur * DD + f], accn);
                    unsafeAtomicAdd(&den[(long)dcur * DD + f], accd);
                    accn = 0.f; accd = 0.f;
                    dcur = dj[j];
                }
                float en = pdj[j] + pej[j] + efj[j] * c1 + c2;
                float sg = sigmoidf_(en);
                accn = fmaf(sg, pbj[j], accn);
                accd += sg;
                float tv = en * snj[j];
                acc_s += tv;
                acc_q = fmaf(tv, tv, acc_q);
            }
        }
    }
    if (live) {
        unsafeAtomicAdd(&num[(long)dcur * DD + f], accn);
        unsafeAtomicAdd(&den[(long)dcur * DD + f], accd);
    }
    __shared__ float ss[DD], sq[DD];
    if (t < DD) { ss[t] = 0.f; sq[t] = 0.f; }
    __syncthreads();
    if (act) { atomicAdd(&ss[f], acc_s); atomicAdd(&sq[f], acc_q); }
    __syncthreads();
    if (t < DD) {
        atomicAdd(&red[t], ss[t]);
        atomicAdd(&red[DD + t], sq[t]);
    }
}

// ---------- layer-2 edge kernel: MFMA bf16, bf16 tables ----------
__global__ __launch_bounds__(640) void k_edge2(
    const float* __restrict__ ef_s, const float* __restrict__ sne_s,
    const int* __restrict__ src_s, const int* __restrict__ dst_s,
    const unsigned short* __restrict__ PD0, const unsigned short* __restrict__ PE0,
    const unsigned short* __restrict__ PB2, const unsigned short* __restrict__ PD2,
    const unsigned short* __restrict__ PE2, const float* __restrict__ CT2,
    const unsigned short* __restrict__ WB, const float* __restrict__ bC2,
    float* __restrict__ num, float* __restrict__ den) {
    __shared__ __align__(16) unsigned short As[10 * 16 * 104];
    int t = threadIdx.x;
    int w = t >> 6, l = t & 63;
    unsigned short* Aw = &As[w * 1664];
    for (int i = l; i < 832; i += 64) ((unsigned int*)Aw)[i] = 0u;
    int wb_e = blockIdx.x * EPB + w * EPW;
    if (wb_e >= NE) return;
    int col = l & 15, hi = l >> 4;
    bf16x8 bfr[15];
#pragma unroll
    for (int q = 0; q < 15; ++q)
        bfr[q] = *(const bf16x8*)(WB + (q * 64 + l) * 8);
    float bc[5];
#pragma unroll
    for (int nt = 0; nt < 5; ++nt) bc[nt] = bC2[nt * 16 + col];
    int e0p = wb_e + hi * 4;
    if (e0p > NE - 1) e0p = NE - 1;
    int dcur = dst_s[e0p];
    float an[5], ad[5];
#pragma unroll
    for (int nt = 0; nt < 5; ++nt) { an[nt] = 0.f; ad[nt] = 0.f; }
    for (int tt = 0; tt < TPW; ++tt) {
        int et = wb_e + tt * 16;
        if (et >= NE) break;
        // ---- stage 16 e1-rows as bf16 (bf16 tables: one u32 covers 2 features) ----
        for (int i = l; i < 560; i += 64) {
            int el = i / 35, fp = i - el * 35, f = fp * 2;
            int e = et + el;
            unsigned int val = 0u;
            if (e < NE) {
                int s = src_s[e], d = dst_s[e];
                float efv = ef_s[e], sn = sne_s[e];
                const float* ct = CT2 + fp * 12;
                unsigned int upd = *(const unsigned int*)(PD0 + (long)s * DD + f);
                unsigned int upe = *(const unsigned int*)(PE0 + (long)d * DD + f);
                float pdx = __uint_as_float(upd << 16);
                float pdy = __uint_as_float(upd & 0xFFFF0000u);
                float pex = __uint_as_float(upe << 16);
                float pey = __uint_as_float(upe & 0xFFFF0000u);
                float en0a = pdx + pex + efv * ct[0] + ct[2];
                float en0b = pdy + pey + efv * ct[1] + ct[3];
                float ra = fmaxf(fmaf(en0a * sn, ct[4], ct[6]), 0.f);
                float rb = fmaxf(fmaf(en0b * sn, ct[5], ct[7]), 0.f);
                float e1a = fmaf(efv, ct[8], ct[10]) + ra;
                float e1b = fmaf(efv, ct[9], ct[11]) + rb;
                val = rne_bf16(e1a) | (rne_bf16(e1b) << 16);
            }
            ((unsigned int*)Aw)[(el * 104 + f) >> 1] = val;
        }
        // ---- A fragments + 15 MFMAs ----
        bf16x8 af[3];
#pragma unroll
        for (int c = 0; c < 3; ++c)
            af[c] = *(const bf16x8*)(Aw + (l & 15) * 104 + c * 32 + hi * 8);
        f32x4 acc[5];
#pragma unroll
        for (int nt = 0; nt < 5; ++nt) {
            acc[nt] = (f32x4){0.f, 0.f, 0.f, 0.f};
#pragma unroll
            for (int c = 0; c < 3; ++c)
                acc[nt] = __builtin_amdgcn_mfma_f32_16x16x32_bf16(af[c], bfr[nt * 3 + c],
                                                                  acc[nt], 0, 0, 0);
        }
        // ---- epilogue: D layout col=lane&15, row=(lane>>4)*4+reg ----
#pragma unroll
        for (int j = 0; j < 4; ++j) {
            int e = et + hi * 4 + j;
            if (e < NE) {
                int d = dst_s[e];
                if (d != dcur) {
#pragma unroll
                    for (int nt = 0; nt < 5; ++nt) {
                        int nv = nt * 16 + col;
                        if (nv < 70) {
                            unsafeAtomicAdd(&num[(long)dcur * DD + nv], an[nt]);
                            unsafeAtomicAdd(&den[(long)dcur * DD + nv], ad[nt]);
                        }
                        an[nt] = 0.f; ad[nt] = 0.f;
                    }
                    dcur = d;
                }
                int s = src_s[e];
#pragma unroll
                for (int nt = 0; nt < 5; ++nt) {
                    int nv = nt * 16 + col;
                    if (nv < 70) {
                        float en = acc[nt][j] + bc[nt] + b2f(PD2[(long)s * DD + nv])
                                 + b2f(PE2[(long)d * DD + nv]);
                        float sg = sigmoidf_(en);
                        an[nt] = fmaf(sg, b2f(PB2[(long)s * DD + nv]), an[nt]);
                        ad[nt] += sg;
                    }
                }
            }
        }
    }
#pragma unroll
    for (int nt = 0; nt < 5; ++nt) {
        int nv = nt * 16 + col;
        if (nv < 70) {
            unsafeAtomicAdd(&num[(long)dcur * DD + nv], an[nt]);
            unsafeAtomicAdd(&den[(long)dcur * DD + nv], ad[nt]);
        }
    }
}

// ---------- node BN stats: grid-stride, reg-accum ----------
__global__ __launch_bounds__(640) void k_nstats(const float* __restrict__ PA,
                                                const float* __restrict__ num,
                                                const float* __restrict__ den,
                                                const float* __restrict__ snn,
                                                float* __restrict__ red) {
    int t = threadIdx.x;
    int r = t / DD, f = t - r * DD;
    bool act = (r < 9);
    float acc_s = 0.f, acc_q = 0.f;
    const int T = (NN + 8) / 9;
    for (int tile = blockIdx.x; tile < T; tile += gridDim.x) {
        int i = tile * 9 + r;
        if (act && i < NN) {
            long o = (long)i * DD + f;
            float v = (PA[o] + num[o] / (den[o] + 1e-6f)) * snn[i];
            acc_s += v;
            acc_q = fmaf(v, v, acc_q);
        }
    }
    __shared__ float ss[DD], sq[DD];
    if (t < DD) { ss[t] = 0.f; sq[t] = 0.f; }
    __syncthreads();
    if (act) { atomicAdd(&ss[f], acc_s); atomicAdd(&sq[f], acc_q); }
    __syncthreads();
    if (t < DD) {
        atomicAdd(&red[t], ss[t]);
        atomicAdd(&red[DD + t], sq[t]);
    }
}

// ---------- finalize BN stats ----------
__global__ void k_stats(const float* __restrict__ sums, float* __restrict__ murs, float invn) {
    int f = threadIdx.x;
    if (f < DD) {
        float mu = sums[f] * invn;
        float var = sums[DD + f] * invn - mu * mu;
        murs[f] = mu;
        murs[DD + f] = rsqrtf(var + 1e-5f);
    }
}

// ---------- recompute v, BN-apply + relu + residual ----------
__global__ __launch_bounds__(256) void k_apply(const float* __restrict__ hin,
                                               const float* __restrict__ PA,
                                               const float* __restrict__ num,
                                               const float* __restrict__ den,
                                               const float* __restrict__ snn,
                                               const float* __restrict__ murs,
                                               const float* __restrict__ g,
                                               const float* __restrict__ b,
                                               float* __restrict__ hout) {
    long idx = (long)blockIdx.x * 256 + threadIdx.x;
    if (idx < (long)NN * DD) {
        int i = (int)(idx / DD);
        int f = (int)(idx - (long)i * DD);
        float v = (PA[idx] + num[idx] / (den[idx] + 1e-6f)) * snn[i];
        float bnv = (v - murs[f]) * murs[DD + f] * g[f] + b[f];
        hout[idx] = hin[idx] + fmaxf(bnv, 0.f);
    }
}

// ---------- per-graph sums ----------
__global__ __launch_bounds__(640) void k_readout(const float* __restrict__ h,
                                                 const int* __restrict__ gid,
                                                 float* __restrict__ gsum,
                                                 float* __restrict__ gcnt) {
    __shared__ float sv[9 * DD];
    __shared__ int sg_[9];
    int t = threadIdx.x;
    int r = t / DD, f = t - r * DD;
    int i = blockIdx.x * 9 + r;
    if (r < 9 && i < NN) {
        sv[r * DD + f] = h[(long)i * DD + f];
        if (f == 0) sg_[r] = gid[i];
    }
    __syncthreads();
    int nvalid = NN - blockIdx.x * 9;
    if (nvalid > 9) nvalid = 9;
    if (t < DD && nvalid > 0) {
        float acc = 0.f;
        int cur = sg_[0];
        for (int rr = 0; rr < nvalid; ++rr) {
            int g = sg_[rr];
            if (g != cur) {
                unsafeAtomicAdd(&gsum[cur * DD + t], acc);
                acc = 0.f;
                cur = g;
            }
            acc += sv[rr * DD + t];
        }
        unsafeAtomicAdd(&gsum[cur * DD + t], acc);
        if (t == 0) {
            int cnt = 0;
            cur = sg_[0];
            for (int rr = 0; rr < nvalid; ++rr) {
                if (sg_[rr] != cur) {
                    unsafeAtomicAdd(&gcnt[cur], (float)cnt);
                    cnt = 0;
                    cur = sg_[rr];
                }
                cnt++;
            }
            unsafeAtomicAdd(&gcnt[cur], (float)cnt);
        }
    }
}

__global__ void k_out(const float* __restrict__ gsum, const float* __restrict__ gcnt,
                      float* __restrict__ out) {
    int idx = blockIdx.x * 256 + threadIdx.x;
    if (idx < NG * DD) {
        int g = idx / DD;
        out[idx] = gsum[idx] / fmaxf(gcnt[g], 1.f);
    }
}

extern "C" void kernel_launch(void* const* d_in, const int* in_sizes, int n_in,
                              void* d_out, int out_size, void* d_ws, size_t ws_size,
                              hipStream_t stream) {
    const float* x   = (const float*)d_in[0];
    const float* ef  = (const float*)d_in[1];
    const float* snn = (const float*)d_in[2];
    const float* sne = (const float*)d_in[3];
    const int*   src = (const int*)d_in[4];
    const int*   dst = (const int*)d_in[5];
    const int*   gid = (const int*)d_in[6];
    const float* Wh  = (const float*)d_in[7];
    const float* bh  = (const float*)d_in[8];
    const float* We  = (const float*)d_in[9];
    const float* be  = (const float*)d_in[10];
    const float* Wg  = (const float*)d_in[11];
    const float* bg  = (const float*)d_in[12];
    const float* gh  = (const float*)d_in[13];
    const float* bbh = (const float*)d_in[14];
    const float* ge  = (const float*)d_in[15];
    const float* bbe = (const float*)d_in[16];
    float* out = (float*)d_out;

    const size_t NF = (size_t)NN * DD;  // 7,000,000

    float* ws = (float*)d_ws;
    float* B0 = ws;            // h0 f32 -> later PD2 bf16 -> h_final f32
    float* B1 = B0 + NF;       // h1 f32
    float* B2 = B1 + NF;       // PA f32 (both layers)
    float* B3 = B2 + NF;       // PB bf16 (both layers; ushort in f32-sized slot)
    float* B4 = B3 + NF;       // PD0 bf16 (kept through k_edge2)
    float* B5 = B4 + NF;       // PE0 bf16 (kept through k_edge2)
    float* B6 = B5 + NF;       // PE2 bf16
    float* num = B6 + NF;      // NF
    float* den = num + NF;     // NF
    float* red  = den + NF;        // 4*DD
    float* gsum = red + 4 * DD;    // NG*DD
    float* gcnt = gsum + NG * DD;  // NG
    float* v1 = gcnt + NG;
    float* v2 = v1 + DD;
    float* murs_e = v2 + DD;       // 2*DD
    float* murs_h = murs_e + 2 * DD;
    int* src_s = (int*)(murs_h + 2 * DD);   // NE
    float* ef_s  = (float*)(src_s + NE);    // NE
    float* sne_s = ef_s + NE;               // NE
    int* dst_s = (int*)(sne_s + NE);        // NE
    float* WT    = (float*)(dst_s + NE);    // 10 * WTS
    uintptr_t pal = ((uintptr_t)(WT + 10 * WTS) + 15) & ~(uintptr_t)15;
    float* CT2 = (float*)pal;                        // 420 floats
    unsigned short* WB = (unsigned short*)(CT2 + 420);  // 7680 u16
    // CSR build scratch: DEAD after k_fill -> alias into num (zeroed after build).
    int* off  = (int*)num;       // NN ints
    int* part = off + NN;        // 256 ints

    unsigned short* B0h = (unsigned short*)B0;
    unsigned short* B3h = (unsigned short*)B3;
    unsigned short* B4h = (unsigned short*)B4;
    unsigned short* B5h = (unsigned short*)B5;
    unsigned short* B6h = (unsigned short*)B6;

    size_t need = (size_t)((char*)(WB + 7680) - (char*)d_ws);  // 268,249,840 B
    if (ws_size < need) return;

    const int NB_N36 = (NN + 35) / 36;        // 2778
    const int NB_N9  = (NN + 8) / 9;          // 11112
    const int NB_E256 = (NE + 255) / 256;     // 3907
    const int NB_SC  = (NN + SCB - 1) / SCB;  // 196
    const int NB_E0  = (NE + CH0 - 1) / CH0;  // 1737
    const int NB_E2  = (NE + EPB - 1) / EPB;  // 1250

    // ---- CSR build FIRST (off/part live in num's space) ----
    hipMemsetAsync(off, 0, NN * sizeof(int), stream);
    k_trAll<<<dim3(70, 9), 72, 0, stream>>>(Wh, Wg, WT);
    k_count<<<NB_E256, 256, 0, stream>>>(dst, off);
    k_scan_a<<<NB_SC, SCB, 0, stream>>>(off, part);
    k_scan_b<<<1, 256, 0, stream>>>(part, NB_SC);
    k_scan_c<<<NB_SC, SCB, 0, stream>>>(off, part);
    k_fill<<<NB_E256, 256, 0, stream>>>(src, dst, ef, sne, off, src_s, ef_s, sne_s, dst_s);

    // ---- now zero accumulators (overwrites dead off/part) ----
    hipMemsetAsync(num, 0, (2 * NF + 4 * DD + NG * DD + NG) * sizeof(float), stream);

    k_pre<<<1, 128, 0, stream>>>(We, be, Wg, bg, v1, v2);
    k_dense_r<<<NB_N36, 640, 0, stream>>>(x, 64, WT + 0 * WTS, bh, B0, NN);

    // ---- layer 0 (params index 0) ----
    k_dense_r <<<NB_N36, 640, 0, stream>>>(B0, 70, WT + 1 * WTS, bg + 0 * 70, B2, NN);   // A f32
    k_dense_rh<<<NB_N36, 640, 0, stream>>>(B0, 70, WT + 2 * WTS, bg + 1 * 70, B3h, NN);  // B bf16
    k_dense_rh<<<NB_N36, 640, 0, stream>>>(B0, 70, WT + 3 * WTS, bg + 3 * 70, B4h, NN);  // D bf16
    k_dense_rh<<<NB_N36, 640, 0, stream>>>(B0, 70, WT + 4 * WTS, bg + 4 * 70, B5h, NN);  // E bf16
    k_edge0<<<NB_E0, 640, 0, stream>>>(ef_s, sne_s, src_s, dst_s, B3h, B4h, B5h, v1, v2,
                                       num, den, red);
    k_stats<<<1, 128, 0, stream>>>(red, murs_e, 1.f / NE);
    k_prep2<<<1, 512, 0, stream>>>(v1, v2, murs_e, ge + 0, bbe + 0, We, be, Wg, CT2, WB);
    k_nstats<<<2048, 640, 0, stream>>>(B2, num, den, snn, red + 2 * DD);
    k_stats<<<1, 128, 0, stream>>>(red + 2 * DD, murs_h, 1.f / NN);
    k_apply<<<(int)((NF + 255) / 256), 256, 0, stream>>>(B0, B2, num, den, snn, murs_h,
                                                         gh + 0, bbh + 0, B1);

    // ---- layer 2 (params index 2) ----
    hipMemsetAsync(num, 0, (2 * NF + 4 * DD) * sizeof(float), stream);  // num, den, red
    k_dense_r <<<NB_N36, 640, 0, stream>>>(B1, 70, WT + 5 * WTS, bg + 10 * 70, B2, NN);  // A f32
    k_dense_rh<<<NB_N36, 640, 0, stream>>>(B1, 70, WT + 6 * WTS, bg + 11 * 70, B3h, NN); // B bf16
    k_dense_rh<<<NB_N36, 640, 0, stream>>>(B1, 70, WT + 7 * WTS, bg + 13 * 70, B0h, NN); // D bf16
    k_dense_rh<<<NB_N36, 640, 0, stream>>>(B1, 70, WT + 8 * WTS, bg + 14 * 70, B6h, NN); // E bf16
    k_edge2<<<NB_E2, 640, 0, stream>>>(ef_s, sne_s, src_s, dst_s, B4h, B5h, B3h, B0h, B6h,
                                       CT2, WB, bg + 12 * 70, num, den);
    k_nstats<<<2048, 640, 0, stream>>>(B2, num, den, snn, red + 2 * DD);
    k_stats<<<1, 128, 0, stream>>>(red + 2 * DD, murs_h, 1.f / NN);
    k_apply<<<(int)((NF + 255) / 256), 256, 0, stream>>>(B1, B2, num, den, snn, murs_h,
                                                         gh + 2 * DD, bbh + 2 * DD, B1);

    // ---- readout ----
    k_readout<<<NB_N9, 640, 0, stream>>>(B1, gid, gsum, gcnt);
    k_out<<<(NG * DD + 255) / 256, 256, 0, stream>>>(gsum, gcnt, out);
}

// Round 15
// 1707.249 us; speedup vs baseline: 7.8817x; 1.0193x over previous
//
#include <hip/hip_runtime.h>

#define NN 100000
#define NE 1000000
#define NG 100
#define DD 70
#define EL0 64             // edges per slot in k_edge0
#define CH0 (9 * EL0)      // 576 edges per block
#define TPW 5              // 16-edge tiles per wave in k_edge2
#define EPW (16 * TPW)     // 80 edges per wave
#define EPB (4 * EPW)      // 320 edges per 256-thread block (4 waves)
#define SCB 512
#define WTS (70 * 72)      // one transposed weight matrix, padded

typedef __attribute__((ext_vector_type(8))) short bf16x8;
typedef __attribute__((ext_vector_type(4))) float f32x4;

__device__ __forceinline__ float sigmoidf_(float x) { return 1.f / (1.f + expf(-x)); }

__device__ __forceinline__ unsigned int rne_bf16(float x) {
    unsigned int u = __float_as_uint(x);
    return (u + 0x7FFFu + ((u >> 16) & 1u)) >> 16;
}
__device__ __forceinline__ float b2f(unsigned short u) {
    return __uint_as_float(((unsigned int)u) << 16);
}

#define DOT4(acc, vv, ww) { acc = fmaf((vv).x, (ww).x, acc); acc = fmaf((vv).y, (ww).y, acc); \
                            acc = fmaf((vv).z, (ww).z, acc); acc = fmaf((vv).w, (ww).w, acc); }

// ---------- transpose weight matrices into WT[m][70][72], zero-padded ----------
__global__ void k_trAll(const float* __restrict__ Wh, const float* __restrict__ Wg,
                        float* __restrict__ WT) {
    int m = blockIdx.y, f = blockIdx.x, k = threadIdx.x;
    const float* W;
    int K = DD;
    switch (m) {
        case 0: W = Wh; K = 64; break;
        case 1: W = Wg + 0 * 4900; break;
        case 2: W = Wg + 1 * 4900; break;
        case 3: W = Wg + 3 * 4900; break;
        case 4: W = Wg + 4 * 4900; break;
        case 5: W = Wg + 10 * 4900; break;
        case 6: W = Wg + 11 * 4900; break;
        case 7: W = Wg + 13 * 4900; break;
        default: W = Wg + 14 * 4900; break;
    }
    if (k < 72) WT[(m * 70 + f) * 72 + k] = (k < K) ? W[k * DD + f] : 0.f;
}

// ---------- single skinny dense (used for h0, K=64) ----------
__global__ __launch_bounds__(640) void k_dense_r(const float* __restrict__ x, int K,
                                                 const float* __restrict__ WTm,
                                                 const float* __restrict__ bias,
                                                 float* __restrict__ out, int nrows) {
    __shared__ float sx[36 * 72];
    int t = threadIdx.x;
    int r = t / DD, f = t - r * DD;
    long rb = (long)blockIdx.x * 36;
    for (int idx = t; idx < 36 * 72; idx += 640) {
        int rr = idx / 72, kk = idx - rr * 72;
        long i = rb + rr;
        sx[idx] = (kk < K && i < nrows) ? x[i * K + kk] : 0.f;
    }
    __syncthreads();
    if (r < 9) {
        const float4* wr = (const float4*)(WTm + f * 72);
        float bb = bias[f];
        float a0 = bb, a1 = bb, a2 = bb, a3 = bb;
        const float4* s0 = (const float4*)&sx[(r) * 72];
        const float4* s1 = (const float4*)&sx[(r + 9) * 72];
        const float4* s2 = (const float4*)&sx[(r + 18) * 72];
        const float4* s3 = (const float4*)&sx[(r + 27) * 72];
#pragma unroll 1
        for (int q = 0; q < 18; q += 2) {
            float4 wA = wr[q], wB = wr[q + 1];
            float4 vA0 = s0[q], vB0 = s0[q + 1];
            DOT4(a0, vA0, wA) DOT4(a0, vB0, wB)
            float4 vA1 = s1[q], vB1 = s1[q + 1];
            DOT4(a1, vA1, wA) DOT4(a1, vB1, wB)
            float4 vA2 = s2[q], vB2 = s2[q + 1];
            DOT4(a2, vA2, wA) DOT4(a2, vB2, wB)
            float4 vA3 = s3[q], vB3 = s3[q + 1];
            DOT4(a3, vA3, wA) DOT4(a3, vB3, wB)
        }
        long i0 = rb + r, i1 = i0 + 9, i2 = i0 + 18, i3 = i0 + 27;
        if (i0 < nrows) out[i0 * DD + f] = a0;
        if (i1 < nrows) out[i1 * DD + f] = a1;
        if (i2 < nrows) out[i2 * DD + f] = a2;
        if (i3 < nrows) out[i3 * DD + f] = a3;
    }
}

// ---------- fused quad dense: A(f32) + B/D/E(bf16) from ONE input staging ----------
#define PROJ(MIDX, BIAS, STORE)                                                   \
    {                                                                             \
        const float4* wr = (const float4*)(WT4 + (MIDX) * WTS + f * 72);          \
        float bb = (BIAS)[f];                                                     \
        float a0 = bb, a1 = bb, a2 = bb, a3 = bb;                                 \
        _Pragma("unroll 1")                                                       \
        for (int q = 0; q < 18; q += 2) {                                         \
            float4 wA = wr[q], wB = wr[q + 1];                                    \
            float4 vA0 = s0[q], vB0 = s0[q + 1];                                  \
            DOT4(a0, vA0, wA) DOT4(a0, vB0, wB)                                   \
            float4 vA1 = s1[q], vB1 = s1[q + 1];                                  \
            DOT4(a1, vA1, wA) DOT4(a1, vB1, wB)                                   \
            float4 vA2 = s2[q], vB2 = s2[q + 1];                                  \
            DOT4(a2, vA2, wA) DOT4(a2, vB2, wB)                                   \
            float4 vA3 = s3[q], vB3 = s3[q + 1];                                  \
            DOT4(a3, vA3, wA) DOT4(a3, vB3, wB)                                   \
        }                                                                         \
        if (i0 < nrows) STORE(i0, a0);                                            \
        if (i1 < nrows) STORE(i1, a1);                                            \
        if (i2 < nrows) STORE(i2, a2);                                            \
        if (i3 < nrows) STORE(i3, a3);                                            \
    }

__global__ __launch_bounds__(640) void k_dense_q(
    const float* __restrict__ x, const float* __restrict__ WT4,
    const float* __restrict__ bA, const float* __restrict__ bB,
    const float* __restrict__ bD, const float* __restrict__ bE,
    float* __restrict__ outA, unsigned short* __restrict__ outB,
    unsigned short* __restrict__ outD, unsigned short* __restrict__ outE, int nrows) {
    __shared__ float sx[36 * 72];
    int t = threadIdx.x;
    int r = t / DD, f = t - r * DD;
    long rb = (long)blockIdx.x * 36;
    for (int idx = t; idx < 36 * 72; idx += 640) {
        int rr = idx / 72, kk = idx - rr * 72;
        long i = rb + rr;
        sx[idx] = (kk < DD && i < nrows) ? x[i * DD + kk] : 0.f;
    }
    __syncthreads();
    if (r < 9) {
        const float4* s0 = (const float4*)&sx[(r) * 72];
        const float4* s1 = (const float4*)&sx[(r + 9) * 72];
        const float4* s2 = (const float4*)&sx[(r + 18) * 72];
        const float4* s3 = (const float4*)&sx[(r + 27) * 72];
        long i0 = rb + r, i1 = i0 + 9, i2 = i0 + 18, i3 = i0 + 27;
#define ST_A(ii, aa) outA[(ii) * DD + f] = (aa)
#define ST_B(ii, aa) outB[(ii) * DD + f] = (unsigned short)rne_bf16(aa)
#define ST_D(ii, aa) outD[(ii) * DD + f] = (unsigned short)rne_bf16(aa)
#define ST_E(ii, aa) outE[(ii) * DD + f] = (unsigned short)rne_bf16(aa)
        PROJ(0, bA, ST_A)
        PROJ(1, bB, ST_B)
        PROJ(2, bD, ST_D)
        PROJ(3, bE, ST_E)
#undef ST_A
#undef ST_B
#undef ST_D
#undef ST_E
    }
}

// ---------- v1 = We @ Wc0 ; v2 = be @ Wc0 + bc0 ----------
__global__ void k_pre(const float* __restrict__ We, const float* __restrict__ be,
                      const float* __restrict__ Wg, const float* __restrict__ bg,
                      float* __restrict__ v1, float* __restrict__ v2) {
    int f = threadIdx.x;
    if (f < DD) {
        const float* W2 = Wg + 2 * DD * DD;
        const float* b2 = bg + 2 * DD;
        float a = 0.f, c = 0.f;
        for (int k = 0; k < DD; ++k) {
            a = fmaf(We[k], W2[k * DD + f], a);
            c = fmaf(be[k], W2[k * DD + f], c);
        }
        v1[f] = a;
        v2[f] = c + b2[f];
    }
}

// ---------- prep for MFMA edge2: CT2 staging constants + WB B-fragments (bf16) ----------
__global__ void k_prep2(const float* __restrict__ v1, const float* __restrict__ v2,
                        const float* __restrict__ murs_e, const float* __restrict__ ge,
                        const float* __restrict__ bbe, const float* __restrict__ We,
                        const float* __restrict__ be, const float* __restrict__ Wg,
                        float* __restrict__ CT2, unsigned short* __restrict__ WB) {
    int t = threadIdx.x;  // 512 threads, 1 block
    if (t < 35) {
        int f0 = 2 * t, f1 = 2 * t + 1;
        float A0 = murs_e[DD + f0] * ge[f0], A1 = murs_e[DD + f1] * ge[f1];
        float* c = CT2 + t * 12;
        c[0] = v1[f0];  c[1] = v1[f1];
        c[2] = v2[f0];  c[3] = v2[f1];
        c[4] = A0;      c[5] = A1;
        c[6] = bbe[f0] - murs_e[f0] * A0;
        c[7] = bbe[f1] - murs_e[f1] * A1;
        c[8] = We[f0];  c[9] = We[f1];
        c[10] = be[f0]; c[11] = be[f1];
    }
    const float* WC2 = Wg + 12 * 4900;
    for (int idx = t; idx < 960; idx += 512) {
        int nt = idx / 192, rem = idx - nt * 192;
        int c = rem / 64, l = rem - c * 64;
        int n = nt * 16 + (l & 15);
        int kb = c * 32 + (l >> 4) * 8;
        for (int j = 0; j < 8; ++j) {
            int k = kb + j;
            unsigned short v = 0;
            if (k < 70 && n < 70) v = (unsigned short)rne_bf16(WC2[k * 70 + n]);
            WB[((nt * 3 + c) * 64 + l) * 8 + j] = v;
        }
    }
}

// ---------- CSR build: count / scan / fill ----------
__global__ void k_count(const int* __restrict__ dst, int* __restrict__ off) {
    int j = blockIdx.x * 256 + threadIdx.x;
    if (j < NE) atomicAdd(&off[dst[j]], 1);
}

__global__ void k_scan_a(int* __restrict__ off, int* __restrict__ part) {
    __shared__ int s[SCB];
    int t = threadIdx.x, i = blockIdx.x * SCB + t;
    int v = (i < NN) ? off[i] : 0;
    s[t] = v;
    __syncthreads();
    for (int d = 1; d < SCB; d <<= 1) {
        int x = (t >= d) ? s[t - d] : 0;
        __syncthreads();
        s[t] += x;
        __syncthreads();
    }
    if (i < NN) off[i] = s[t] - v;
    if (t == SCB - 1) part[blockIdx.x] = s[t];
}

__global__ void k_scan_b(int* __restrict__ part, int nb) {
    __shared__ int s[256];
    int t = threadIdx.x;
    int v = (t < nb) ? part[t] : 0;
    s[t] = v;
    __syncthreads();
    for (int d = 1; d < 256; d <<= 1) {
        int x = (t >= d) ? s[t - d] : 0;
        __syncthreads();
        s[t] += x;
        __syncthreads();
    }
    if (t < nb) part[t] = s[t] - v;
}

__global__ void k_scan_c(int* __restrict__ off, const int* __restrict__ part) {
    int i = blockIdx.x * SCB + threadIdx.x;
    if (i < NN) off[i] += part[blockIdx.x];
}

__global__ void k_fill(const int* __restrict__ src, const int* __restrict__ dst,
                       const float* __restrict__ ef, const float* __restrict__ sne,
                       int* __restrict__ off, int* __restrict__ src_s,
                       float* __restrict__ ef_s, float* __restrict__ sne_s,
                       int* __restrict__ dst_s) {
    int j = blockIdx.x * 256 + threadIdx.x;
    if (j < NE) {
        int d = dst[j];
        int pos = atomicAdd(&off[d], 1);
        src_s[pos] = src[j];
        ef_s[pos] = ef[j];
        sne_s[pos] = sne[j];
        dst_s[pos] = d;
    }
}

// ---------- layer-0 edge pass: edge-centric, bf16 tables, compare-flush ----------
__global__ __launch_bounds__(640) void k_edge0(
    const float* __restrict__ ef_s, const float* __restrict__ sne_s,
    const int* __restrict__ src_s, const int* __restrict__ dst_s,
    const unsigned short* __restrict__ PB, const unsigned short* __restrict__ PD,
    const unsigned short* __restrict__ PE, const float* __restrict__ v1,
    const float* __restrict__ v2, float* __restrict__ num,
    float* __restrict__ den, float* __restrict__ red) {
    int t = threadIdx.x;
    int r = t / DD, f = t - r * DD;
    bool act = (r < 9);
    float c1 = 0.f, c2 = 0.f;
    if (act) { c1 = v1[f]; c2 = v2[f]; }
    float acc_s = 0.f, acc_q = 0.f;
    int e_beg = blockIdx.x * CH0 + r * EL0;
    bool live = act && e_beg < NE;
    int dcur = 0;
    float accn = 0.f, accd = 0.f;
    int lim = 0;
    if (live) {
        dcur = dst_s[e_beg];
        lim = NE - e_beg;
        if (lim > EL0) lim = EL0;
    }
    for (int g = 0; g < lim; g += 4) {
        int m = lim - g;
        if (m > 4) m = 4;
        int dj[4];
        float pdj[4], pbj[4], pej[4], efj[4], snj[4];
#pragma unroll
        for (int j = 0; j < 4; ++j) {
            if (j < m) {
                int e = e_beg + g + j;
                int s = src_s[e];
                int d = dst_s[e];
                dj[j] = d;
                efj[j] = ef_s[e];
                snj[j] = sne_s[e];
                pdj[j] = b2f(PD[(long)s * DD + f]);
                pbj[j] = b2f(PB[(long)s * DD + f]);
                pej[j] = b2f(PE[(long)d * DD + f]);
            }
        }
#pragma unroll
        for (int j = 0; j < 4; ++j) {
            if (j < m) {
                if (dj[j] != dcur) {
                    unsafeAtomicAdd(&num[(long)dcur * DD + f], accn);
                    unsafeAtomicAdd(&den[(long)dcur * DD + f], accd);
                    accn = 0.f; accd = 0.f;
                    dcur = dj[j];
                }
                float en = pdj[j] + pej[j] + efj[j] * c1 + c2;
                float sg = sigmoidf_(en);
                accn = fmaf(sg, pbj[j], accn);
                accd += sg;
                float tv = en * snj[j];
                acc_s += tv;
                acc_q = fmaf(tv, tv, acc_q);
            }
        }
    }
    if (live) {
        unsafeAtomicAdd(&num[(long)dcur * DD + f], accn);
        unsafeAtomicAdd(&den[(long)dcur * DD + f], accd);
    }
    __shared__ float ss[DD], sq[DD];
    if (t < DD) { ss[t] = 0.f; sq[t] = 0.f; }
    __syncthreads();
    if (act) { atomicAdd(&ss[f], acc_s); atomicAdd(&sq[f], acc_q); }
    __syncthreads();
    if (t < DD) {
        atomicAdd(&red[t], ss[t]);
        atomicAdd(&red[DD + t], sq[t]);
    }
}

// ---------- layer-2 edge kernel: MFMA bf16, 256-thread blocks (4 indep waves) ----------
__global__ __launch_bounds__(256) void k_edge2(
    const float* __restrict__ ef_s, const float* __restrict__ sne_s,
    const int* __restrict__ src_s, const int* __restrict__ dst_s,
    const unsigned short* __restrict__ PD0, const unsigned short* __restrict__ PE0,
    const unsigned short* __restrict__ PB2, const unsigned short* __restrict__ PD2,
    const unsigned short* __restrict__ PE2, const float* __restrict__ CT2,
    const unsigned short* __restrict__ WB, const float* __restrict__ bC2,
    float* __restrict__ num, float* __restrict__ den) {
    __shared__ __align__(16) unsigned short As[4 * 16 * 104];
    int t = threadIdx.x;
    int w = t >> 6, l = t & 63;
    unsigned short* Aw = &As[w * 1664];
    for (int i = l; i < 832; i += 64) ((unsigned int*)Aw)[i] = 0u;
    int wb_e = blockIdx.x * EPB + w * EPW;
    if (wb_e >= NE) return;
    int col = l & 15, hi = l >> 4;
    bf16x8 bfr[15];
#pragma unroll
    for (int q = 0; q < 15; ++q)
        bfr[q] = *(const bf16x8*)(WB + (q * 64 + l) * 8);
    float bc[5];
#pragma unroll
    for (int nt = 0; nt < 5; ++nt) bc[nt] = bC2[nt * 16 + col];
    int e0p = wb_e + hi * 4;
    if (e0p > NE - 1) e0p = NE - 1;
    int dcur = dst_s[e0p];
    float an[5], ad[5];
#pragma unroll
    for (int nt = 0; nt < 5; ++nt) { an[nt] = 0.f; ad[nt] = 0.f; }
    for (int tt = 0; tt < TPW; ++tt) {
        int et = wb_e + tt * 16;
        if (et >= NE) break;
        // ---- stage 16 e1-rows as bf16 (bf16 tables: one u32 covers 2 features) ----
        for (int i = l; i < 560; i += 64) {
            int el = i / 35, fp = i - el * 35, f = fp * 2;
            int e = et + el;
            unsigned int val = 0u;
            if (e < NE) {
                int s = src_s[e], d = dst_s[e];
                float efv = ef_s[e], sn = sne_s[e];
                const float* ct = CT2 + fp * 12;
                unsigned int upd = *(const unsigned int*)(PD0 + (long)s * DD + f);
                unsigned int upe = *(const unsigned int*)(PE0 + (long)d * DD + f);
                float pdx = __uint_as_float(upd << 16);
                float pdy = __uint_as_float(upd & 0xFFFF0000u);
                float pex = __uint_as_float(upe << 16);
                float pey = __uint_as_float(upe & 0xFFFF0000u);
                float en0a = pdx + pex + efv * ct[0] + ct[2];
                float en0b = pdy + pey + efv * ct[1] + ct[3];
                float ra = fmaxf(fmaf(en0a * sn, ct[4], ct[6]), 0.f);
                float rb = fmaxf(fmaf(en0b * sn, ct[5], ct[7]), 0.f);
                float e1a = fmaf(efv, ct[8], ct[10]) + ra;
                float e1b = fmaf(efv, ct[9], ct[11]) + rb;
                val = rne_bf16(e1a) | (rne_bf16(e1b) << 16);
            }
            ((unsigned int*)Aw)[(el * 104 + f) >> 1] = val;
        }
        // ---- A fragments + 15 MFMAs ----
        bf16x8 af[3];
#pragma unroll
        for (int c = 0; c < 3; ++c)
            af[c] = *(const bf16x8*)(Aw + (l & 15) * 104 + c * 32 + hi * 8);
        f32x4 acc[5];
#pragma unroll
        for (int nt = 0; nt < 5; ++nt) {
            acc[nt] = (f32x4){0.f, 0.f, 0.f, 0.f};
#pragma unroll
            for (int c = 0; c < 3; ++c)
                acc[nt] = __builtin_amdgcn_mfma_f32_16x16x32_bf16(af[c], bfr[nt * 3 + c],
                                                                  acc[nt], 0, 0, 0);
        }
        // ---- epilogue: D layout col=lane&15, row=(lane>>4)*4+reg ----
#pragma unroll
        for (int j = 0; j < 4; ++j) {
            int e = et + hi * 4 + j;
            if (e < NE) {
                int d = dst_s[e];
                if (d != dcur) {
#pragma unroll
                    for (int nt = 0; nt < 5; ++nt) {
                        int nv = nt * 16 + col;
                        if (nv < 70) {
                            unsafeAtomicAdd(&num[(long)dcur * DD + nv], an[nt]);
                            unsafeAtomicAdd(&den[(long)dcur * DD + nv], ad[nt]);
                        }
                        an[nt] = 0.f; ad[nt] = 0.f;
                    }
                    dcur = d;
                }
                int s = src_s[e];
#pragma unroll
                for (int nt = 0; nt < 5; ++nt) {
                    int nv = nt * 16 + col;
                    if (nv < 70) {
                        float en = acc[nt][j] + bc[nt] + b2f(PD2[(long)s * DD + nv])
                                 + b2f(PE2[(long)d * DD + nv]);
                        float sg = sigmoidf_(en);
                        an[nt] = fmaf(sg, b2f(PB2[(long)s * DD + nv]), an[nt]);
                        ad[nt] += sg;
                    }
                }
            }
        }
    }
#pragma unroll
    for (int nt = 0; nt < 5; ++nt) {
        int nv = nt * 16 + col;
        if (nv < 70) {
            unsafeAtomicAdd(&num[(long)dcur * DD + nv], an[nt]);
            unsafeAtomicAdd(&den[(long)dcur * DD + nv], ad[nt]);
        }
    }
}

// ---------- node BN stats: grid-stride, reg-accum ----------
__global__ __launch_bounds__(640) void k_nstats(const float* __restrict__ PA,
                                                const float* __restrict__ num,
                                                const float* __restrict__ den,
                                                const float* __restrict__ snn,
                                                float* __restrict__ red) {
    int t = threadIdx.x;
    int r = t / DD, f = t - r * DD;
    bool act = (r < 9);
    float acc_s = 0.f, acc_q = 0.f;
    const int T = (NN + 8) / 9;
    for (int tile = blockIdx.x; tile < T; tile += gridDim.x) {
        int i = tile * 9 + r;
        if (act && i < NN) {
            long o = (long)i * DD + f;
            float v = (PA[o] + num[o] / (den[o] + 1e-6f)) * snn[i];
            acc_s += v;
            acc_q = fmaf(v, v, acc_q);
        }
    }
    __shared__ float ss[DD], sq[DD];
    if (t < DD) { ss[t] = 0.f; sq[t] = 0.f; }
    __syncthreads();
    if (act) { atomicAdd(&ss[f], acc_s); atomicAdd(&sq[f], acc_q); }
    __syncthreads();
    if (t < DD) {
        atomicAdd(&red[t], ss[t]);
        atomicAdd(&red[DD + t], sq[t]);
    }
}

// ---------- finalize BN stats ----------
__global__ void k_stats(const float* __restrict__ sums, float* __restrict__ murs, float invn) {
    int f = threadIdx.x;
    if (f < DD) {
        float mu = sums[f] * invn;
        float var = sums[DD + f] * invn - mu * mu;
        murs[f] = mu;
        murs[DD + f] = rsqrtf(var + 1e-5f);
    }
}

// ---------- recompute v, BN-apply + relu + residual ----------
__global__ __launch_bounds__(256) void k_apply(const float* __restrict__ hin,
                                               const float* __restrict__ PA,
                                               const float* __restrict__ num,
                                               const float* __restrict__ den,
                                               const float* __restrict__ snn,
                                               const float* __restrict__ murs,
                                               const float* __restrict__ g,
                                               const float* __restrict__ b,
                                               float* __restrict__ hout) {
    long idx = (long)blockIdx.x * 256 + threadIdx.x;
    if (idx < (long)NN * DD) {
        int i = (int)(idx / DD);
        int f = (int)(idx - (long)i * DD);
        float v = (PA[idx] + num[idx] / (den[idx] + 1e-6f)) * snn[i];
        float bnv = (v - murs[f]) * murs[DD + f] * g[f] + b[f];
        hout[idx] = hin[idx] + fmaxf(bnv, 0.f);
    }
}

// ---------- per-graph sums ----------
__global__ __launch_bounds__(640) void k_readout(const float* __restrict__ h,
                                                 const int* __restrict__ gid,
                                                 float* __restrict__ gsum,
                                                 float* __restrict__ gcnt) {
    __shared__ float sv[9 * DD];
    __shared__ int sg_[9];
    int t = threadIdx.x;
    int r = t / DD, f = t - r * DD;
    int i = blockIdx.x * 9 + r;
    if (r < 9 && i < NN) {
        sv[r * DD + f] = h[(long)i * DD + f];
        if (f == 0) sg_[r] = gid[i];
    }
    __syncthreads();
    int nvalid = NN - blockIdx.x * 9;
    if (nvalid > 9) nvalid = 9;
    if (t < DD && nvalid > 0) {
        float acc = 0.f;
        int cur = sg_[0];
        for (int rr = 0; rr < nvalid; ++rr) {
            int g = sg_[rr];
            if (g != cur) {
                unsafeAtomicAdd(&gsum[cur * DD + t], acc);
                acc = 0.f;
                cur = g;
            }
            acc += sv[rr * DD + t];
        }
        unsafeAtomicAdd(&gsum[cur * DD + t], acc);
        if (t == 0) {
            int cnt = 0;
            cur = sg_[0];
            for (int rr = 0; rr < nvalid; ++rr) {
                if (sg_[rr] != cur) {
                    unsafeAtomicAdd(&gcnt[cur], (float)cnt);
                    cnt = 0;
                    cur = sg_[rr];
                }
                cnt++;
            }
            unsafeAtomicAdd(&gcnt[cur], (float)cnt);
        }
    }
}

__global__ void k_out(const float* __restrict__ gsum, const float* __restrict__ gcnt,
                      float* __restrict__ out) {
    int idx = blockIdx.x * 256 + threadIdx.x;
    if (idx < NG * DD) {
        int g = idx / DD;
        out[idx] = gsum[idx] / fmaxf(gcnt[g], 1.f);
    }
}

extern "C" void kernel_launch(void* const* d_in, const int* in_sizes, int n_in,
                              void* d_out, int out_size, void* d_ws, size_t ws_size,
                              hipStream_t stream) {
    const float* x   = (const float*)d_in[0];
    const float* ef  = (const float*)d_in[1];
    const float* snn = (const float*)d_in[2];
    const float* sne = (const float*)d_in[3];
    const int*   src = (const int*)d_in[4];
    const int*   dst = (const int*)d_in[5];
    const int*   gid = (const int*)d_in[6];
    const float* Wh  = (const float*)d_in[7];
    const float* bh  = (const float*)d_in[8];
    const float* We  = (const float*)d_in[9];
    const float* be  = (const float*)d_in[10];
    const float* Wg  = (const float*)d_in[11];
    const float* bg  = (const float*)d_in[12];
    const float* gh  = (const float*)d_in[13];
    const float* bbh = (const float*)d_in[14];
    const float* ge  = (const float*)d_in[15];
    const float* bbe = (const float*)d_in[16];
    float* out = (float*)d_out;

    const size_t NF = (size_t)NN * DD;  // 7,000,000

    float* ws = (float*)d_ws;
    float* B0 = ws;            // h0 f32 -> later PD2 bf16
    float* B1 = B0 + NF;       // h1 f32 -> h_final f32
    float* B2 = B1 + NF;       // PA f32 (both layers)
    float* B3 = B2 + NF;       // PB bf16 (both layers)
    float* B4 = B3 + NF;       // PD0 bf16 (kept through k_edge2)
    float* B5 = B4 + NF;       // PE0 bf16 (kept through k_edge2)
    float* B6 = B5 + NF;       // PE2 bf16
    float* num = B6 + NF;      // NF
    float* den = num + NF;     // NF
    float* red  = den + NF;        // 4*DD
    float* gsum = red + 4 * DD;    // NG*DD
    float* gcnt = gsum + NG * DD;  // NG
    float* v1 = gcnt + NG;
    float* v2 = v1 + DD;
    float* murs_e = v2 + DD;       // 2*DD
    float* murs_h = murs_e + 2 * DD;
    int* src_s = (int*)(murs_h + 2 * DD);   // NE
    float* ef_s  = (float*)(src_s + NE);    // NE
    float* sne_s = ef_s + NE;               // NE
    int* dst_s = (int*)(sne_s + NE);        // NE
    float* WT    = (float*)(dst_s + NE);    // 10 * WTS
    uintptr_t pal = ((uintptr_t)(WT + 10 * WTS) + 15) & ~(uintptr_t)15;
    float* CT2 = (float*)pal;                        // 420 floats
    unsigned short* WB = (unsigned short*)(CT2 + 420);  // 7680 u16
    // CSR build scratch: DEAD after k_fill -> alias into num (zeroed after build).
    int* off  = (int*)num;       // NN ints
    int* part = off + NN;        // 256 ints

    unsigned short* B0h = (unsigned short*)B0;
    unsigned short* B3h = (unsigned short*)B3;
    unsigned short* B4h = (unsigned short*)B4;
    unsigned short* B5h = (unsigned short*)B5;
    unsigned short* B6h = (unsigned short*)B6;

    size_t need = (size_t)((char*)(WB + 7680) - (char*)d_ws);  // 268,249,840 B
    if (ws_size < need) return;

    const int NB_N36 = (NN + 35) / 36;        // 2778
    const int NB_N9  = (NN + 8) / 9;          // 11112
    const int NB_E256 = (NE + 255) / 256;     // 3907
    const int NB_SC  = (NN + SCB - 1) / SCB;  // 196
    const int NB_E0  = (NE + CH0 - 1) / CH0;  // 1737
    const int NB_E2  = (NE + EPB - 1) / EPB;  // 3125

    // ---- CSR build FIRST (off/part live in num's space) ----
    hipMemsetAsync(off, 0, NN * sizeof(int), stream);
    k_trAll<<<dim3(70, 9), 72, 0, stream>>>(Wh, Wg, WT);
    k_count<<<NB_E256, 256, 0, stream>>>(dst, off);
    k_scan_a<<<NB_SC, SCB, 0, stream>>>(off, part);
    k_scan_b<<<1, 256, 0, stream>>>(part, NB_SC);
    k_scan_c<<<NB_SC, SCB, 0, stream>>>(off, part);
    k_fill<<<NB_E256, 256, 0, stream>>>(src, dst, ef, sne, off, src_s, ef_s, sne_s, dst_s);

    // ---- now zero accumulators (overwrites dead off/part) ----
    hipMemsetAsync(num, 0, (2 * NF + 4 * DD + NG * DD + NG) * sizeof(float), stream);

    k_pre<<<1, 128, 0, stream>>>(We, be, Wg, bg, v1, v2);
    k_dense_r<<<NB_N36, 640, 0, stream>>>(x, 64, WT + 0 * WTS, bh, B0, NN);

    // ---- layer 0 (params index 0): fused quad dense A,B,D,E ----
    k_dense_q<<<NB_N36, 640, 0, stream>>>(B0, WT + 1 * WTS, bg + 0 * 70, bg + 1 * 70,
                                          bg + 3 * 70, bg + 4 * 70, B2, B3h, B4h, B5h, NN);
    k_edge0<<<NB_E0, 640, 0, stream>>>(ef_s, sne_s, src_s, dst_s, B3h, B4h, B5h, v1, v2,
                                       num, den, red);
    k_stats<<<1, 128, 0, stream>>>(red, murs_e, 1.f / NE);
    k_prep2<<<1, 512, 0, stream>>>(v1, v2, murs_e, ge + 0, bbe + 0, We, be, Wg, CT2, WB);
    k_nstats<<<2048, 640, 0, stream>>>(B2, num, den, snn, red + 2 * DD);
    k_stats<<<1, 128, 0, stream>>>(red + 2 * DD, murs_h, 1.f / NN);
    k_apply<<<(int)((NF + 255) / 256), 256, 0, stream>>>(B0, B2, num, den, snn, murs_h,
                                                         gh + 0, bbh + 0, B1);

    // ---- layer 2 (params index 2): fused quad dense ----
    hipMemsetAsync(num, 0, (2 * NF + 4 * DD) * sizeof(float), stream);  // num, den, red
    k_dense_q<<<NB_N36, 640, 0, stream>>>(B1, WT + 5 * WTS, bg + 10 * 70, bg + 11 * 70,
                                          bg + 13 * 70, bg + 14 * 70, B2, B3h, B0h, B6h, NN);
    k_edge2<<<NB_E2, 256, 0, stream>>>(ef_s, sne_s, src_s, dst_s, B4h, B5h, B3h, B0h, B6h,
                                       CT2, WB, bg + 12 * 70, num, den);
    k_nstats<<<2048, 640, 0, stream>>>(B2, num, den, snn, red + 2 * DD);
    k_stats<<<1, 128, 0, stream>>>(red + 2 * DD, murs_h, 1.f / NN);
    k_apply<<<(int)((NF + 255) / 256), 256, 0, stream>>>(B1, B2, num, den, snn, murs_h,
                                                         gh + 2 * DD, bbh + 2 * DD, B1);

    // ---- readout ----
    k_readout<<<NB_N9, 640, 0, stream>>>(B1, gid, gsum, gcnt);
    k_out<<<(NG * DD + 255) / 256, 256, 0, stream>>>(gsum, gcnt, out);
}

// Round 16
// 1583.309 us; speedup vs baseline: 8.4987x; 1.0783x over previous
//
#include <hip/hip_runtime.h>

#define NN 100000
#define NE 1000000
#define NG 100
#define DD 70
#define EL0 64             // edges per slot in k_edge0
#define CH0 (9 * EL0)      // 576 edges per block
#define TPW 5              // 16-edge tiles per wave in k_edge2
#define EPW (16 * TPW)     // 80 edges per wave
#define EPB (4 * EPW)      // 320 edges per 256-thread block (4 waves)
#define SCB 512
#define WTS (70 * 72)      // one transposed weight matrix, padded

typedef __attribute__((ext_vector_type(8))) short bf16x8;
typedef __attribute__((ext_vector_type(4))) float f32x4;

__device__ __forceinline__ float sigmoidf_(float x) { return 1.f / (1.f + expf(-x)); }

__device__ __forceinline__ unsigned int rne_bf16(float x) {
    unsigned int u = __float_as_uint(x);
    return (u + 0x7FFFu + ((u >> 16) & 1u)) >> 16;
}
__device__ __forceinline__ float b2f(unsigned short u) {
    return __uint_as_float(((unsigned int)u) << 16);
}
__device__ __forceinline__ float lo2f(unsigned int u) { return __uint_as_float(u << 16); }
__device__ __forceinline__ float hi2f(unsigned int u) { return __uint_as_float(u & 0xFFFF0000u); }

#define DOT4(acc, vv, ww) { acc = fmaf((vv).x, (ww).x, acc); acc = fmaf((vv).y, (ww).y, acc); \
                            acc = fmaf((vv).z, (ww).z, acc); acc = fmaf((vv).w, (ww).w, acc); }

// ---------- transpose weight matrices into WT[m][70][72], zero-padded ----------
__global__ void k_trAll(const float* __restrict__ Wh, const float* __restrict__ Wg,
                        float* __restrict__ WT) {
    int m = blockIdx.y, f = blockIdx.x, k = threadIdx.x;
    const float* W;
    int K = DD;
    switch (m) {
        case 0: W = Wh; K = 64; break;
        case 1: W = Wg + 0 * 4900; break;
        case 2: W = Wg + 1 * 4900; break;
        case 3: W = Wg + 3 * 4900; break;
        case 4: W = Wg + 4 * 4900; break;
        case 5: W = Wg + 10 * 4900; break;
        case 6: W = Wg + 11 * 4900; break;
        case 7: W = Wg + 13 * 4900; break;
        default: W = Wg + 14 * 4900; break;
    }
    if (k < 72) WT[(m * 70 + f) * 72 + k] = (k < K) ? W[k * DD + f] : 0.f;
}

// ---------- single skinny dense (used for h0, K=64) ----------
__global__ __launch_bounds__(640) void k_dense_r(const float* __restrict__ x, int K,
                                                 const float* __restrict__ WTm,
                                                 const float* __restrict__ bias,
                                                 float* __restrict__ out, int nrows) {
    __shared__ float sx[36 * 72];
    int t = threadIdx.x;
    int r = t / DD, f = t - r * DD;
    long rb = (long)blockIdx.x * 36;
    for (int idx = t; idx < 36 * 72; idx += 640) {
        int rr = idx / 72, kk = idx - rr * 72;
        long i = rb + rr;
        sx[idx] = (kk < K && i < nrows) ? x[i * K + kk] : 0.f;
    }
    __syncthreads();
    if (r < 9) {
        const float4* wr = (const float4*)(WTm + f * 72);
        float bb = bias[f];
        float a0 = bb, a1 = bb, a2 = bb, a3 = bb;
        const float4* s0 = (const float4*)&sx[(r) * 72];
        const float4* s1 = (const float4*)&sx[(r + 9) * 72];
        const float4* s2 = (const float4*)&sx[(r + 18) * 72];
        const float4* s3 = (const float4*)&sx[(r + 27) * 72];
#pragma unroll 1
        for (int q = 0; q < 18; q += 2) {
            float4 wA = wr[q], wB = wr[q + 1];
            float4 vA0 = s0[q], vB0 = s0[q + 1];
            DOT4(a0, vA0, wA) DOT4(a0, vB0, wB)
            float4 vA1 = s1[q], vB1 = s1[q + 1];
            DOT4(a1, vA1, wA) DOT4(a1, vB1, wB)
            float4 vA2 = s2[q], vB2 = s2[q + 1];
            DOT4(a2, vA2, wA) DOT4(a2, vB2, wB)
            float4 vA3 = s3[q], vB3 = s3[q + 1];
            DOT4(a3, vA3, wA) DOT4(a3, vB3, wB)
        }
        long i0 = rb + r, i1 = i0 + 9, i2 = i0 + 18, i3 = i0 + 27;
        if (i0 < nrows) out[i0 * DD + f] = a0;
        if (i1 < nrows) out[i1 * DD + f] = a1;
        if (i2 < nrows) out[i2 * DD + f] = a2;
        if (i3 < nrows) out[i3 * DD + f] = a3;
    }
}

// ---------- fused quad dense: A(f32), D(bf16 std), E(bf16), DB packed u32 ----------
#define PROJ(MIDX, BIAS, STORE)                                                   \
    {                                                                             \
        const float4* wr = (const float4*)(WT4 + (MIDX) * WTS + f * 72);          \
        float bb = (BIAS)[f];                                                     \
        float a0 = bb, a1 = bb, a2 = bb, a3 = bb;                                 \
        _Pragma("unroll 1")                                                       \
        for (int q = 0; q < 18; q += 2) {                                         \
            float4 wA = wr[q], wB = wr[q + 1];                                    \
            float4 vA0 = s0[q], vB0 = s0[q + 1];                                  \
            DOT4(a0, vA0, wA) DOT4(a0, vB0, wB)                                   \
            float4 vA1 = s1[q], vB1 = s1[q + 1];                                  \
            DOT4(a1, vA1, wA) DOT4(a1, vB1, wB)                                   \
            float4 vA2 = s2[q], vB2 = s2[q + 1];                                  \
            DOT4(a2, vA2, wA) DOT4(a2, vB2, wB)                                   \
            float4 vA3 = s3[q], vB3 = s3[q + 1];                                  \
            DOT4(a3, vA3, wA) DOT4(a3, vB3, wB)                                   \
        }                                                                         \
        STORE(0, i0, a0)                                                          \
        STORE(1, i1, a1)                                                          \
        STORE(2, i2, a2)                                                          \
        STORE(3, i3, a3)                                                          \
    }

__global__ __launch_bounds__(640) void k_dense_q(
    const float* __restrict__ x, const float* __restrict__ WT4,
    const float* __restrict__ bA, const float* __restrict__ bB,
    const float* __restrict__ bD, const float* __restrict__ bE,
    float* __restrict__ outA, unsigned short* __restrict__ outDstd,
    unsigned short* __restrict__ outE, unsigned int* __restrict__ outDB, int nrows) {
    __shared__ float sx[36 * 72];
    int t = threadIdx.x;
    int r = t / DD, f = t - r * DD;
    long rb = (long)blockIdx.x * 36;
    for (int idx = t; idx < 36 * 72; idx += 640) {
        int rr = idx / 72, kk = idx - rr * 72;
        long i = rb + rr;
        sx[idx] = (kk < DD && i < nrows) ? x[i * DD + kk] : 0.f;
    }
    __syncthreads();
    if (r < 9) {
        const float4* s0 = (const float4*)&sx[(r) * 72];
        const float4* s1 = (const float4*)&sx[(r + 9) * 72];
        const float4* s2 = (const float4*)&sx[(r + 18) * 72];
        const float4* s3 = (const float4*)&sx[(r + 27) * 72];
        long i0 = rb + r, i1 = i0 + 9, i2 = i0 + 18, i3 = i0 + 27;
        float vB0 = 0.f, vB1 = 0.f, vB2 = 0.f, vB3 = 0.f;
#define ST_A(row, ii, aa) if ((ii) < nrows) outA[(ii) * DD + f] = (aa);
#define ST_B(row, ii, aa) vB##row = (aa);
#define ST_D(row, ii, aa) if ((ii) < nrows) { unsigned int ud = rne_bf16(aa); \
            outDstd[(ii) * DD + f] = (unsigned short)ud; \
            outDB[(ii) * DD + f] = ud | (rne_bf16(vB##row) << 16); }
#define ST_E(row, ii, aa) if ((ii) < nrows) outE[(ii) * DD + f] = (unsigned short)rne_bf16(aa);
        PROJ(0, bA, ST_A)
        PROJ(1, bB, ST_B)
        PROJ(2, bD, ST_D)
        PROJ(3, bE, ST_E)
#undef ST_A
#undef ST_B
#undef ST_D
#undef ST_E
    }
}

// ---------- v1 = We @ Wc0 ; v2 = be @ Wc0 + bc0 ----------
__global__ void k_pre(const float* __restrict__ We, const float* __restrict__ be,
                      const float* __restrict__ Wg, const float* __restrict__ bg,
                      float* __restrict__ v1, float* __restrict__ v2) {
    int f = threadIdx.x;
    if (f < DD) {
        const float* W2 = Wg + 2 * DD * DD;
        const float* b2 = bg + 2 * DD;
        float a = 0.f, c = 0.f;
        for (int k = 0; k < DD; ++k) {
            a = fmaf(We[k], W2[k * DD + f], a);
            c = fmaf(be[k], W2[k * DD + f], c);
        }
        v1[f] = a;
        v2[f] = c + b2[f];
    }
}

// ---------- prep for MFMA edge2: CT2 staging constants + WB B-fragments (bf16) ----------
__global__ void k_prep2(const float* __restrict__ v1, const float* __restrict__ v2,
                        const float* __restrict__ murs_e, const float* __restrict__ ge,
                        const float* __restrict__ bbe, const float* __restrict__ We,
                        const float* __restrict__ be, const float* __restrict__ Wg,
                        float* __restrict__ CT2, unsigned short* __restrict__ WB) {
    int t = threadIdx.x;  // 512 threads, 1 block
    if (t < 35) {
        int f0 = 2 * t, f1 = 2 * t + 1;
        float A0 = murs_e[DD + f0] * ge[f0], A1 = murs_e[DD + f1] * ge[f1];
        float* c = CT2 + t * 12;
        c[0] = v1[f0];  c[1] = v1[f1];
        c[2] = v2[f0];  c[3] = v2[f1];
        c[4] = A0;      c[5] = A1;
        c[6] = bbe[f0] - murs_e[f0] * A0;
        c[7] = bbe[f1] - murs_e[f1] * A1;
        c[8] = We[f0];  c[9] = We[f1];
        c[10] = be[f0]; c[11] = be[f1];
    }
    const float* WC2 = Wg + 12 * 4900;
    for (int idx = t; idx < 960; idx += 512) {
        int nt = idx / 192, rem = idx - nt * 192;
        int c = rem / 64, l = rem - c * 64;
        int n = nt * 16 + (l & 15);
        int kb = c * 32 + (l >> 4) * 8;
        for (int j = 0; j < 8; ++j) {
            int k = kb + j;
            unsigned short v = 0;
            if (k < 70 && n < 70) v = (unsigned short)rne_bf16(WC2[k * 70 + n]);
            WB[((nt * 3 + c) * 64 + l) * 8 + j] = v;
        }
    }
}

// ---------- CSR build: count / scan / fill ----------
__global__ void k_count(const int* __restrict__ dst, int* __restrict__ off) {
    int j = blockIdx.x * 256 + threadIdx.x;
    if (j < NE) atomicAdd(&off[dst[j]], 1);
}

__global__ void k_scan_a(int* __restrict__ off, int* __restrict__ part) {
    __shared__ int s[SCB];
    int t = threadIdx.x, i = blockIdx.x * SCB + t;
    int v = (i < NN) ? off[i] : 0;
    s[t] = v;
    __syncthreads();
    for (int d = 1; d < SCB; d <<= 1) {
        int x = (t >= d) ? s[t - d] : 0;
        __syncthreads();
        s[t] += x;
        __syncthreads();
    }
    if (i < NN) off[i] = s[t] - v;
    if (t == SCB - 1) part[blockIdx.x] = s[t];
}

__global__ void k_scan_b(int* __restrict__ part, int nb) {
    __shared__ int s[256];
    int t = threadIdx.x;
    int v = (t < nb) ? part[t] : 0;
    s[t] = v;
    __syncthreads();
    for (int d = 1; d < 256; d <<= 1) {
        int x = (t >= d) ? s[t - d] : 0;
        __syncthreads();
        s[t] += x;
        __syncthreads();
    }
    if (t < nb) part[t] = s[t] - v;
}

__global__ void k_scan_c(int* __restrict__ off, const int* __restrict__ part) {
    int i = blockIdx.x * SCB + threadIdx.x;
    if (i < NN) off[i] += part[blockIdx.x];
}

__global__ void k_fill(const int* __restrict__ src, const int* __restrict__ dst,
                       const float* __restrict__ ef, const float* __restrict__ sne,
                       int* __restrict__ off, int* __restrict__ src_s,
                       float* __restrict__ ef_s, float* __restrict__ sne_s,
                       int* __restrict__ dst_s) {
    int j = blockIdx.x * 256 + threadIdx.x;
    if (j < NE) {
        int d = dst[j];
        int pos = atomicAdd(&off[d], 1);
        src_s[pos] = src[j];
        ef_s[pos] = ef[j];
        sne_s[pos] = sne[j];
        dst_s[pos] = d;
    }
}

// ---------- layer-0 edge pass: DB0 packed gather + run-cached PE ----------
__global__ __launch_bounds__(640) void k_edge0(
    const float* __restrict__ ef_s, const float* __restrict__ sne_s,
    const int* __restrict__ src_s, const int* __restrict__ dst_s,
    const unsigned int* __restrict__ DB0, const unsigned short* __restrict__ PE,
    const float* __restrict__ v1, const float* __restrict__ v2,
    float* __restrict__ num, float* __restrict__ den, float* __restrict__ red) {
    int t = threadIdx.x;
    int r = t / DD, f = t - r * DD;
    bool act = (r < 9);
    float c1 = 0.f, c2 = 0.f;
    if (act) { c1 = v1[f]; c2 = v2[f]; }
    float acc_s = 0.f, acc_q = 0.f;
    int e_beg = blockIdx.x * CH0 + r * EL0;
    bool live = act && e_beg < NE;
    int dcur = 0;
    float pe = 0.f, accn = 0.f, accd = 0.f;
    int lim = 0;
    if (live) {
        dcur = dst_s[e_beg];
        pe = b2f(PE[(long)dcur * DD + f]);
        lim = NE - e_beg;
        if (lim > EL0) lim = EL0;
    }
    for (int g = 0; g < lim; g += 4) {
        int m = lim - g;
        if (m > 4) m = 4;
        int dj[4];
        unsigned int dbj[4];
        float efj[4], snj[4];
#pragma unroll
        for (int j = 0; j < 4; ++j) {
            if (j < m) {
                int e = e_beg + g + j;
                int s = src_s[e];
                dj[j] = dst_s[e];
                efj[j] = ef_s[e];
                snj[j] = sne_s[e];
                dbj[j] = DB0[(long)s * DD + f];  // D low, B high
            }
        }
#pragma unroll
        for (int j = 0; j < 4; ++j) {
            if (j < m) {
                if (dj[j] != dcur) {
                    unsafeAtomicAdd(&num[(long)dcur * DD + f], accn);
                    unsafeAtomicAdd(&den[(long)dcur * DD + f], accd);
                    accn = 0.f; accd = 0.f;
                    dcur = dj[j];
                    pe = b2f(PE[(long)dcur * DD + f]);
                }
                float en = lo2f(dbj[j]) + pe + efj[j] * c1 + c2;
                float sg = sigmoidf_(en);
                accn = fmaf(sg, hi2f(dbj[j]), accn);
                accd += sg;
                float tv = en * snj[j];
                acc_s += tv;
                acc_q = fmaf(tv, tv, acc_q);
            }
        }
    }
    if (live) {
        unsafeAtomicAdd(&num[(long)dcur * DD + f], accn);
        unsafeAtomicAdd(&den[(long)dcur * DD + f], accd);
    }
    __shared__ float ss[DD], sq[DD];
    if (t < DD) { ss[t] = 0.f; sq[t] = 0.f; }
    __syncthreads();
    if (act) { atomicAdd(&ss[f], acc_s); atomicAdd(&sq[f], acc_q); }
    __syncthreads();
    if (t < DD) {
        atomicAdd(&red[t], ss[t]);
        atomicAdd(&red[DD + t], sq[t]);
    }
}

// ---------- layer-2 edge kernel: MFMA bf16, DB2 packed + run-cached PE2 ----------
__global__ __launch_bounds__(256) void k_edge2(
    const float* __restrict__ ef_s, const float* __restrict__ sne_s,
    const int* __restrict__ src_s, const int* __restrict__ dst_s,
    const unsigned short* __restrict__ PD0, const unsigned short* __restrict__ PE0,
    const unsigned int* __restrict__ DB2, const unsigned short* __restrict__ PE2,
    const float* __restrict__ CT2, const unsigned short* __restrict__ WB,
    const float* __restrict__ bC2, float* __restrict__ num, float* __restrict__ den) {
    __shared__ __align__(16) unsigned short As[4 * 16 * 104];
    int t = threadIdx.x;
    int w = t >> 6, l = t & 63;
    unsigned short* Aw = &As[w * 1664];
    for (int i = l; i < 832; i += 64) ((unsigned int*)Aw)[i] = 0u;
    int wb_e = blockIdx.x * EPB + w * EPW;
    if (wb_e >= NE) return;
    int col = l & 15, hi = l >> 4;
    bf16x8 bfr[15];
#pragma unroll
    for (int q = 0; q < 15; ++q)
        bfr[q] = *(const bf16x8*)(WB + (q * 64 + l) * 8);
    float bc[5];
#pragma unroll
    for (int nt = 0; nt < 5; ++nt) bc[nt] = bC2[nt * 16 + col];
    int e0p = wb_e + hi * 4;
    if (e0p > NE - 1) e0p = NE - 1;
    int dcur = dst_s[e0p];
    float an[5], ad[5], pe2c[5];
#pragma unroll
    for (int nt = 0; nt < 5; ++nt) {
        an[nt] = 0.f; ad[nt] = 0.f;
        int nv = nt * 16 + col;
        pe2c[nt] = (nv < 70) ? b2f(PE2[(long)dcur * DD + nv]) : 0.f;
    }
    for (int tt = 0; tt < TPW; ++tt) {
        int et = wb_e + tt * 16;
        if (et >= NE) break;
        // ---- stage 16 e1-rows as bf16 (bf16 tables: one u32 covers 2 features) ----
        for (int i = l; i < 560; i += 64) {
            int el = i / 35, fp = i - el * 35, f = fp * 2;
            int e = et + el;
            unsigned int val = 0u;
            if (e < NE) {
                int s = src_s[e], d = dst_s[e];
                float efv = ef_s[e], sn = sne_s[e];
                const float* ct = CT2 + fp * 12;
                unsigned int upd = *(const unsigned int*)(PD0 + (long)s * DD + f);
                unsigned int upe = *(const unsigned int*)(PE0 + (long)d * DD + f);
                float pdx = lo2f(upd), pdy = hi2f(upd);
                float pex = lo2f(upe), pey = hi2f(upe);
                float en0a = pdx + pex + efv * ct[0] + ct[2];
                float en0b = pdy + pey + efv * ct[1] + ct[3];
                float ra = fmaxf(fmaf(en0a * sn, ct[4], ct[6]), 0.f);
                float rb = fmaxf(fmaf(en0b * sn, ct[5], ct[7]), 0.f);
                float e1a = fmaf(efv, ct[8], ct[10]) + ra;
                float e1b = fmaf(efv, ct[9], ct[11]) + rb;
                val = rne_bf16(e1a) | (rne_bf16(e1b) << 16);
            }
            ((unsigned int*)Aw)[(el * 104 + f) >> 1] = val;
        }
        // ---- A fragments + 15 MFMAs ----
        bf16x8 af[3];
#pragma unroll
        for (int c = 0; c < 3; ++c)
            af[c] = *(const bf16x8*)(Aw + (l & 15) * 104 + c * 32 + hi * 8);
        f32x4 acc[5];
#pragma unroll
        for (int nt = 0; nt < 5; ++nt) {
            acc[nt] = (f32x4){0.f, 0.f, 0.f, 0.f};
#pragma unroll
            for (int c = 0; c < 3; ++c)
                acc[nt] = __builtin_amdgcn_mfma_f32_16x16x32_bf16(af[c], bfr[nt * 3 + c],
                                                                  acc[nt], 0, 0, 0);
        }
        // ---- epilogue: D layout col=lane&15, row=(lane>>4)*4+reg ----
#pragma unroll
        for (int j = 0; j < 4; ++j) {
            int e = et + hi * 4 + j;
            if (e < NE) {
                int d = dst_s[e];
                if (d != dcur) {
#pragma unroll
                    for (int nt = 0; nt < 5; ++nt) {
                        int nv = nt * 16 + col;
                        if (nv < 70) {
                            unsafeAtomicAdd(&num[(long)dcur * DD + nv], an[nt]);
                            unsafeAtomicAdd(&den[(long)dcur * DD + nv], ad[nt]);
                        }
                        an[nt] = 0.f; ad[nt] = 0.f;
                    }
                    dcur = d;
#pragma unroll
                    for (int nt = 0; nt < 5; ++nt) {
                        int nv = nt * 16 + col;
                        if (nv < 70) pe2c[nt] = b2f(PE2[(long)dcur * DD + nv]);
                    }
                }
                int s = src_s[e];
#pragma unroll
                for (int nt = 0; nt < 5; ++nt) {
                    int nv = nt * 16 + col;
                    if (nv < 70) {
                        unsigned int db = DB2[(long)s * DD + nv];  // D low, B high
                        float en = acc[nt][j] + bc[nt] + lo2f(db) + pe2c[nt];
                        float sg = sigmoidf_(en);
                        an[nt] = fmaf(sg, hi2f(db), an[nt]);
                        ad[nt] += sg;
                    }
                }
            }
        }
    }
#pragma unroll
    for (int nt = 0; nt < 5; ++nt) {
        int nv = nt * 16 + col;
        if (nv < 70) {
            unsafeAtomicAdd(&num[(long)dcur * DD + nv], an[nt]);
            unsafeAtomicAdd(&den[(long)dcur * DD + nv], ad[nt]);
        }
    }
}

// ---------- node BN stats: grid-stride, reg-accum ----------
__global__ __launch_bounds__(640) void k_nstats(const float* __restrict__ PA,
                                                const float* __restrict__ num,
                                                const float* __restrict__ den,
                                                const float* __restrict__ snn,
                                                float* __restrict__ red) {
    int t = threadIdx.x;
    int r = t / DD, f = t - r * DD;
    bool act = (r < 9);
    float acc_s = 0.f, acc_q = 0.f;
    const int T = (NN + 8) / 9;
    for (int tile = blockIdx.x; tile < T; tile += gridDim.x) {
        int i = tile * 9 + r;
        if (act && i < NN) {
            long o = (long)i * DD + f;
            float v = (PA[o] + num[o] / (den[o] + 1e-6f)) * snn[i];
            acc_s += v;
            acc_q = fmaf(v, v, acc_q);
        }
    }
    __shared__ float ss[DD], sq[DD];
    if (t < DD) { ss[t] = 0.f; sq[t] = 0.f; }
    __syncthreads();
    if (act) { atomicAdd(&ss[f], acc_s); atomicAdd(&sq[f], acc_q); }
    __syncthreads();
    if (t < DD) {
        atomicAdd(&red[t], ss[t]);
        atomicAdd(&red[DD + t], sq[t]);
    }
}

// ---------- finalize BN stats ----------
__global__ void k_stats(const float* __restrict__ sums, float* __restrict__ murs, float invn) {
    int f = threadIdx.x;
    if (f < DD) {
        float mu = sums[f] * invn;
        float var = sums[DD + f] * invn - mu * mu;
        murs[f] = mu;
        murs[DD + f] = rsqrtf(var + 1e-5f);
    }
}

// ---------- recompute v, BN-apply + relu + residual ----------
__global__ __launch_bounds__(256) void k_apply(const float* __restrict__ hin,
                                               const float* __restrict__ PA,
                                               const float* __restrict__ num,
                                               const float* __restrict__ den,
                                               const float* __restrict__ snn,
                                               const float* __restrict__ murs,
                                               const float* __restrict__ g,
                                               const float* __restrict__ b,
                                               float* __restrict__ hout) {
    long idx = (long)blockIdx.x * 256 + threadIdx.x;
    if (idx < (long)NN * DD) {
        int i = (int)(idx / DD);
        int f = (int)(idx - (long)i * DD);
        float v = (PA[idx] + num[idx] / (den[idx] + 1e-6f)) * snn[i];
        float bnv = (v - murs[f]) * murs[DD + f] * g[f] + b[f];
        hout[idx] = hin[idx] + fmaxf(bnv, 0.f);
    }
}

// ---------- per-graph sums ----------
__global__ __launch_bounds__(640) void k_readout(const float* __restrict__ h,
                                                 const int* __restrict__ gid,
                                                 float* __restrict__ gsum,
                                                 float* __restrict__ gcnt) {
    __shared__ float sv[9 * DD];
    __shared__ int sg_[9];
    int t = threadIdx.x;
    int r = t / DD, f = t - r * DD;
    int i = blockIdx.x * 9 + r;
    if (r < 9 && i < NN) {
        sv[r * DD + f] = h[(long)i * DD + f];
        if (f == 0) sg_[r] = gid[i];
    }
    __syncthreads();
    int nvalid = NN - blockIdx.x * 9;
    if (nvalid > 9) nvalid = 9;
    if (t < DD && nvalid > 0) {
        float acc = 0.f;
        int cur = sg_[0];
        for (int rr = 0; rr < nvalid; ++rr) {
            int g = sg_[rr];
            if (g != cur) {
                unsafeAtomicAdd(&gsum[cur * DD + t], acc);
                acc = 0.f;
                cur = g;
            }
            acc += sv[rr * DD + t];
        }
        unsafeAtomicAdd(&gsum[cur * DD + t], acc);
        if (t == 0) {
            int cnt = 0;
            cur = sg_[0];
            for (int rr = 0; rr < nvalid; ++rr) {
                if (sg_[rr] != cur) {
                    unsafeAtomicAdd(&gcnt[cur], (float)cnt);
                    cnt = 0;
                    cur = sg_[rr];
                }
                cnt++;
            }
            unsafeAtomicAdd(&gcnt[cur], (float)cnt);
        }
    }
}

__global__ void k_out(const float* __restrict__ gsum, const float* __restrict__ gcnt,
                      float* __restrict__ out) {
    int idx = blockIdx.x * 256 + threadIdx.x;
    if (idx < NG * DD) {
        int g = idx / DD;
        out[idx] = gsum[idx] / fmaxf(gcnt[g], 1.f);
    }
}

extern "C" void kernel_launch(void* const* d_in, const int* in_sizes, int n_in,
                              void* d_out, int out_size, void* d_ws, size_t ws_size,
                              hipStream_t stream) {
    const float* x   = (const float*)d_in[0];
    const float* ef  = (const float*)d_in[1];
    const float* snn = (const float*)d_in[2];
    const float* sne = (const float*)d_in[3];
    const int*   src = (const int*)d_in[4];
    const int*   dst = (const int*)d_in[5];
    const int*   gid = (const int*)d_in[6];
    const float* Wh  = (const float*)d_in[7];
    const float* bh  = (const float*)d_in[8];
    const float* We  = (const float*)d_in[9];
    const float* be  = (const float*)d_in[10];
    const float* Wg  = (const float*)d_in[11];
    const float* bg  = (const float*)d_in[12];
    const float* gh  = (const float*)d_in[13];
    const float* bbh = (const float*)d_in[14];
    const float* ge  = (const float*)d_in[15];
    const float* bbe = (const float*)d_in[16];
    float* out = (float*)d_out;

    const size_t NF = (size_t)NN * DD;  // 7,000,000

    float* ws = (float*)d_ws;
    float* B0 = ws;            // h0 f32 -> DB2 u32 (after layer-0 apply)
    float* B1 = B0 + NF;       // h1 f32 -> h_final f32
    float* B2 = B1 + NF;       // PA f32 (both layers)
    float* B3 = B2 + NF;       // scratch (layer-2 dead D-std)
    float* B4 = B3 + NF;       // PD0 bf16 (kept through k_edge2)
    float* B5 = B4 + NF;       // PE0 bf16 (kept through k_edge2)
    float* B6 = B5 + NF;       // DB0 u32 (layer 0) -> PE2 bf16 (layer 2)
    float* num = B6 + NF;      // NF
    float* den = num + NF;     // NF
    float* red  = den + NF;        // 4*DD
    float* gsum = red + 4 * DD;    // NG*DD
    float* gcnt = gsum + NG * DD;  // NG
    float* v1 = gcnt + NG;
    float* v2 = v1 + DD;
    float* murs_e = v2 + DD;       // 2*DD
    float* murs_h = murs_e + 2 * DD;
    int* src_s = (int*)(murs_h + 2 * DD);   // NE
    float* ef_s  = (float*)(src_s + NE);    // NE
    float* sne_s = ef_s + NE;               // NE
    int* dst_s = (int*)(sne_s + NE);        // NE
    float* WT    = (float*)(dst_s + NE);    // 10 * WTS
    uintptr_t pal = ((uintptr_t)(WT + 10 * WTS) + 15) & ~(uintptr_t)15;
    float* CT2 = (float*)pal;                        // 420 floats
    unsigned short* WB = (unsigned short*)(CT2 + 420);  // 7680 u16
    // CSR build scratch: DEAD after k_fill -> alias into num (zeroed after build).
    int* off  = (int*)num;       // NN ints
    int* part = off + NN;        // 256 ints

    unsigned short* B3h = (unsigned short*)B3;
    unsigned short* B4h = (unsigned short*)B4;
    unsigned short* B5h = (unsigned short*)B5;
    unsigned short* B6h = (unsigned short*)B6;
    unsigned int*   B6u = (unsigned int*)B6;
    unsigned int*   B0u = (unsigned int*)B0;

    size_t need = (size_t)((char*)(WB + 7680) - (char*)d_ws);  // 268,249,840 B
    if (ws_size < need) return;

    const int NB_N36 = (NN + 35) / 36;        // 2778
    const int NB_N9  = (NN + 8) / 9;          // 11112
    const int NB_E256 = (NE + 255) / 256;     // 3907
    const int NB_SC  = (NN + SCB - 1) / SCB;  // 196
    const int NB_E0  = (NE + CH0 - 1) / CH0;  // 1737
    const int NB_E2  = (NE + EPB - 1) / EPB;  // 3125

    // ---- CSR build FIRST (off/part live in num's space) ----
    hipMemsetAsync(off, 0, NN * sizeof(int), stream);
    k_trAll<<<dim3(70, 9), 72, 0, stream>>>(Wh, Wg, WT);
    k_count<<<NB_E256, 256, 0, stream>>>(dst, off);
    k_scan_a<<<NB_SC, SCB, 0, stream>>>(off, part);
    k_scan_b<<<1, 256, 0, stream>>>(part, NB_SC);
    k_scan_c<<<NB_SC, SCB, 0, stream>>>(off, part);
    k_fill<<<NB_E256, 256, 0, stream>>>(src, dst, ef, sne, off, src_s, ef_s, sne_s, dst_s);

    // ---- now zero accumulators (overwrites dead off/part) ----
    hipMemsetAsync(num, 0, (2 * NF + 4 * DD + NG * DD + NG) * sizeof(float), stream);

    k_pre<<<1, 128, 0, stream>>>(We, be, Wg, bg, v1, v2);
    k_dense_r<<<NB_N36, 640, 0, stream>>>(x, 64, WT + 0 * WTS, bh, B0, NN);

    // ---- layer 0: fused quad dense A,B,D,E (DB0 packed into B6) ----
    k_dense_q<<<NB_N36, 640, 0, stream>>>(B0, WT + 1 * WTS, bg + 0 * 70, bg + 1 * 70,
                                          bg + 3 * 70, bg + 4 * 70, B2, B4h, B5h, B6u, NN);
    k_edge0<<<NB_E0, 640, 0, stream>>>(ef_s, sne_s, src_s, dst_s, B6u, B5h, v1, v2,
                                       num, den, red);
    k_stats<<<1, 128, 0, stream>>>(red, murs_e, 1.f / NE);
    k_prep2<<<1, 512, 0, stream>>>(v1, v2, murs_e, ge + 0, bbe + 0, We, be, Wg, CT2, WB);
    k_nstats<<<2048, 640, 0, stream>>>(B2, num, den, snn, red + 2 * DD);
    k_stats<<<1, 128, 0, stream>>>(red + 2 * DD, murs_h, 1.f / NN);
    k_apply<<<(int)((NF + 255) / 256), 256, 0, stream>>>(B0, B2, num, den, snn, murs_h,
                                                         gh + 0, bbh + 0, B1);

    // ---- layer 2: fused quad dense (DB2 packed into B0, E2 into B6h) ----
    hipMemsetAsync(num, 0, (2 * NF + 4 * DD) * sizeof(float), stream);  // num, den, red
    k_dense_q<<<NB_N36, 640, 0, stream>>>(B1, WT + 5 * WTS, bg + 10 * 70, bg + 11 * 70,
                                          bg + 13 * 70, bg + 14 * 70, B2, B3h, B6h, B0u, NN);
    k_edge2<<<NB_E2, 256, 0, stream>>>(ef_s, sne_s, src_s, dst_s, B4h, B5h, B0u, B6h,
                                       CT2, WB, bg + 12 * 70, num, den);
    k_nstats<<<2048, 640, 0, stream>>>(B2, num, den, snn, red + 2 * DD);
    k_stats<<<1, 128, 0, stream>>>(red + 2 * DD, murs_h, 1.f / NN);
    k_apply<<<(int)((NF + 255) / 256), 256, 0, stream>>>(B1, B2, num, den, snn, murs_h,
                                                         gh + 2 * DD, bbh + 2 * DD, B1);

    // ---- readout ----
    k_readout<<<NB_N9, 640, 0, stream>>>(B1, gid, gsum, gcnt);
    k_out<<<(NG * DD + 255) / 256, 256, 0, stream>>>(gsum, gcnt, out);
}

// Round 17
// 1555.694 us; speedup vs baseline: 8.6496x; 1.0178x over previous
//
#include <hip/hip_runtime.h>

#define NN 100000
#define NE 1000000
#define NG 100
#define DD 70
#define SE0 64             // edges per 16-lane group in k_edge0 (serial)
#define EPB0 (16 * SE0)    // 1024 edges per 256-thread block
#define TPW 5              // 16-edge tiles per wave in k_edge2
#define EPW (16 * TPW)     // 80 edges per wave
#define EPB (4 * EPW)      // 320 edges per 256-thread block (4 waves)
#define SCB 512
#define WTS (70 * 72)      // one transposed weight matrix, padded

typedef __attribute__((ext_vector_type(8))) short bf16x8;
typedef __attribute__((ext_vector_type(4))) float f32x4;

__device__ __forceinline__ float sigmoidf_(float x) { return 1.f / (1.f + expf(-x)); }

__device__ __forceinline__ unsigned int rne_bf16(float x) {
    unsigned int u = __float_as_uint(x);
    return (u + 0x7FFFu + ((u >> 16) & 1u)) >> 16;
}
__device__ __forceinline__ float b2f(unsigned short u) {
    return __uint_as_float(((unsigned int)u) << 16);
}
__device__ __forceinline__ float lo2f(unsigned int u) { return __uint_as_float(u << 16); }
__device__ __forceinline__ float hi2f(unsigned int u) { return __uint_as_float(u & 0xFFFF0000u); }

#define DOT4(acc, vv, ww) { acc = fmaf((vv).x, (ww).x, acc); acc = fmaf((vv).y, (ww).y, acc); \
                            acc = fmaf((vv).z, (ww).z, acc); acc = fmaf((vv).w, (ww).w, acc); }

// ---------- transpose weight matrices into WT[m][70][72], zero-padded ----------
__global__ void k_trAll(const float* __restrict__ Wh, const float* __restrict__ Wg,
                        float* __restrict__ WT) {
    int m = blockIdx.y, f = blockIdx.x, k = threadIdx.x;
    const float* W;
    int K = DD;
    switch (m) {
        case 0: W = Wh; K = 64; break;
        case 1: W = Wg + 0 * 4900; break;
        case 2: W = Wg + 1 * 4900; break;
        case 3: W = Wg + 3 * 4900; break;
        case 4: W = Wg + 4 * 4900; break;
        case 5: W = Wg + 10 * 4900; break;
        case 6: W = Wg + 11 * 4900; break;
        case 7: W = Wg + 13 * 4900; break;
        default: W = Wg + 14 * 4900; break;
    }
    if (k < 72) WT[(m * 70 + f) * 72 + k] = (k < K) ? W[k * DD + f] : 0.f;
}

// ---------- single skinny dense (used for h0, K=64) ----------
__global__ __launch_bounds__(640) void k_dense_r(const float* __restrict__ x, int K,
                                                 const float* __restrict__ WTm,
                                                 const float* __restrict__ bias,
                                                 float* __restrict__ out, int nrows) {
    __shared__ float sx[36 * 72];
    int t = threadIdx.x;
    int r = t / DD, f = t - r * DD;
    long rb = (long)blockIdx.x * 36;
    for (int idx = t; idx < 36 * 72; idx += 640) {
        int rr = idx / 72, kk = idx - rr * 72;
        long i = rb + rr;
        sx[idx] = (kk < K && i < nrows) ? x[i * K + kk] : 0.f;
    }
    __syncthreads();
    if (r < 9) {
        const float4* wr = (const float4*)(WTm + f * 72);
        float bb = bias[f];
        float a0 = bb, a1 = bb, a2 = bb, a3 = bb;
        const float4* s0 = (const float4*)&sx[(r) * 72];
        const float4* s1 = (const float4*)&sx[(r + 9) * 72];
        const float4* s2 = (const float4*)&sx[(r + 18) * 72];
        const float4* s3 = (const float4*)&sx[(r + 27) * 72];
#pragma unroll 1
        for (int q = 0; q < 18; q += 2) {
            float4 wA = wr[q], wB = wr[q + 1];
            float4 vA0 = s0[q], vB0 = s0[q + 1];
            DOT4(a0, vA0, wA) DOT4(a0, vB0, wB)
            float4 vA1 = s1[q], vB1 = s1[q + 1];
            DOT4(a1, vA1, wA) DOT4(a1, vB1, wB)
            float4 vA2 = s2[q], vB2 = s2[q + 1];
            DOT4(a2, vA2, wA) DOT4(a2, vB2, wB)
            float4 vA3 = s3[q], vB3 = s3[q + 1];
            DOT4(a3, vA3, wA) DOT4(a3, vB3, wB)
        }
        long i0 = rb + r, i1 = i0 + 9, i2 = i0 + 18, i3 = i0 + 27;
        if (i0 < nrows) out[i0 * DD + f] = a0;
        if (i1 < nrows) out[i1 * DD + f] = a1;
        if (i2 < nrows) out[i2 * DD + f] = a2;
        if (i3 < nrows) out[i3 * DD + f] = a3;
    }
}

// ---------- fused quad dense, PAIRED projections: one q-sweep feeds 2 matrices ----------
// Per-matrix FMA order identical to the old PROJ -> bit-identical results.
#define PROJ2(M0, M1, BIAS0, BIAS1, ST0, ST1)                                     \
    {                                                                             \
        const float4* wr0 = (const float4*)(WT4 + (M0) * WTS + f * 72);           \
        const float4* wr1 = (const float4*)(WT4 + (M1) * WTS + f * 72);           \
        float bb0 = (BIAS0)[f], bb1 = (BIAS1)[f];                                 \
        float a0 = bb0, a1 = bb0, a2 = bb0, a3 = bb0;                             \
        float c0 = bb1, c1 = bb1, c2 = bb1, c3 = bb1;                             \
        _Pragma("unroll 1")                                                       \
        for (int q = 0; q < 18; q += 2) {                                         \
            float4 wA0 = wr0[q], wB0 = wr0[q + 1];                                \
            float4 wA1 = wr1[q], wB1 = wr1[q + 1];                                \
            float4 vA = s0[q], vB = s0[q + 1];                                    \
            DOT4(a0, vA, wA0) DOT4(a0, vB, wB0)                                   \
            DOT4(c0, vA, wA1) DOT4(c0, vB, wB1)                                   \
            vA = s1[q]; vB = s1[q + 1];                                           \
            DOT4(a1, vA, wA0) DOT4(a1, vB, wB0)                                   \
            DOT4(c1, vA, wA1) DOT4(c1, vB, wB1)                                   \
            vA = s2[q]; vB = s2[q + 1];                                           \
            DOT4(a2, vA, wA0) DOT4(a2, vB, wB0)                                   \
            DOT4(c2, vA, wA1) DOT4(c2, vB, wB1)                                   \
            vA = s3[q]; vB = s3[q + 1];                                           \
            DOT4(a3, vA, wA0) DOT4(a3, vB, wB0)                                   \
            DOT4(c3, vA, wA1) DOT4(c3, vB, wB1)                                   \
        }                                                                         \
        ST0(0, i0, a0) ST0(1, i1, a1) ST0(2, i2, a2) ST0(3, i3, a3)               \
        ST1(0, i0, c0) ST1(1, i1, c1) ST1(2, i2, c2) ST1(3, i3, c3)               \
    }

__global__ __launch_bounds__(640) void k_dense_q(
    const float* __restrict__ x, const float* __restrict__ WT4,
    const float* __restrict__ bA, const float* __restrict__ bB,
    const float* __restrict__ bD, const float* __restrict__ bE,
    float* __restrict__ outA, unsigned short* __restrict__ outDstd,
    unsigned short* __restrict__ outE, unsigned int* __restrict__ outDB, int nrows) {
    __shared__ float sx[36 * 72];
    int t = threadIdx.x;
    int r = t / DD, f = t - r * DD;
    long rb = (long)blockIdx.x * 36;
    for (int idx = t; idx < 36 * 72; idx += 640) {
        int rr = idx / 72, kk = idx - rr * 72;
        long i = rb + rr;
        sx[idx] = (kk < DD && i < nrows) ? x[i * DD + kk] : 0.f;
    }
    __syncthreads();
    if (r < 9) {
        const float4* s0 = (const float4*)&sx[(r) * 72];
        const float4* s1 = (const float4*)&sx[(r + 9) * 72];
        const float4* s2 = (const float4*)&sx[(r + 18) * 72];
        const float4* s3 = (const float4*)&sx[(r + 27) * 72];
        long i0 = rb + r, i1 = i0 + 9, i2 = i0 + 18, i3 = i0 + 27;
        float vB0 = 0.f, vB1 = 0.f, vB2 = 0.f, vB3 = 0.f;
#define ST_A(row, ii, aa) if ((ii) < nrows) outA[(ii) * DD + f] = (aa);
#define ST_B(row, ii, aa) vB##row = (aa);
#define ST_D(row, ii, aa) if ((ii) < nrows) { unsigned int ud = rne_bf16(aa); \
            outDstd[(ii) * DD + f] = (unsigned short)ud; \
            outDB[(ii) * DD + f] = ud | (rne_bf16(vB##row) << 16); }
#define ST_E(row, ii, aa) if ((ii) < nrows) outE[(ii) * DD + f] = (unsigned short)rne_bf16(aa);
        PROJ2(0, 1, bA, bB, ST_A, ST_B)
        PROJ2(2, 3, bD, bE, ST_D, ST_E)
#undef ST_A
#undef ST_B
#undef ST_D
#undef ST_E
    }
}

// ---------- v1 = We @ Wc0 ; v2 = be @ Wc0 + bc0 ----------
__global__ void k_pre(const float* __restrict__ We, const float* __restrict__ be,
                      const float* __restrict__ Wg, const float* __restrict__ bg,
                      float* __restrict__ v1, float* __restrict__ v2) {
    int f = threadIdx.x;
    if (f < DD) {
        const float* W2 = Wg + 2 * DD * DD;
        const float* b2 = bg + 2 * DD;
        float a = 0.f, c = 0.f;
        for (int k = 0; k < DD; ++k) {
            a = fmaf(We[k], W2[k * DD + f], a);
            c = fmaf(be[k], W2[k * DD + f], c);
        }
        v1[f] = a;
        v2[f] = c + b2[f];
    }
}

// ---------- prep for MFMA edge2: CT2 staging constants + WB B-fragments (bf16) ----------
__global__ void k_prep2(const float* __restrict__ v1, const float* __restrict__ v2,
                        const float* __restrict__ murs_e, const float* __restrict__ ge,
                        const float* __restrict__ bbe, const float* __restrict__ We,
                        const float* __restrict__ be, const float* __restrict__ Wg,
                        float* __restrict__ CT2, unsigned short* __restrict__ WB) {
    int t = threadIdx.x;  // 512 threads, 1 block
    if (t < 35) {
        int f0 = 2 * t, f1 = 2 * t + 1;
        float A0 = murs_e[DD + f0] * ge[f0], A1 = murs_e[DD + f1] * ge[f1];
        float* c = CT2 + t * 12;
        c[0] = v1[f0];  c[1] = v1[f1];
        c[2] = v2[f0];  c[3] = v2[f1];
        c[4] = A0;      c[5] = A1;
        c[6] = bbe[f0] - murs_e[f0] * A0;
        c[7] = bbe[f1] - murs_e[f1] * A1;
        c[8] = We[f0];  c[9] = We[f1];
        c[10] = be[f0]; c[11] = be[f1];
    }
    const float* WC2 = Wg + 12 * 4900;
    for (int idx = t; idx < 960; idx += 512) {
        int nt = idx / 192, rem = idx - nt * 192;
        int c = rem / 64, l = rem - c * 64;
        int n = nt * 16 + (l & 15);
        int kb = c * 32 + (l >> 4) * 8;
        for (int j = 0; j < 8; ++j) {
            int k = kb + j;
            unsigned short v = 0;
            if (k < 70 && n < 70) v = (unsigned short)rne_bf16(WC2[k * 70 + n]);
            WB[((nt * 3 + c) * 64 + l) * 8 + j] = v;
        }
    }
}

// ---------- CSR build: count / scan / fill ----------
__global__ void k_count(const int* __restrict__ dst, int* __restrict__ off) {
    int j = blockIdx.x * 256 + threadIdx.x;
    if (j < NE) atomicAdd(&off[dst[j]], 1);
}

__global__ void k_scan_a(int* __restrict__ off, int* __restrict__ part) {
    __shared__ int s[SCB];
    int t = threadIdx.x, i = blockIdx.x * SCB + t;
    int v = (i < NN) ? off[i] : 0;
    s[t] = v;
    __syncthreads();
    for (int d = 1; d < SCB; d <<= 1) {
        int x = (t >= d) ? s[t - d] : 0;
        __syncthreads();
        s[t] += x;
        __syncthreads();
    }
    if (i < NN) off[i] = s[t] - v;
    if (t == SCB - 1) part[blockIdx.x] = s[t];
}

__global__ void k_scan_b(int* __restrict__ part, int nb) {
    __shared__ int s[256];
    int t = threadIdx.x;
    int v = (t < nb) ? part[t] : 0;
    s[t] = v;
    __syncthreads();
    for (int d = 1; d < 256; d <<= 1) {
        int x = (t >= d) ? s[t - d] : 0;
        __syncthreads();
        s[t] += x;
        __syncthreads();
    }
    if (t < nb) part[t] = s[t] - v;
}

__global__ void k_scan_c(int* __restrict__ off, const int* __restrict__ part) {
    int i = blockIdx.x * SCB + threadIdx.x;
    if (i < NN) off[i] += part[blockIdx.x];
}

__global__ void k_fill(const int* __restrict__ src, const int* __restrict__ dst,
                       const float* __restrict__ ef, const float* __restrict__ sne,
                       int* __restrict__ off, int* __restrict__ src_s,
                       float* __restrict__ ef_s, float* __restrict__ sne_s,
                       int* __restrict__ dst_s) {
    int j = blockIdx.x * 256 + threadIdx.x;
    if (j < NE) {
        int d = dst[j];
        int pos = atomicAdd(&off[d], 1);
        src_s[pos] = src[j];
        ef_s[pos] = ef[j];
        sne_s[pos] = sne[j];
        dst_s[pos] = d;
    }
}

// ---------- layer-0 edge pass: col/hi decomposition, 256 threads, 4 indep waves ----------
// 16-lane group (hi) owns SE0 consecutive sorted edges; lane covers 5 features (col+16*nt).
__global__ __launch_bounds__(256) void k_edge0(
    const float* __restrict__ ef_s, const float* __restrict__ sne_s,
    const int* __restrict__ src_s, const int* __restrict__ dst_s,
    const unsigned int* __restrict__ DB0, const unsigned short* __restrict__ PE,
    const float* __restrict__ v1, const float* __restrict__ v2,
    float* __restrict__ num, float* __restrict__ den, float* __restrict__ red) {
    __shared__ float ss[DD], sq[DD];
    int t = threadIdx.x;
    if (t < DD) { ss[t] = 0.f; sq[t] = 0.f; }
    int w = t >> 6, l = t & 63;
    int col = l & 15, hi = l >> 4;
    float c1v[5], c2v[5];
#pragma unroll
    for (int nt = 0; nt < 5; ++nt) {
        int nv = nt * 16 + col;
        c1v[nt] = (nv < DD) ? v1[nv] : 0.f;
        c2v[nt] = (nv < DD) ? v2[nv] : 0.f;
    }
    int e_beg = (blockIdx.x * 16 + w * 4 + hi) * SE0;
    bool live = e_beg < NE;
    int lim = live ? (NE - e_beg < SE0 ? NE - e_beg : SE0) : 0;
    int dcur = live ? dst_s[e_beg] : 0;
    float pec[5], an[5], ad[5], as_[5], aq[5];
#pragma unroll
    for (int nt = 0; nt < 5; ++nt) {
        int nv = nt * 16 + col;
        pec[nt] = (live && nv < DD) ? b2f(PE[(long)dcur * DD + nv]) : 0.f;
        an[nt] = 0.f; ad[nt] = 0.f; as_[nt] = 0.f; aq[nt] = 0.f;
    }
    for (int ee = 0; ee < lim; ++ee) {
        int e = e_beg + ee;
        int d = dst_s[e], s = src_s[e];
        float efv = ef_s[e], snv = sne_s[e];
        if (d != dcur) {
#pragma unroll
            for (int nt = 0; nt < 5; ++nt) {
                int nv = nt * 16 + col;
                if (nv < DD) {
                    unsafeAtomicAdd(&num[(long)dcur * DD + nv], an[nt]);
                    unsafeAtomicAdd(&den[(long)dcur * DD + nv], ad[nt]);
                }
                an[nt] = 0.f; ad[nt] = 0.f;
            }
            dcur = d;
#pragma unroll
            for (int nt = 0; nt < 5; ++nt) {
                int nv = nt * 16 + col;
                if (nv < DD) pec[nt] = b2f(PE[(long)dcur * DD + nv]);
            }
        }
#pragma unroll
        for (int nt = 0; nt < 5; ++nt) {
            int nv = nt * 16 + col;
            if (nv < DD) {
                unsigned int db = DB0[(long)s * DD + nv];  // D low, B high
                float en = lo2f(db) + pec[nt] + efv * c1v[nt] + c2v[nt];
                float sg = sigmoidf_(en);
                an[nt] = fmaf(sg, hi2f(db), an[nt]);
                ad[nt] += sg;
                float tv = en * snv;
                as_[nt] += tv;
                aq[nt] = fmaf(tv, tv, aq[nt]);
            }
        }
    }
    if (live) {
#pragma unroll
        for (int nt = 0; nt < 5; ++nt) {
            int nv = nt * 16 + col;
            if (nv < DD) {
                unsafeAtomicAdd(&num[(long)dcur * DD + nv], an[nt]);
                unsafeAtomicAdd(&den[(long)dcur * DD + nv], ad[nt]);
            }
        }
    }
    __syncthreads();
#pragma unroll
    for (int nt = 0; nt < 5; ++nt) {
        int nv = nt * 16 + col;
        if (nv < DD) { atomicAdd(&ss[nv], as_[nt]); atomicAdd(&sq[nv], aq[nt]); }
    }
    __syncthreads();
    if (t < DD) {
        atomicAdd(&red[t], ss[t]);
        atomicAdd(&red[DD + t], sq[t]);
    }
}

// ---------- layer-2 edge kernel: MFMA bf16, DB2 packed + run-cached PE2 ----------
__global__ __launch_bounds__(256) void k_edge2(
    const float* __restrict__ ef_s, const float* __restrict__ sne_s,
    const int* __restrict__ src_s, const int* __restrict__ dst_s,
    const unsigned short* __restrict__ PD0, const unsigned short* __restrict__ PE0,
    const unsigned int* __restrict__ DB2, const unsigned short* __restrict__ PE2,
    const float* __restrict__ CT2, const unsigned short* __restrict__ WB,
    const float* __restrict__ bC2, float* __restrict__ num, float* __restrict__ den) {
    __shared__ __align__(16) unsigned short As[4 * 16 * 104];
    int t = threadIdx.x;
    int w = t >> 6, l = t & 63;
    unsigned short* Aw = &As[w * 1664];
    for (int i = l; i < 832; i += 64) ((unsigned int*)Aw)[i] = 0u;
    int wb_e = blockIdx.x * EPB + w * EPW;
    if (wb_e >= NE) return;
    int col = l & 15, hi = l >> 4;
    bf16x8 bfr[15];
#pragma unroll
    for (int q = 0; q < 15; ++q)
        bfr[q] = *(const bf16x8*)(WB + (q * 64 + l) * 8);
    float bc[5];
#pragma unroll
    for (int nt = 0; nt < 5; ++nt) bc[nt] = bC2[nt * 16 + col];
    int e0p = wb_e + hi * 4;
    if (e0p > NE - 1) e0p = NE - 1;
    int dcur = dst_s[e0p];
    float an[5], ad[5], pe2c[5];
#pragma unroll
    for (int nt = 0; nt < 5; ++nt) {
        an[nt] = 0.f; ad[nt] = 0.f;
        int nv = nt * 16 + col;
        pe2c[nt] = (nv < 70) ? b2f(PE2[(long)dcur * DD + nv]) : 0.f;
    }
    for (int tt = 0; tt < TPW; ++tt) {
        int et = wb_e + tt * 16;
        if (et >= NE) break;
        // ---- stage 16 e1-rows as bf16 (bf16 tables: one u32 covers 2 features) ----
        for (int i = l; i < 560; i += 64) {
            int el = i / 35, fp = i - el * 35, f = fp * 2;
            int e = et + el;
            unsigned int val = 0u;
            if (e < NE) {
                int s = src_s[e], d = dst_s[e];
                float efv = ef_s[e], sn = sne_s[e];
                const float* ct = CT2 + fp * 12;
                unsigned int upd = *(const unsigned int*)(PD0 + (long)s * DD + f);
                unsigned int upe = *(const unsigned int*)(PE0 + (long)d * DD + f);
                float pdx = lo2f(upd), pdy = hi2f(upd);
                float pex = lo2f(upe), pey = hi2f(upe);
                float en0a = pdx + pex + efv * ct[0] + ct[2];
                float en0b = pdy + pey + efv * ct[1] + ct[3];
                float ra = fmaxf(fmaf(en0a * sn, ct[4], ct[6]), 0.f);
                float rb = fmaxf(fmaf(en0b * sn, ct[5], ct[7]), 0.f);
                float e1a = fmaf(efv, ct[8], ct[10]) + ra;
                float e1b = fmaf(efv, ct[9], ct[11]) + rb;
                val = rne_bf16(e1a) | (rne_bf16(e1b) << 16);
            }
            ((unsigned int*)Aw)[(el * 104 + f) >> 1] = val;
        }
        // ---- A fragments + 15 MFMAs ----
        bf16x8 af[3];
#pragma unroll
        for (int c = 0; c < 3; ++c)
            af[c] = *(const bf16x8*)(Aw + (l & 15) * 104 + c * 32 + hi * 8);
        f32x4 acc[5];
#pragma unroll
        for (int nt = 0; nt < 5; ++nt) {
            acc[nt] = (f32x4){0.f, 0.f, 0.f, 0.f};
#pragma unroll
            for (int c = 0; c < 3; ++c)
                acc[nt] = __builtin_amdgcn_mfma_f32_16x16x32_bf16(af[c], bfr[nt * 3 + c],
                                                                  acc[nt], 0, 0, 0);
        }
        // ---- epilogue: D layout col=lane&15, row=(lane>>4)*4+reg ----
#pragma unroll
        for (int j = 0; j < 4; ++j) {
            int e = et + hi * 4 + j;
            if (e < NE) {
                int d = dst_s[e];
                if (d != dcur) {
#pragma unroll
                    for (int nt = 0; nt < 5; ++nt) {
                        int nv = nt * 16 + col;
                        if (nv < 70) {
                            unsafeAtomicAdd(&num[(long)dcur * DD + nv], an[nt]);
                            unsafeAtomicAdd(&den[(long)dcur * DD + nv], ad[nt]);
                        }
                        an[nt] = 0.f; ad[nt] = 0.f;
                    }
                    dcur = d;
#pragma unroll
                    for (int nt = 0; nt < 5; ++nt) {
                        int nv = nt * 16 + col;
                        if (nv < 70) pe2c[nt] = b2f(PE2[(long)dcur * DD + nv]);
                    }
                }
                int s = src_s[e];
#pragma unroll
                for (int nt = 0; nt < 5; ++nt) {
                    int nv = nt * 16 + col;
                    if (nv < 70) {
                        unsigned int db = DB2[(long)s * DD + nv];  // D low, B high
                        float en = acc[nt][j] + bc[nt] + lo2f(db) + pe2c[nt];
                        float sg = sigmoidf_(en);
                        an[nt] = fmaf(sg, hi2f(db), an[nt]);
                        ad[nt] += sg;
                    }
                }
            }
        }
    }
#pragma unroll
    for (int nt = 0; nt < 5; ++nt) {
        int nv = nt * 16 + col;
        if (nv < 70) {
            unsafeAtomicAdd(&num[(long)dcur * DD + nv], an[nt]);
            unsafeAtomicAdd(&den[(long)dcur * DD + nv], ad[nt]);
        }
    }
}

// ---------- node BN stats: grid-stride, reg-accum ----------
__global__ __launch_bounds__(640) void k_nstats(const float* __restrict__ PA,
                                                const float* __restrict__ num,
                                                const float* __restrict__ den,
                                                const float* __restrict__ snn,
                                                float* __restrict__ red) {
    int t = threadIdx.x;
    int r = t / DD, f = t - r * DD;
    bool act = (r < 9);
    float acc_s = 0.f, acc_q = 0.f;
    const int T = (NN + 8) / 9;
    for (int tile = blockIdx.x; tile < T; tile += gridDim.x) {
        int i = tile * 9 + r;
        if (act && i < NN) {
            long o = (long)i * DD + f;
            float v = (PA[o] + num[o] / (den[o] + 1e-6f)) * snn[i];
            acc_s += v;
            acc_q = fmaf(v, v, acc_q);
        }
    }
    __shared__ float ss[DD], sq[DD];
    if (t < DD) { ss[t] = 0.f; sq[t] = 0.f; }
    __syncthreads();
    if (act) { atomicAdd(&ss[f], acc_s); atomicAdd(&sq[f], acc_q); }
    __syncthreads();
    if (t < DD) {
        atomicAdd(&red[t], ss[t]);
        atomicAdd(&red[DD + t], sq[t]);
    }
}

// ---------- finalize BN stats ----------
__global__ void k_stats(const float* __restrict__ sums, float* __restrict__ murs, float invn) {
    int f = threadIdx.x;
    if (f < DD) {
        float mu = sums[f] * invn;
        float var = sums[DD + f] * invn - mu * mu;
        murs[f] = mu;
        murs[DD + f] = rsqrtf(var + 1e-5f);
    }
}

// ---------- recompute v, BN-apply + relu + residual ----------
__global__ __launch_bounds__(256) void k_apply(const float* __restrict__ hin,
                                               const float* __restrict__ PA,
                                               const float* __restrict__ num,
                                               const float* __restrict__ den,
                                               const float* __restrict__ snn,
                                               const float* __restrict__ murs,
                                               const float* __restrict__ g,
                                               const float* __restrict__ b,
                                               float* __restrict__ hout) {
    long idx = (long)blockIdx.x * 256 + threadIdx.x;
    if (idx < (long)NN * DD) {
        int i = (int)(idx / DD);
        int f = (int)(idx - (long)i * DD);
        float v = (PA[idx] + num[idx] / (den[idx] + 1e-6f)) * snn[i];
        float bnv = (v - murs[f]) * murs[DD + f] * g[f] + b[f];
        hout[idx] = hin[idx] + fmaxf(bnv, 0.f);
    }
}

// ---------- per-graph sums ----------
__global__ __launch_bounds__(640) void k_readout(const float* __restrict__ h,
                                                 const int* __restrict__ gid,
                                                 float* __restrict__ gsum,
                                                 float* __restrict__ gcnt) {
    __shared__ float sv[9 * DD];
    __shared__ int sg_[9];
    int t = threadIdx.x;
    int r = t / DD, f = t - r * DD;
    int i = blockIdx.x * 9 + r;
    if (r < 9 && i < NN) {
        sv[r * DD + f] = h[(long)i * DD + f];
        if (f == 0) sg_[r] = gid[i];
    }
    __syncthreads();
    int nvalid = NN - blockIdx.x * 9;
    if (nvalid > 9) nvalid = 9;
    if (t < DD && nvalid > 0) {
        float acc = 0.f;
        int cur = sg_[0];
        for (int rr = 0; rr < nvalid; ++rr) {
            int g = sg_[rr];
            if (g != cur) {
                unsafeAtomicAdd(&gsum[cur * DD + t], acc);
                acc = 0.f;
                cur = g;
            }
            acc += sv[rr * DD + t];
        }
        unsafeAtomicAdd(&gsum[cur * DD + t], acc);
        if (t == 0) {
            int cnt = 0;
            cur = sg_[0];
            for (int rr = 0; rr < nvalid; ++rr) {
                if (sg_[rr] != cur) {
                    unsafeAtomicAdd(&gcnt[cur], (float)cnt);
                    cnt = 0;
                    cur = sg_[rr];
                }
                cnt++;
            }
            unsafeAtomicAdd(&gcnt[cur], (float)cnt);
        }
    }
}

__global__ void k_out(const float* __restrict__ gsum, const float* __restrict__ gcnt,
                      float* __restrict__ out) {
    int idx = blockIdx.x * 256 + threadIdx.x;
    if (idx < NG * DD) {
        int g = idx / DD;
        out[idx] = gsum[idx] / fmaxf(gcnt[g], 1.f);
    }
}

extern "C" void kernel_launch(void* const* d_in, const int* in_sizes, int n_in,
                              void* d_out, int out_size, void* d_ws, size_t ws_size,
                              hipStream_t stream) {
    const float* x   = (const float*)d_in[0];
    const float* ef  = (const float*)d_in[1];
    const float* snn = (const float*)d_in[2];
    const float* sne = (const float*)d_in[3];
    const int*   src = (const int*)d_in[4];
    const int*   dst = (const int*)d_in[5];
    const int*   gid = (const int*)d_in[6];
    const float* Wh  = (const float*)d_in[7];
    const float* bh  = (const float*)d_in[8];
    const float* We  = (const float*)d_in[9];
    const float* be  = (const float*)d_in[10];
    const float* Wg  = (const float*)d_in[11];
    const float* bg  = (const float*)d_in[12];
    const float* gh  = (const float*)d_in[13];
    const float* bbh = (const float*)d_in[14];
    const float* ge  = (const float*)d_in[15];
    const float* bbe = (const float*)d_in[16];
    float* out = (float*)d_out;

    const size_t NF = (size_t)NN * DD;  // 7,000,000

    float* ws = (float*)d_ws;
    float* B0 = ws;            // h0 f32 -> DB2 u32 (after layer-0 apply)
    float* B1 = B0 + NF;       // h1 f32 -> h_final f32
    float* B2 = B1 + NF;       // PA f32 (both layers)
    float* B3 = B2 + NF;       // scratch (layer-2 dead D-std)
    float* B4 = B3 + NF;       // PD0 bf16 (kept through k_edge2)
    float* B5 = B4 + NF;       // PE0 bf16 (kept through k_edge2)
    float* B6 = B5 + NF;       // DB0 u32 (layer 0) -> PE2 bf16 (layer 2)
    float* num = B6 + NF;      // NF
    float* den = num + NF;     // NF
    float* red  = den + NF;        // 4*DD
    float* gsum = red + 4 * DD;    // NG*DD
    float* gcnt = gsum + NG * DD;  // NG
    float* v1 = gcnt + NG;
    float* v2 = v1 + DD;
    float* murs_e = v2 + DD;       // 2*DD
    float* murs_h = murs_e + 2 * DD;
    int* src_s = (int*)(murs_h + 2 * DD);   // NE
    float* ef_s  = (float*)(src_s + NE);    // NE
    float* sne_s = ef_s + NE;               // NE
    int* dst_s = (int*)(sne_s + NE);        // NE
    float* WT    = (float*)(dst_s + NE);    // 10 * WTS
    uintptr_t pal = ((uintptr_t)(WT + 10 * WTS) + 15) & ~(uintptr_t)15;
    float* CT2 = (float*)pal;                        // 420 floats
    unsigned short* WB = (unsigned short*)(CT2 + 420);  // 7680 u16
    // CSR build scratch: DEAD after k_fill -> alias into num (zeroed after build).
    int* off  = (int*)num;       // NN ints
    int* part = off + NN;        // 256 ints

    unsigned short* B3h = (unsigned short*)B3;
    unsigned short* B4h = (unsigned short*)B4;
    unsigned short* B5h = (unsigned short*)B5;
    unsigned short* B6h = (unsigned short*)B6;
    unsigned int*   B6u = (unsigned int*)B6;
    unsigned int*   B0u = (unsigned int*)B0;

    size_t need = (size_t)((char*)(WB + 7680) - (char*)d_ws);  // 268,249,840 B
    if (ws_size < need) return;

    const int NB_N36 = (NN + 35) / 36;        // 2778
    const int NB_N9  = (NN + 8) / 9;          // 11112
    const int NB_E256 = (NE + 255) / 256;     // 3907
    const int NB_SC  = (NN + SCB - 1) / SCB;  // 196
    const int NB_E0  = (NE + EPB0 - 1) / EPB0;  // 977
    const int NB_E2  = (NE + EPB - 1) / EPB;    // 3125

    // ---- CSR build FIRST (off/part live in num's space) ----
    hipMemsetAsync(off, 0, NN * sizeof(int), stream);
    k_trAll<<<dim3(70, 9), 72, 0, stream>>>(Wh, Wg, WT);
    k_count<<<NB_E256, 256, 0, stream>>>(dst, off);
    k_scan_a<<<NB_SC, SCB, 0, stream>>>(off, part);
    k_scan_b<<<1, 256, 0, stream>>>(part, NB_SC);
    k_scan_c<<<NB_SC, SCB, 0, stream>>>(off, part);
    k_fill<<<NB_E256, 256, 0, stream>>>(src, dst, ef, sne, off, src_s, ef_s, sne_s, dst_s);

    // ---- now zero accumulators (overwrites dead off/part) ----
    hipMemsetAsync(num, 0, (2 * NF + 4 * DD + NG * DD + NG) * sizeof(float), stream);

    k_pre<<<1, 128, 0, stream>>>(We, be, Wg, bg, v1, v2);
    k_dense_r<<<NB_N36, 640, 0, stream>>>(x, 64, WT + 0 * WTS, bh, B0, NN);

    // ---- layer 0: fused quad dense A,B,D,E (DB0 packed into B6) ----
    k_dense_q<<<NB_N36, 640, 0, stream>>>(B0, WT + 1 * WTS, bg + 0 * 70, bg + 1 * 70,
                                          bg + 3 * 70, bg + 4 * 70, B2, B4h, B5h, B6u, NN);
    k_edge0<<<NB_E0, 256, 0, stream>>>(ef_s, sne_s, src_s, dst_s, B6u, B5h, v1, v2,
                                       num, den, red);
    k_stats<<<1, 128, 0, stream>>>(red, murs_e, 1.f / NE);
    k_prep2<<<1, 512, 0, stream>>>(v1, v2, murs_e, ge + 0, bbe + 0, We, be, Wg, CT2, WB);
    k_nstats<<<2048, 640, 0, stream>>>(B2, num, den, snn, red + 2 * DD);
    k_stats<<<1, 128, 0, stream>>>(red + 2 * DD, murs_h, 1.f / NN);
    k_apply<<<(int)((NF + 255) / 256), 256, 0, stream>>>(B0, B2, num, den, snn, murs_h,
                                                         gh + 0, bbh + 0, B1);

    // ---- layer 2: fused quad dense (DB2 packed into B0, E2 into B6h) ----
    hipMemsetAsync(num, 0, (2 * NF + 4 * DD) * sizeof(float), stream);  // num, den, red
    k_dense_q<<<NB_N36, 640, 0, stream>>>(B1, WT + 5 * WTS, bg + 10 * 70, bg + 11 * 70,
                                          bg + 13 * 70, bg + 14 * 70, B2, B3h, B6h, B0u, NN);
    k_edge2<<<NB_E2, 256, 0, stream>>>(ef_s, sne_s, src_s, dst_s, B4h, B5h, B0u, B6h,
                                       CT2, WB, bg + 12 * 70, num, den);
    k_nstats<<<2048, 640, 0, stream>>>(B2, num, den, snn, red + 2 * DD);
    k_stats<<<1, 128, 0, stream>>>(red + 2 * DD, murs_h, 1.f / NN);
    k_apply<<<(int)((NF + 255) / 256), 256, 0, stream>>>(B1, B2, num, den, snn, murs_h,
                                                         gh + 2 * DD, bbh + 2 * DD, B1);

    // ---- readout ----
    k_readout<<<NB_N9, 640, 0, stream>>>(B1, gid, gsum, gcnt);
    k_out<<<(NG * DD + 255) / 256, 256, 0, stream>>>(gsum, gcnt, out);
}